// Round 2
// baseline (855.265 us; speedup 1.0000x reference)
//
#include <hip/hip_runtime.h>

// Problem constants
#define BB   4
#define SS   2048
#define DDIM 1024
#define HH   16
#define DKK  64
#define FFF  2048
#define NTOK (BB * SS)   // 8192
#define QKVS 3072        // fused qkv row stride
#define SCALE_Q 0.18033688011112042f   // 0.125 * log2(e), folded into Q

typedef __bf16 bf16x8 __attribute__((ext_vector_type(8)));
typedef float floatx4 __attribute__((ext_vector_type(4)));

__device__ __forceinline__ unsigned short f2bf(float f) {
    union { float f; unsigned u; } v; v.f = f;
    unsigned r = v.u + 0x7fffu + ((v.u >> 16) & 1u);   // RNE
    return (unsigned short)(r >> 16);
}

// pack hi16(a),hi16(b) -> one u32 (bf16 truncation x2 in one v_perm)
__device__ __forceinline__ unsigned pack_bf_trunc(float a, float b) {
    union { float f; unsigned u; } x, y; x.f = a; y.f = b;
    return __builtin_amdgcn_perm(y.u, x.u, 0x07060302u);
}

__device__ __forceinline__ bf16x8 as_frag(uint4 v) {
    union { uint4 u; bf16x8 f; } c; c.u = v; return c.f;
}

__device__ __forceinline__ void async_copy16(const unsigned short* g, unsigned short* l) {
    __builtin_amdgcn_global_load_lds(
        (const __attribute__((address_space(1))) void*)g,
        (__attribute__((address_space(3))) void*)l, 16, 0, 0);
}

// ---------------------------------------------------------------------------
// All six weight transposes fused: fp32 W[K][N] -> bf16 Wt[N][K], 64x64 tiles
// Wq/Wk/Wv land in one contiguous wqkvT [3072][1024].
// ---------------------------------------------------------------------------
__global__ __launch_bounds__(256) void transpose_all(
    const float* __restrict__ Wq, const float* __restrict__ Wk,
    const float* __restrict__ Wv, const float* __restrict__ Wo,
    const float* __restrict__ fc1, const float* __restrict__ fc2,
    unsigned short* __restrict__ wqkvT, unsigned short* __restrict__ woT,
    unsigned short* __restrict__ fc1T, unsigned short* __restrict__ fc2T) {
    __shared__ float tile[64][65];
    int t = blockIdx.x;
    const float* src; unsigned short* dst; int K, N, tl;
    if (t < 256)       { src = Wq;  dst = wqkvT;                       K = 1024; N = 1024; tl = t; }
    else if (t < 512)  { src = Wk;  dst = wqkvT + (size_t)1024 * 1024; K = 1024; N = 1024; tl = t - 256; }
    else if (t < 768)  { src = Wv;  dst = wqkvT + (size_t)2048 * 1024; K = 1024; N = 1024; tl = t - 512; }
    else if (t < 1024) { src = Wo;  dst = woT;                         K = 1024; N = 1024; tl = t - 768; }
    else if (t < 1536) { src = fc1; dst = fc1T;                        K = 1024; N = 2048; tl = t - 1024; }
    else               { src = fc2; dst = fc2T;                        K = 2048; N = 1024; tl = t - 1536; }
    int kt = K >> 6;
    int k0 = (tl & (kt - 1)) * 64, n0 = (tl / kt) * 64;
    int tid = threadIdx.x;
#pragma unroll
    for (int i = 0; i < 16; ++i) {
        int e = i * 256 + tid;
        int r = e >> 6, c = e & 63;
        tile[r][c] = src[(size_t)(k0 + r) * N + (n0 + c)];
    }
    __syncthreads();
#pragma unroll
    for (int i = 0; i < 16; ++i) {
        int e = i * 256 + tid;
        int r = e >> 6, c = e & 63;
        dst[(size_t)(n0 + r) * K + (k0 + c)] = f2bf(tile[c][r]);
    }
}

// ---------------------------------------------------------------------------
// LayerNorm: fp32 in -> bf16 out
// ---------------------------------------------------------------------------
__device__ __forceinline__ float block_sum256(float s) {
#pragma unroll
    for (int o = 32; o > 0; o >>= 1) s += __shfl_xor(s, o);
    __shared__ float partial[4];
    int w = threadIdx.x >> 6;
    __syncthreads();
    if ((threadIdx.x & 63) == 0) partial[w] = s;
    __syncthreads();
    return partial[0] + partial[1] + partial[2] + partial[3];
}

__global__ __launch_bounds__(256) void layernorm_bf16(
    const float* __restrict__ x, const float* __restrict__ g,
    const float* __restrict__ b, unsigned short* __restrict__ out, float eps) {
    size_t row = blockIdx.x;
    const float* xr = x + row * DDIM;
    int tid = threadIdx.x;
    float4 v = *(const float4*)(xr + tid * 4);
    float mu = block_sum256(v.x + v.y + v.z + v.w) * (1.0f / DDIM);
    float dx = v.x - mu, dy = v.y - mu, dz = v.z - mu, dw = v.w - mu;
    float var = block_sum256(dx * dx + dy * dy + dz * dz + dw * dw) * (1.0f / DDIM);
    float rstd = rsqrtf(var + eps);
    int c = tid * 4;
    unsigned short* o = out + row * DDIM + c;
    o[0] = f2bf(dx * rstd * g[c + 0] + b[c + 0]);
    o[1] = f2bf(dy * rstd * g[c + 1] + b[c + 1]);
    o[2] = f2bf(dz * rstd * g[c + 2] + b[c + 2]);
    o[3] = f2bf(dw * rstd * g[c + 3] + b[c + 3]);
}

// ---------------------------------------------------------------------------
// Double-buffered GEMM (r9 structure, kept for N=1024 outputs where 256^2
// tiling under-fills the grid): 128x128 tile, BK=32, one barrier per iter.
// ---------------------------------------------------------------------------
__global__ __launch_bounds__(256) void gemm_db(
    const unsigned short* __restrict__ A, const unsigned short* __restrict__ Bt,
    const float* __restrict__ bias, const float* __restrict__ resid,
    float* __restrict__ outf, unsigned short* __restrict__ outh,
    int M, int N, int K, int relu, int lda, int qcols) {
    __shared__ unsigned short As[2][128 * 32];
    __shared__ unsigned short Bs[2][128 * 32];
    int tid = threadIdx.x;
    int wave = tid >> 6, lane = tid & 63;
    int lr = lane & 15, quad = lane >> 4;
    int bid = blockIdx.x;
    int m0 = (bid & 63) * 128;         // M == 8192 -> 64 m-tiles
    int n0 = (bid >> 6) * 128;
    int wm = (wave >> 1) * 64, wn = (wave & 1) * 64;

    floatx4 acc[4][4];
#pragma unroll
    for (int i = 0; i < 4; ++i)
#pragma unroll
        for (int t = 0; t < 4; ++t)
#pragma unroll
            for (int r = 0; r < 4; ++r) acc[i][t][r] = 0.0f;

    int srow = tid >> 2;               // 0..63
    int scol = (tid & 3) * 8;
    const unsigned short* ag0 = A  + (size_t)(m0 + srow) * lda + scol;
    const unsigned short* ag1 = A  + (size_t)(m0 + srow + 64) * lda + scol;
    const unsigned short* bg0 = Bt + (size_t)(n0 + srow) * K + scol;
    const unsigned short* bg1 = Bt + (size_t)(n0 + srow + 64) * K + scol;
    int l0 = srow * 32 + scol;
    int l1 = (srow + 64) * 32 + scol;

    async_copy16(ag0, &As[0][l0]);
    async_copy16(ag1, &As[0][l1]);
    async_copy16(bg0, &Bs[0][l0]);
    async_copy16(bg1, &Bs[0][l1]);

    int cur = 0;
    for (int k0 = 0; k0 < K; k0 += 32) {
        __syncthreads();
        if (k0 + 32 < K) {
            int nb = cur ^ 1, kn = k0 + 32;
            async_copy16(ag0 + kn, &As[nb][l0]);
            async_copy16(ag1 + kn, &As[nb][l1]);
            async_copy16(bg0 + kn, &Bs[nb][l0]);
            async_copy16(bg1 + kn, &Bs[nb][l1]);
        }
        bf16x8 af[4], bfr[4];
#pragma unroll
        for (int i = 0; i < 4; ++i)
            af[i] = *(const bf16x8*)&As[cur][(wm + 16 * i + lr) * 32 + quad * 8];
#pragma unroll
        for (int t = 0; t < 4; ++t)
            bfr[t] = *(const bf16x8*)&Bs[cur][(wn + 16 * t + lr) * 32 + quad * 8];
#pragma unroll
        for (int i = 0; i < 4; ++i)
#pragma unroll
            for (int t = 0; t < 4; ++t)
                acc[i][t] = __builtin_amdgcn_mfma_f32_16x16x32_bf16(
                    af[i], bfr[t], acc[i][t], 0, 0, 0);
        cur ^= 1;
    }

#pragma unroll
    for (int i = 0; i < 4; ++i) {
#pragma unroll
        for (int t = 0; t < 4; ++t) {
            int col = n0 + wn + 16 * t + lr;
            float cs = (col < qcols) ? SCALE_Q : 1.0f;
#pragma unroll
            for (int r = 0; r < 4; ++r) {
                int row = m0 + wm + 16 * i + quad * 4 + r;
                float v = acc[i][t][r];
                if (bias)  v += bias[col];
                if (resid) v += resid[(size_t)row * N + col];
                if (relu)  v = fmaxf(v, 0.0f);
                v *= cs;
                size_t idx = (size_t)row * N + col;
                if (outf) outf[idx] = v;
                else      outh[idx] = f2bf(v);
            }
        }
    }
}

// ---------------------------------------------------------------------------
// 256x256 8-phase GEMM (m201 template: T2 st_16x32 LDS swizzle + T3/T4
// 8-phase counted-vmcnt pipeline + T5 setprio). 512 threads = 8 waves (2Mx4N),
// BK=64, 128 KiB LDS (2 bufs x (A 32KB + B 32KB)), 1 block/CU.
// (verified round 1: end-to-end -18.5us on QKV+fc1)
// ---------------------------------------------------------------------------
#define BAR8() asm volatile("s_barrier" ::: "memory")
#define WAIT_LGKM0() do { asm volatile("s_waitcnt lgkmcnt(0)" ::: "memory"); \
                          __builtin_amdgcn_sched_barrier(0); } while (0)

#define STAGE_A8(T, h) do { \
    const unsigned short* s_ = A + (size_t)(m0 + (h) * 128 + rowin) * lda + (T) * 64; \
    unsigned short* d_ = Asm + ((((T) & 1) << 14) + ((h) << 13) + sdst); \
    async_copy16(s_ + c0, d_); async_copy16(s_ + c1, d_ + 512); } while (0)

#define STAGE_B8(T, h) do { \
    const unsigned short* s_ = Bt + (size_t)(n0 + (h) * 128 + rowin) * (size_t)K + (T) * 64; \
    unsigned short* d_ = Bsm + ((((T) & 1) << 14) + ((h) << 13) + sdst); \
    async_copy16(s_ + c0, d_); async_copy16(s_ + c1, d_ + 512); } while (0)

#define READ_A4(P, ibase) \
    _Pragma("unroll") \
    for (int i = 0; i < 4; ++i) \
        _Pragma("unroll") \
        for (int kk = 0; kk < 2; ++kk) \
            a_f[i][kk] = *(const bf16x8*)&Asm[(P) + aoff + ((((ibase) + i) * 2 + kk) << 9)];

#define READ_B8(P) \
    _Pragma("unroll") \
    for (int t = 0; t < 4; ++t) \
        _Pragma("unroll") \
        for (int kk = 0; kk < 2; ++kk) \
            b_f[t][kk] = *(const bf16x8*)&Bsm[(P) + boff + ((t * 2 + kk) << 9)];

#define MFMA_Q(ilo, tlo) \
    _Pragma("unroll") \
    for (int i = 0; i < 4; ++i) \
        _Pragma("unroll") \
        for (int t = 0; t < 2; ++t) \
            _Pragma("unroll") \
            for (int kk = 0; kk < 2; ++kk) \
                acc[(ilo) + i][(tlo) + t] = __builtin_amdgcn_mfma_f32_16x16x32_bf16( \
                    a_f[i][kk], b_f[(tlo) + t][kk], acc[(ilo) + i][(tlo) + t], 0, 0, 0);

__global__ __launch_bounds__(512, 2) void gemm_8ph(
    const unsigned short* __restrict__ A, const unsigned short* __restrict__ Bt,
    const float* __restrict__ bias, unsigned short* __restrict__ outh,
    int M, int N, int K, int relu, int lda, int qcols) {
    // 2 bufs x (2 halves x 16 subtiles x 512 ushorts) = 32768 ushorts each
    __shared__ unsigned short Asm[32768];
    __shared__ unsigned short Bsm[32768];

    int tid = threadIdx.x;
    int w = tid >> 6, lane = tid & 63;
    int lr = lane & 15, quad = lane >> 4;

    // grid: requires gridDim.x % 8 == 0 and M == 8192 (32 m-tiles)
    int nwg = gridDim.x;
    int bid = blockIdx.x;
    int swz = (bid & 7) * (nwg >> 3) + (bid >> 3);   // XCD-contiguous
    int m0 = (swz & 31) << 8;
    int n0 = (swz >> 5) << 8;

    // staging geometry: wave w owns subtile-row w (rows w*16..w*16+15) of each
    // 128-row half-tile, both 32-col halves. Per-lane inverse-swizzled source.
    int rowin = (w << 4) + (lane >> 2);              // 0..127
    int q = (lane & 3) ^ ((lane >> 5) << 1);         // ^2 for lanes 32..63
    int c0 = q * 8, c1 = 32 + q * 8;                 // element col offsets
    int sdst = w << 10;                              // subtile 2w, ushort units

    // frag-read LDS offsets (ushort units); swizzled column
    int qsw8 = ((lane & 8) ? (quad ^ 2) : quad) * 8;
    int aoff = (w >> 2) * 8192 + lr * 32 + qsw8;                       // + (2i+kk)<<9
    int boff = ((w & 3) >> 1) * 8192 + ((w & 3) & 1) * 4096 + lr * 32 + qsw8;
    int wm = (w >> 2) * 128, wn = (w & 3) * 64;

    floatx4 acc[8][4];
#pragma unroll
    for (int i = 0; i < 8; ++i)
#pragma unroll
        for (int t = 0; t < 4; ++t)
#pragma unroll
            for (int r = 0; r < 4; ++r) acc[i][t][r] = 0.0f;

    int NT = K >> 6;   // assumed even, >= 2 (K = 1024 here)

    // prologue: 7 half-tiles = slots [t0.B0,t0.B1,t0.A0,t0.A1,t1.B0,t1.B1,t1.A0]
    STAGE_B8(0, 0); STAGE_B8(0, 1); STAGE_A8(0, 0); STAGE_A8(0, 1);
    STAGE_B8(1, 0); STAGE_B8(1, 1); STAGE_A8(1, 0);
    asm volatile("s_waitcnt vmcnt(4)" ::: "memory");   // tile 0 fully resident
    BAR8();

    bf16x8 a_f[4][2], b_f[4][2];

    for (int T = 0; T < NT; T += 2) {
        // ================= tile T (buf 0) =================
        // ---- phase 1: read A m0-3 + B all; stage (T+1).A1; MFMA Q00
        READ_A4(0, 0);
        READ_B8(0);
        if (T + 1 < NT) STAGE_A8(T + 1, 1);
        BAR8(); WAIT_LGKM0();
        __builtin_amdgcn_s_setprio(1); MFMA_Q(0, 0); __builtin_amdgcn_s_setprio(0);
        BAR8();
        // ---- phase 2: stage (T+2).B0; MFMA Q01
        if (T + 2 < NT) STAGE_B8(T + 2, 0);
        BAR8();
        __builtin_amdgcn_s_setprio(1); MFMA_Q(0, 2); __builtin_amdgcn_s_setprio(0);
        BAR8();
        // ---- phase 3: read A m4-7; stage (T+2).B1; MFMA Q10
        READ_A4(0, 4);
        if (T + 2 < NT) STAGE_B8(T + 2, 1);
        BAR8(); WAIT_LGKM0();
        __builtin_amdgcn_s_setprio(1); MFMA_Q(4, 0); __builtin_amdgcn_s_setprio(0);
        BAR8();
        // ---- phase 4: stage (T+2).A0; MFMA Q11; counted vmcnt
        if (T + 2 < NT) STAGE_A8(T + 2, 0);
        BAR8();
        __builtin_amdgcn_s_setprio(1); MFMA_Q(4, 2); __builtin_amdgcn_s_setprio(0);
        if (T + 2 < NT) { asm volatile("s_waitcnt vmcnt(6)" ::: "memory"); }
        else            { asm volatile("s_waitcnt vmcnt(0)" ::: "memory"); }
        BAR8();

        // ================= tile T+1 (buf 1) =================
        // ---- phase 5
        READ_A4(16384, 0);
        READ_B8(16384);
        if (T + 2 < NT) STAGE_A8(T + 2, 1);
        BAR8(); WAIT_LGKM0();
        __builtin_amdgcn_s_setprio(1); MFMA_Q(0, 0); __builtin_amdgcn_s_setprio(0);
        BAR8();
        // ---- phase 6
        if (T + 3 < NT) STAGE_B8(T + 3, 0);
        BAR8();
        __builtin_amdgcn_s_setprio(1); MFMA_Q(0, 2); __builtin_amdgcn_s_setprio(0);
        BAR8();
        // ---- phase 7
        READ_A4(16384, 4);
        if (T + 3 < NT) STAGE_B8(T + 3, 1);
        BAR8(); WAIT_LGKM0();
        __builtin_amdgcn_s_setprio(1); MFMA_Q(4, 0); __builtin_amdgcn_s_setprio(0);
        BAR8();
        // ---- phase 8
        if (T + 3 < NT) STAGE_A8(T + 3, 0);
        BAR8();
        __builtin_amdgcn_s_setprio(1); MFMA_Q(4, 2); __builtin_amdgcn_s_setprio(0);
        if (T + 3 < NT) { asm volatile("s_waitcnt vmcnt(6)" ::: "memory"); }
        else            { asm volatile("s_waitcnt vmcnt(0)" ::: "memory"); }
        BAR8();
    }

    // epilogue
#pragma unroll
    for (int i = 0; i < 8; ++i) {
#pragma unroll
        for (int t = 0; t < 4; ++t) {
            int col = n0 + wn + 16 * t + lr;
            float cs = (col < qcols) ? SCALE_Q : 1.0f;
            float bv = bias ? bias[col] : 0.0f;
#pragma unroll
            for (int r = 0; r < 4; ++r) {
                int row = m0 + wm + 16 * i + quad * 4 + r;
                float v = acc[i][t][r] + bv;
                if (relu) v = fmaxf(v, 0.0f);
                outh[(size_t)row * N + col] = f2bf(v * cs);
            }
        }
    }
}

// ---------------------------------------------------------------------------
// V transpose: vsrc rows (stride QKVS) -> vt[bh][dk][s'] with per-64-block
// permutation sigma(u) = 4*(u&15) + (u>>4)  (matches attention P-writes).
// ---------------------------------------------------------------------------
__global__ __launch_bounds__(256) void transpose_v(
    const unsigned short* __restrict__ vsrc, unsigned short* __restrict__ vt) {
    int bh = blockIdx.y;
    int b = bh >> 4, h = bh & 15;
    int s = blockIdx.x * 256 + threadIdx.x;
    size_t inbase = ((size_t)(b * SS + s)) * QKVS + h * 64;
    size_t outbase = (size_t)bh * 64 * SS;
    int sp = (s & ~63) + 4 * (s & 15) + ((s >> 4) & 3);
#pragma unroll
    for (int dk8 = 0; dk8 < 8; ++dk8) {
        uint4 raw = *(const uint4*)(vsrc + inbase + dk8 * 8);
        const unsigned short* ph = (const unsigned short*)&raw;
#pragma unroll
        for (int i = 0; i < 8; ++i)
            vt[outbase + (size_t)(dk8 * 8 + i) * SS + sp] = ph[i];
    }
}

// ---------------------------------------------------------------------------
// Flash attention v8 = v7 structure with FULL-GRID RESIDENCY:
// launch_bounds(256,4). Counters at (256,2): Occupancy 21%, MfmaUtil 19%,
// VALUBusy 47%, HBM 4.8% -> latency-bound at 2 blocks/CU. VGPR=124<=128 and
// LDS=34816*4=136KB<=160KB both fit 4 blocks/CU; grid is exactly 1024 = 4/CU,
// so min-waves=4 makes the whole grid co-resident (4 independent blocks/CU
// interleave MFMA/TRANS/VMEM phases).
// ctx is written into the dead V-columns of the qkv buffer (stride QKVS).
// ---------------------------------------------------------------------------
#define PST 68    // Ps row stride (bf16)

__global__ __launch_bounds__(256, 4) void attention_mfma7(
    const unsigned short* __restrict__ qkv, const unsigned short* __restrict__ vt,
    unsigned short* __restrict__ ctx /* = qkv + 2048, stride QKVS */) {
    __shared__ unsigned short Ps[256 * PST];   // 34816 B; reused by epilogue

    int tid = threadIdx.x;
    int wave = tid >> 6, lane = tid & 63;
    int lr = lane & 15, quad = lane >> 4;
    int wq = wave >> 1, wj = wave & 1;

    int bid = blockIdx.x;
    int bh = bid & 63;                 // same bh -> same XCD
    int qt = bid >> 6;
    int b = bh >> 4, h = bh & 15;
    int q0 = qt * 128;
    size_t q_base = ((size_t)b * SS) * QKVS + h * 64;
    size_t k_base = q_base + 1024;
    size_t vt_base = (size_t)bh * 64 * SS;

    // preload Q A-frags (Q already carries SCALE_Q)
    uint4 af[4][2];
#pragma unroll
    for (int i = 0; i < 4; ++i)
#pragma unroll
        for (int kk = 0; kk < 2; ++kk)
            af[i][kk] = *(const uint4*)(qkv + q_base +
                (size_t)(q0 + 64 * wq + 16 * i + lr) * QKVS + kk * 32 + quad * 8);

    floatx4 o[4][4];
    float l[4][4];
#pragma unroll
    for (int i = 0; i < 4; ++i)
#pragma unroll
        for (int t = 0; t < 4; ++t) {
#pragma unroll
            for (int r = 0; r < 4; ++r) o[i][t][r] = 0.0f;
            l[i][t] = 0.0f;
        }
    floatx4 zf;
#pragma unroll
    for (int r = 0; r < 4; ++r) zf[r] = 0.0f;

    unsigned short* myPs = &Ps[wave * 64 * PST];

    for (int jt = 0; jt < SS / 128; ++jt) {
        int j0 = jt * 128 + 64 * wj;

        // S = Q K^T : kk=0 writes (zero C), kk=1 accumulates
        floatx4 s[4][4];
        {
            uint4 bv[4];
#pragma unroll
            for (int t = 0; t < 4; ++t)
                bv[t] = *(const uint4*)(qkv + k_base +
                    (size_t)(j0 + 16 * t + lr) * QKVS + quad * 8);
#pragma unroll
            for (int i = 0; i < 4; ++i)
#pragma unroll
                for (int t = 0; t < 4; ++t)
                    s[i][t] = __builtin_amdgcn_mfma_f32_16x16x32_bf16(
                        as_frag(af[i][0]), as_frag(bv[t]), zf, 0, 0, 0);
        }
        {
            uint4 bv[4];
#pragma unroll
            for (int t = 0; t < 4; ++t)
                bv[t] = *(const uint4*)(qkv + k_base +
                    (size_t)(j0 + 16 * t + lr) * QKVS + 32 + quad * 8);
#pragma unroll
            for (int i = 0; i < 4; ++i)
#pragma unroll
                for (int t = 0; t < 4; ++t)
                    s[i][t] = __builtin_amdgcn_mfma_f32_16x16x32_bf16(
                        as_frag(af[i][1]), as_frag(bv[t]), s[i][t], 0, 0, 0);
        }

        // softmax-lite: p = exp2(s) directly; wave-private P write
#pragma unroll
        for (int i = 0; i < 4; ++i) {
#pragma unroll
            for (int r = 0; r < 4; ++r) {
                float p0 = exp2f(s[i][0][r]);
                float p1 = exp2f(s[i][1][r]);
                float p2 = exp2f(s[i][2][r]);
                float p3 = exp2f(s[i][3][r]);
                l[i][r] += (p0 + p1) + (p2 + p3);
                uint2 w;
                w.x = pack_bf_trunc(p0, p1);
                w.y = pack_bf_trunc(p2, p3);
                *(uint2*)&myPs[(16 * i + quad * 4 + r) * PST + 4 * lr] = w;
            }
        }

        // O += P @ V-half
#pragma unroll
        for (int kk = 0; kk < 2; ++kk) {
            uint4 vv[4];
#pragma unroll
            for (int t = 0; t < 4; ++t)
                vv[t] = *(const uint4*)(vt + vt_base +
                    (size_t)(16 * t + lr) * SS + j0 + kk * 32 + quad * 8);
            bf16x8 pf[4];
#pragma unroll
            for (int i = 0; i < 4; ++i)
                pf[i] = *(const bf16x8*)&myPs[(16 * i + lr) * PST + kk * 32 + quad * 8];
#pragma unroll
            for (int i = 0; i < 4; ++i)
#pragma unroll
                for (int t = 0; t < 4; ++t)
                    o[i][t] = __builtin_amdgcn_mfma_f32_16x16x32_bf16(
                        pf[i], as_frag(vv[t]), o[i][t], 0, 0, 0);
        }
    }

    // reduce l partials across the 16 lanes of each row
#pragma unroll
    for (int i = 0; i < 4; ++i)
#pragma unroll
        for (int r = 0; r < 4; ++r) {
            float ls = l[i][r];
            ls += __shfl_xor(ls, 1);
            ls += __shfl_xor(ls, 2);
            ls += __shfl_xor(ls, 4);
            ls += __shfl_xor(ls, 8);
            l[i][r] = ls;
        }

    // merge j-halves: wj==1 dumps partial O,l to LDS; wj==0 combines+stores
    __syncthreads();
    float* obuf = (float*)Ps;             // [2][64][65] floats
    float* lbuf = obuf + 2 * 64 * 65;     // [2][64] floats
    if (wj == 1) {
#pragma unroll
        for (int i = 0; i < 4; ++i)
#pragma unroll
            for (int r = 0; r < 4; ++r) {
                int rl = 16 * i + quad * 4 + r;
#pragma unroll
                for (int t = 0; t < 4; ++t)
                    obuf[(wq * 64 + rl) * 65 + 16 * t + lr] = o[i][t][r];
                if (lr == 0) lbuf[wq * 64 + rl] = l[i][r];
            }
    }
    __syncthreads();
    if (wj == 0) {
#pragma unroll
        for (int i = 0; i < 4; ++i)
#pragma unroll
            for (int r = 0; r < 4; ++r) {
                int rl = 16 * i + quad * 4 + r;
                float inv = 1.0f / (l[i][r] + lbuf[wq * 64 + rl]);
                int row = q0 + 64 * wq + rl;
                size_t base = ((size_t)(b * SS + row)) * QKVS + h * 64;
#pragma unroll
                for (int t = 0; t < 4; ++t)
                    ctx[base + 16 * t + lr] =
                        f2bf((o[i][t][r] + obuf[(wq * 64 + rl) * 65 + 16 * t + lr]) * inv);
            }
    }
}

// ---------------------------------------------------------------------------
extern "C" void kernel_launch(void* const* d_in, const int* in_sizes, int n_in,
                              void* d_out, int out_size, void* d_ws, size_t ws_size,
                              hipStream_t stream) {
    const float* x     = (const float*)d_in[0];
    const float* Wq    = (const float*)d_in[1];
    const float* Wk    = (const float*)d_in[2];
    const float* Wv    = (const float*)d_in[3];
    const float* Wo    = (const float*)d_in[4];
    const float* ln1g  = (const float*)d_in[5];
    const float* ln1b  = (const float*)d_in[6];
    const float* fc1w  = (const float*)d_in[7];
    const float* fc1b  = (const float*)d_in[8];
    const float* fc2w  = (const float*)d_in[9];
    const float* fc2b  = (const float*)d_in[10];
    const float* ln2g  = (const float*)d_in[11];
    const float* ln2b  = (const float*)d_in[12];
    float* out = (float*)d_out;

    // workspace (peak 80MB):
    //  0..16 : weights (wqkvT@0 [3072x1024] 6MB, woT@6, fc1T@8, fc2T@12)
    // 16..32 : xn -> vt (after QKV GEMM) -> hn (after attention)
    // 32..80 : qkvb [8192][3072] 48MB; ctx lives in its V-cols (2048..3071)
    //          after transpose_v consumes them; h1 [8192][2048] overlays
    //          bytes 32..64MB once ctx is dead (after Wo GEMM).
    char* ws = (char*)d_ws;
    const size_t MB = 1024 * 1024;
    unsigned short* wqkvT = (unsigned short*)(ws + 0 * MB);
    unsigned short* woT   = (unsigned short*)(ws + 6 * MB);
    unsigned short* fc1T  = (unsigned short*)(ws + 8 * MB);
    unsigned short* fc2T  = (unsigned short*)(ws + 12 * MB);
    unsigned short* xn    = (unsigned short*)(ws + 16 * MB);
    unsigned short* vt    = xn;
    unsigned short* hn    = xn;
    unsigned short* qkvb  = (unsigned short*)(ws + 32 * MB);
    unsigned short* ctx   = qkvb + 2048;        // V-cols, stride QKVS
    unsigned short* h1    = qkvb;               // reuse after ctx dead

    dim3 blk(256);

    transpose_all<<<2048, blk, 0, stream>>>(Wq, Wk, Wv, Wo, fc1w, fc2w,
                                            wqkvT, woT, fc1T, fc2T);

    layernorm_bf16<<<NTOK, blk, 0, stream>>>(x, ln1g, ln1b, xn, 1e-5f);

    // fused QKV projection on the 8-phase 256^2 template:
    // 32 m-tiles x 12 n-tiles = 384 blocks (%8==0); Q cols pre-scaled
    gemm_8ph<<<384, 512, 0, stream>>>(xn, wqkvT, nullptr, qkvb,
                                      NTOK, QKVS, 1024, 0, 1024, 1024);
    transpose_v<<<dim3(8, 64), blk, 0, stream>>>(qkvb + 2048, vt);  // vt over xn

    attention_mfma7<<<1024, blk, 0, stream>>>(qkvb, vt, ctx);

    // Wo GEMM reads ctx (stride QKVS) -> fp32 out with residual x
    // (N=1024 -> 256^2 grid would be 128 blocks = half GPU; keep 128^2 db)
    gemm_db<<<512, blk, 0, stream>>>(ctx, woT, nullptr, x, out, nullptr,
                                     NTOK, 1024, 1024, 0, QKVS, 0);
    layernorm_bf16<<<NTOK, blk, 0, stream>>>(out, ln2g, ln2b, hn, 1e-6f);
    // fc1 on the 8-phase template: 32 x 8 = 256 blocks
    gemm_8ph<<<256, 512, 0, stream>>>(hn, fc1T, fc1b, h1,
                                      NTOK, 2048, 1024, 1, 1024, 0);
    gemm_db<<<512, blk, 0, stream>>>(h1, fc2T, fc2b, out, out, nullptr,
                                     NTOK, 1024, 2048, 0, 2048, 0);
}

// Round 3
// 774.344 us; speedup vs baseline: 1.1045x; 1.1045x over previous
//
#include <hip/hip_runtime.h>

// Problem constants
#define BB   4
#define SS   2048
#define DDIM 1024
#define HH   16
#define DKK  64
#define FFF  2048
#define NTOK (BB * SS)   // 8192
#define QKVS 3072        // fused qkv row stride
#define SCALE_Q 0.18033688011112042f   // 0.125 * log2(e), folded into Q

typedef __bf16 bf16x8 __attribute__((ext_vector_type(8)));
typedef float floatx4 __attribute__((ext_vector_type(4)));

__device__ __forceinline__ unsigned short f2bf(float f) {
    union { float f; unsigned u; } v; v.f = f;
    unsigned r = v.u + 0x7fffu + ((v.u >> 16) & 1u);   // RNE
    return (unsigned short)(r >> 16);
}

// pack hi16(a),hi16(b) -> one u32 (bf16 truncation x2 in one v_perm)
__device__ __forceinline__ unsigned pack_bf_trunc(float a, float b) {
    union { float f; unsigned u; } x, y; x.f = a; y.f = b;
    return __builtin_amdgcn_perm(y.u, x.u, 0x07060302u);
}

__device__ __forceinline__ bf16x8 as_frag(uint4 v) {
    union { uint4 u; bf16x8 f; } c; c.u = v; return c.f;
}

__device__ __forceinline__ void async_copy16(const unsigned short* g, unsigned short* l) {
    __builtin_amdgcn_global_load_lds(
        (const __attribute__((address_space(1))) void*)g,
        (__attribute__((address_space(3))) void*)l, 16, 0, 0);
}

// ---------------------------------------------------------------------------
// All six weight transposes fused: fp32 W[K][N] -> bf16 Wt[N][K], 64x64 tiles
// Wq/Wk/Wv land in one contiguous wqkvT [3072][1024].
// ---------------------------------------------------------------------------
__global__ __launch_bounds__(256) void transpose_all(
    const float* __restrict__ Wq, const float* __restrict__ Wk,
    const float* __restrict__ Wv, const float* __restrict__ Wo,
    const float* __restrict__ fc1, const float* __restrict__ fc2,
    unsigned short* __restrict__ wqkvT, unsigned short* __restrict__ woT,
    unsigned short* __restrict__ fc1T, unsigned short* __restrict__ fc2T) {
    __shared__ float tile[64][65];
    int t = blockIdx.x;
    const float* src; unsigned short* dst; int K, N, tl;
    if (t < 256)       { src = Wq;  dst = wqkvT;                       K = 1024; N = 1024; tl = t; }
    else if (t < 512)  { src = Wk;  dst = wqkvT + (size_t)1024 * 1024; K = 1024; N = 1024; tl = t - 256; }
    else if (t < 768)  { src = Wv;  dst = wqkvT + (size_t)2048 * 1024; K = 1024; N = 1024; tl = t - 512; }
    else if (t < 1024) { src = Wo;  dst = woT;                         K = 1024; N = 1024; tl = t - 768; }
    else if (t < 1536) { src = fc1; dst = fc1T;                        K = 1024; N = 2048; tl = t - 1024; }
    else               { src = fc2; dst = fc2T;                        K = 2048; N = 1024; tl = t - 1536; }
    int kt = K >> 6;
    int k0 = (tl & (kt - 1)) * 64, n0 = (tl / kt) * 64;
    int tid = threadIdx.x;
#pragma unroll
    for (int i = 0; i < 16; ++i) {
        int e = i * 256 + tid;
        int r = e >> 6, c = e & 63;
        tile[r][c] = src[(size_t)(k0 + r) * N + (n0 + c)];
    }
    __syncthreads();
#pragma unroll
    for (int i = 0; i < 16; ++i) {
        int e = i * 256 + tid;
        int r = e >> 6, c = e & 63;
        dst[(size_t)(n0 + r) * K + (k0 + c)] = f2bf(tile[c][r]);
    }
}

// ---------------------------------------------------------------------------
// LayerNorm: fp32 in -> bf16 out
// ---------------------------------------------------------------------------
__device__ __forceinline__ float block_sum256(float s) {
#pragma unroll
    for (int o = 32; o > 0; o >>= 1) s += __shfl_xor(s, o);
    __shared__ float partial[4];
    int w = threadIdx.x >> 6;
    __syncthreads();
    if ((threadIdx.x & 63) == 0) partial[w] = s;
    __syncthreads();
    return partial[0] + partial[1] + partial[2] + partial[3];
}

__global__ __launch_bounds__(256) void layernorm_bf16(
    const float* __restrict__ x, const float* __restrict__ g,
    const float* __restrict__ b, unsigned short* __restrict__ out, float eps) {
    size_t row = blockIdx.x;
    const float* xr = x + row * DDIM;
    int tid = threadIdx.x;
    float4 v = *(const float4*)(xr + tid * 4);
    float mu = block_sum256(v.x + v.y + v.z + v.w) * (1.0f / DDIM);
    float dx = v.x - mu, dy = v.y - mu, dz = v.z - mu, dw = v.w - mu;
    float var = block_sum256(dx * dx + dy * dy + dz * dz + dw * dw) * (1.0f / DDIM);
    float rstd = rsqrtf(var + eps);
    int c = tid * 4;
    unsigned short* o = out + row * DDIM + c;
    o[0] = f2bf(dx * rstd * g[c + 0] + b[c + 0]);
    o[1] = f2bf(dy * rstd * g[c + 1] + b[c + 1]);
    o[2] = f2bf(dz * rstd * g[c + 2] + b[c + 2]);
    o[3] = f2bf(dw * rstd * g[c + 3] + b[c + 3]);
}

// ---------------------------------------------------------------------------
// Double-buffered GEMM (r9 structure, kept for N=1024 outputs where 256^2
// tiling under-fills the grid): 128x128 tile, BK=32, one barrier per iter.
// ---------------------------------------------------------------------------
__global__ __launch_bounds__(256) void gemm_db(
    const unsigned short* __restrict__ A, const unsigned short* __restrict__ Bt,
    const float* __restrict__ bias, const float* __restrict__ resid,
    float* __restrict__ outf, unsigned short* __restrict__ outh,
    int M, int N, int K, int relu, int lda, int qcols) {
    __shared__ unsigned short As[2][128 * 32];
    __shared__ unsigned short Bs[2][128 * 32];
    int tid = threadIdx.x;
    int wave = tid >> 6, lane = tid & 63;
    int lr = lane & 15, quad = lane >> 4;
    int bid = blockIdx.x;
    int m0 = (bid & 63) * 128;         // M == 8192 -> 64 m-tiles
    int n0 = (bid >> 6) * 128;
    int wm = (wave >> 1) * 64, wn = (wave & 1) * 64;

    floatx4 acc[4][4];
#pragma unroll
    for (int i = 0; i < 4; ++i)
#pragma unroll
        for (int t = 0; t < 4; ++t)
#pragma unroll
            for (int r = 0; r < 4; ++r) acc[i][t][r] = 0.0f;

    int srow = tid >> 2;               // 0..63
    int scol = (tid & 3) * 8;
    const unsigned short* ag0 = A  + (size_t)(m0 + srow) * lda + scol;
    const unsigned short* ag1 = A  + (size_t)(m0 + srow + 64) * lda + scol;
    const unsigned short* bg0 = Bt + (size_t)(n0 + srow) * K + scol;
    const unsigned short* bg1 = Bt + (size_t)(n0 + srow + 64) * K + scol;
    int l0 = srow * 32 + scol;
    int l1 = (srow + 64) * 32 + scol;

    async_copy16(ag0, &As[0][l0]);
    async_copy16(ag1, &As[0][l1]);
    async_copy16(bg0, &Bs[0][l0]);
    async_copy16(bg1, &Bs[0][l1]);

    int cur = 0;
    for (int k0 = 0; k0 < K; k0 += 32) {
        __syncthreads();
        if (k0 + 32 < K) {
            int nb = cur ^ 1, kn = k0 + 32;
            async_copy16(ag0 + kn, &As[nb][l0]);
            async_copy16(ag1 + kn, &As[nb][l1]);
            async_copy16(bg0 + kn, &Bs[nb][l0]);
            async_copy16(bg1 + kn, &Bs[nb][l1]);
        }
        bf16x8 af[4], bfr[4];
#pragma unroll
        for (int i = 0; i < 4; ++i)
            af[i] = *(const bf16x8*)&As[cur][(wm + 16 * i + lr) * 32 + quad * 8];
#pragma unroll
        for (int t = 0; t < 4; ++t)
            bfr[t] = *(const bf16x8*)&Bs[cur][(wn + 16 * t + lr) * 32 + quad * 8];
#pragma unroll
        for (int i = 0; i < 4; ++i)
#pragma unroll
            for (int t = 0; t < 4; ++t)
                acc[i][t] = __builtin_amdgcn_mfma_f32_16x16x32_bf16(
                    af[i], bfr[t], acc[i][t], 0, 0, 0);
        cur ^= 1;
    }

#pragma unroll
    for (int i = 0; i < 4; ++i) {
#pragma unroll
        for (int t = 0; t < 4; ++t) {
            int col = n0 + wn + 16 * t + lr;
            float cs = (col < qcols) ? SCALE_Q : 1.0f;
#pragma unroll
            for (int r = 0; r < 4; ++r) {
                int row = m0 + wm + 16 * i + quad * 4 + r;
                float v = acc[i][t][r];
                if (bias)  v += bias[col];
                if (resid) v += resid[(size_t)row * N + col];
                if (relu)  v = fmaxf(v, 0.0f);
                v *= cs;
                size_t idx = (size_t)row * N + col;
                if (outf) outf[idx] = v;
                else      outh[idx] = f2bf(v);
            }
        }
    }
}

// ---------------------------------------------------------------------------
// 256x256 8-phase GEMM (m201 template: T2 st_16x32 LDS swizzle + T3/T4
// 8-phase counted-vmcnt pipeline + T5 setprio). 512 threads = 8 waves (2Mx4N),
// BK=64, 128 KiB LDS (2 bufs x (A 32KB + B 32KB)), 1 block/CU.
// (verified round 1: end-to-end -18.5us on QKV+fc1)
// ---------------------------------------------------------------------------
#define BAR8() asm volatile("s_barrier" ::: "memory")
#define WAIT_LGKM0() do { asm volatile("s_waitcnt lgkmcnt(0)" ::: "memory"); \
                          __builtin_amdgcn_sched_barrier(0); } while (0)

#define STAGE_A8(T, h) do { \
    const unsigned short* s_ = A + (size_t)(m0 + (h) * 128 + rowin) * lda + (T) * 64; \
    unsigned short* d_ = Asm + ((((T) & 1) << 14) + ((h) << 13) + sdst); \
    async_copy16(s_ + c0, d_); async_copy16(s_ + c1, d_ + 512); } while (0)

#define STAGE_B8(T, h) do { \
    const unsigned short* s_ = Bt + (size_t)(n0 + (h) * 128 + rowin) * (size_t)K + (T) * 64; \
    unsigned short* d_ = Bsm + ((((T) & 1) << 14) + ((h) << 13) + sdst); \
    async_copy16(s_ + c0, d_); async_copy16(s_ + c1, d_ + 512); } while (0)

#define READ_A4(P, ibase) \
    _Pragma("unroll") \
    for (int i = 0; i < 4; ++i) \
        _Pragma("unroll") \
        for (int kk = 0; kk < 2; ++kk) \
            a_f[i][kk] = *(const bf16x8*)&Asm[(P) + aoff + ((((ibase) + i) * 2 + kk) << 9)];

#define READ_B8(P) \
    _Pragma("unroll") \
    for (int t = 0; t < 4; ++t) \
        _Pragma("unroll") \
        for (int kk = 0; kk < 2; ++kk) \
            b_f[t][kk] = *(const bf16x8*)&Bsm[(P) + boff + ((t * 2 + kk) << 9)];

#define MFMA_Q(ilo, tlo) \
    _Pragma("unroll") \
    for (int i = 0; i < 4; ++i) \
        _Pragma("unroll") \
        for (int t = 0; t < 2; ++t) \
            _Pragma("unroll") \
            for (int kk = 0; kk < 2; ++kk) \
                acc[(ilo) + i][(tlo) + t] = __builtin_amdgcn_mfma_f32_16x16x32_bf16( \
                    a_f[i][kk], b_f[(tlo) + t][kk], acc[(ilo) + i][(tlo) + t], 0, 0, 0);

__global__ __launch_bounds__(512, 2) void gemm_8ph(
    const unsigned short* __restrict__ A, const unsigned short* __restrict__ Bt,
    const float* __restrict__ bias, unsigned short* __restrict__ outh,
    int M, int N, int K, int relu, int lda, int qcols) {
    // 2 bufs x (2 halves x 16 subtiles x 512 ushorts) = 32768 ushorts each
    __shared__ unsigned short Asm[32768];
    __shared__ unsigned short Bsm[32768];

    int tid = threadIdx.x;
    int w = tid >> 6, lane = tid & 63;
    int lr = lane & 15, quad = lane >> 4;

    // grid: requires gridDim.x % 8 == 0 and M == 8192 (32 m-tiles)
    int nwg = gridDim.x;
    int bid = blockIdx.x;
    int swz = (bid & 7) * (nwg >> 3) + (bid >> 3);   // XCD-contiguous
    int m0 = (swz & 31) << 8;
    int n0 = (swz >> 5) << 8;

    // staging geometry: wave w owns subtile-row w (rows w*16..w*16+15) of each
    // 128-row half-tile, both 32-col halves. Per-lane inverse-swizzled source.
    int rowin = (w << 4) + (lane >> 2);              // 0..127
    int q = (lane & 3) ^ ((lane >> 5) << 1);         // ^2 for lanes 32..63
    int c0 = q * 8, c1 = 32 + q * 8;                 // element col offsets
    int sdst = w << 10;                              // subtile 2w, ushort units

    // frag-read LDS offsets (ushort units); swizzled column
    int qsw8 = ((lane & 8) ? (quad ^ 2) : quad) * 8;
    int aoff = (w >> 2) * 8192 + lr * 32 + qsw8;                       // + (2i+kk)<<9
    int boff = ((w & 3) >> 1) * 8192 + ((w & 3) & 1) * 4096 + lr * 32 + qsw8;
    int wm = (w >> 2) * 128, wn = (w & 3) * 64;

    floatx4 acc[8][4];
#pragma unroll
    for (int i = 0; i < 8; ++i)
#pragma unroll
        for (int t = 0; t < 4; ++t)
#pragma unroll
            for (int r = 0; r < 4; ++r) acc[i][t][r] = 0.0f;

    int NT = K >> 6;   // assumed even, >= 2 (K = 1024 here)

    // prologue: 7 half-tiles = slots [t0.B0,t0.B1,t0.A0,t0.A1,t1.B0,t1.B1,t1.A0]
    STAGE_B8(0, 0); STAGE_B8(0, 1); STAGE_A8(0, 0); STAGE_A8(0, 1);
    STAGE_B8(1, 0); STAGE_B8(1, 1); STAGE_A8(1, 0);
    asm volatile("s_waitcnt vmcnt(4)" ::: "memory");   // tile 0 fully resident
    BAR8();

    bf16x8 a_f[4][2], b_f[4][2];

    for (int T = 0; T < NT; T += 2) {
        // ================= tile T (buf 0) =================
        // ---- phase 1: read A m0-3 + B all; stage (T+1).A1; MFMA Q00
        READ_A4(0, 0);
        READ_B8(0);
        if (T + 1 < NT) STAGE_A8(T + 1, 1);
        BAR8(); WAIT_LGKM0();
        __builtin_amdgcn_s_setprio(1); MFMA_Q(0, 0); __builtin_amdgcn_s_setprio(0);
        BAR8();
        // ---- phase 2: stage (T+2).B0; MFMA Q01
        if (T + 2 < NT) STAGE_B8(T + 2, 0);
        BAR8();
        __builtin_amdgcn_s_setprio(1); MFMA_Q(0, 2); __builtin_amdgcn_s_setprio(0);
        BAR8();
        // ---- phase 3: read A m4-7; stage (T+2).B1; MFMA Q10
        READ_A4(0, 4);
        if (T + 2 < NT) STAGE_B8(T + 2, 1);
        BAR8(); WAIT_LGKM0();
        __builtin_amdgcn_s_setprio(1); MFMA_Q(4, 0); __builtin_amdgcn_s_setprio(0);
        BAR8();
        // ---- phase 4: stage (T+2).A0; MFMA Q11; counted vmcnt
        if (T + 2 < NT) STAGE_A8(T + 2, 0);
        BAR8();
        __builtin_amdgcn_s_setprio(1); MFMA_Q(4, 2); __builtin_amdgcn_s_setprio(0);
        if (T + 2 < NT) { asm volatile("s_waitcnt vmcnt(6)" ::: "memory"); }
        else            { asm volatile("s_waitcnt vmcnt(0)" ::: "memory"); }
        BAR8();

        // ================= tile T+1 (buf 1) =================
        // ---- phase 5
        READ_A4(16384, 0);
        READ_B8(16384);
        if (T + 2 < NT) STAGE_A8(T + 2, 1);
        BAR8(); WAIT_LGKM0();
        __builtin_amdgcn_s_setprio(1); MFMA_Q(0, 0); __builtin_amdgcn_s_setprio(0);
        BAR8();
        // ---- phase 6
        if (T + 3 < NT) STAGE_B8(T + 3, 0);
        BAR8();
        __builtin_amdgcn_s_setprio(1); MFMA_Q(0, 2); __builtin_amdgcn_s_setprio(0);
        BAR8();
        // ---- phase 7
        READ_A4(16384, 4);
        if (T + 3 < NT) STAGE_B8(T + 3, 1);
        BAR8(); WAIT_LGKM0();
        __builtin_amdgcn_s_setprio(1); MFMA_Q(4, 0); __builtin_amdgcn_s_setprio(0);
        BAR8();
        // ---- phase 8
        if (T + 3 < NT) STAGE_A8(T + 3, 0);
        BAR8();
        __builtin_amdgcn_s_setprio(1); MFMA_Q(4, 2); __builtin_amdgcn_s_setprio(0);
        if (T + 3 < NT) { asm volatile("s_waitcnt vmcnt(6)" ::: "memory"); }
        else            { asm volatile("s_waitcnt vmcnt(0)" ::: "memory"); }
        BAR8();
    }

    // epilogue
#pragma unroll
    for (int i = 0; i < 8; ++i) {
#pragma unroll
        for (int t = 0; t < 4; ++t) {
            int col = n0 + wn + 16 * t + lr;
            float cs = (col < qcols) ? SCALE_Q : 1.0f;
            float bv = bias ? bias[col] : 0.0f;
#pragma unroll
            for (int r = 0; r < 4; ++r) {
                int row = m0 + wm + 16 * i + quad * 4 + r;
                float v = acc[i][t][r] + bv;
                if (relu) v = fmaxf(v, 0.0f);
                outh[(size_t)row * N + col] = f2bf(v * cs);
            }
        }
    }
}

// ---------------------------------------------------------------------------
// V transpose: vsrc rows (stride QKVS) -> vt[bh][dk][s'] with per-64-block
// permutation sigma(u) = 4*(u&15) + (u>>4)  (matches attention P-writes).
// ---------------------------------------------------------------------------
__global__ __launch_bounds__(256) void transpose_v(
    const unsigned short* __restrict__ vsrc, unsigned short* __restrict__ vt) {
    int bh = blockIdx.y;
    int b = bh >> 4, h = bh & 15;
    int s = blockIdx.x * 256 + threadIdx.x;
    size_t inbase = ((size_t)(b * SS + s)) * QKVS + h * 64;
    size_t outbase = (size_t)bh * 64 * SS;
    int sp = (s & ~63) + 4 * (s & 15) + ((s >> 4) & 3);
#pragma unroll
    for (int dk8 = 0; dk8 < 8; ++dk8) {
        uint4 raw = *(const uint4*)(vsrc + inbase + dk8 * 8);
        const unsigned short* ph = (const unsigned short*)&raw;
#pragma unroll
        for (int i = 0; i < 8; ++i)
            vt[outbase + (size_t)(dk8 * 8 + i) * SS + sp] = ph[i];
    }
}

// ---------------------------------------------------------------------------
// Flash attention v9: v7 structure (the verified 152us kernel) with
// launch_bounds(256,3).
// Round-2 post-mortem: (256,4) capped VGPR at 128 -> allocator cliff
// (VGPR 124->64, 2.1GB scratch traffic/dispatch, 470us). (256,3) gives a
// 170-VGPR budget (124 fits with headroom -> identical codegen) while
// raising residency 2->3 blocks/CU (round-2 showed min-waves does control
// residency: occupancy followed the hint).
// ctx is written into the dead V-columns of the qkv buffer (stride QKVS).
// ---------------------------------------------------------------------------
#define PST 68    // Ps row stride (bf16)

__global__ __launch_bounds__(256, 3) void attention_mfma7(
    const unsigned short* __restrict__ qkv, const unsigned short* __restrict__ vt,
    unsigned short* __restrict__ ctx /* = qkv + 2048, stride QKVS */) {
    __shared__ unsigned short Ps[256 * PST];   // 34816 B; reused by epilogue

    int tid = threadIdx.x;
    int wave = tid >> 6, lane = tid & 63;
    int lr = lane & 15, quad = lane >> 4;
    int wq = wave >> 1, wj = wave & 1;

    int bid = blockIdx.x;
    int bh = bid & 63;                 // same bh -> same XCD
    int qt = bid >> 6;
    int b = bh >> 4, h = bh & 15;
    int q0 = qt * 128;
    size_t q_base = ((size_t)b * SS) * QKVS + h * 64;
    size_t k_base = q_base + 1024;
    size_t vt_base = (size_t)bh * 64 * SS;

    // preload Q A-frags (Q already carries SCALE_Q)
    uint4 af[4][2];
#pragma unroll
    for (int i = 0; i < 4; ++i)
#pragma unroll
        for (int kk = 0; kk < 2; ++kk)
            af[i][kk] = *(const uint4*)(qkv + q_base +
                (size_t)(q0 + 64 * wq + 16 * i + lr) * QKVS + kk * 32 + quad * 8);

    floatx4 o[4][4];
    float l[4][4];
#pragma unroll
    for (int i = 0; i < 4; ++i)
#pragma unroll
        for (int t = 0; t < 4; ++t) {
#pragma unroll
            for (int r = 0; r < 4; ++r) o[i][t][r] = 0.0f;
            l[i][t] = 0.0f;
        }
    floatx4 zf;
#pragma unroll
    for (int r = 0; r < 4; ++r) zf[r] = 0.0f;

    unsigned short* myPs = &Ps[wave * 64 * PST];

    for (int jt = 0; jt < SS / 128; ++jt) {
        int j0 = jt * 128 + 64 * wj;

        // S = Q K^T : kk=0 writes (zero C), kk=1 accumulates
        floatx4 s[4][4];
        {
            uint4 bv[4];
#pragma unroll
            for (int t = 0; t < 4; ++t)
                bv[t] = *(const uint4*)(qkv + k_base +
                    (size_t)(j0 + 16 * t + lr) * QKVS + quad * 8);
#pragma unroll
            for (int i = 0; i < 4; ++i)
#pragma unroll
                for (int t = 0; t < 4; ++t)
                    s[i][t] = __builtin_amdgcn_mfma_f32_16x16x32_bf16(
                        as_frag(af[i][0]), as_frag(bv[t]), zf, 0, 0, 0);
        }
        {
            uint4 bv[4];
#pragma unroll
            for (int t = 0; t < 4; ++t)
                bv[t] = *(const uint4*)(qkv + k_base +
                    (size_t)(j0 + 16 * t + lr) * QKVS + 32 + quad * 8);
#pragma unroll
            for (int i = 0; i < 4; ++i)
#pragma unroll
                for (int t = 0; t < 4; ++t)
                    s[i][t] = __builtin_amdgcn_mfma_f32_16x16x32_bf16(
                        as_frag(af[i][1]), as_frag(bv[t]), s[i][t], 0, 0, 0);
        }

        // softmax-lite: p = exp2(s) directly; wave-private P write
#pragma unroll
        for (int i = 0; i < 4; ++i) {
#pragma unroll
            for (int r = 0; r < 4; ++r) {
                float p0 = exp2f(s[i][0][r]);
                float p1 = exp2f(s[i][1][r]);
                float p2 = exp2f(s[i][2][r]);
                float p3 = exp2f(s[i][3][r]);
                l[i][r] += (p0 + p1) + (p2 + p3);
                uint2 w;
                w.x = pack_bf_trunc(p0, p1);
                w.y = pack_bf_trunc(p2, p3);
                *(uint2*)&myPs[(16 * i + quad * 4 + r) * PST + 4 * lr] = w;
            }
        }

        // O += P @ V-half
#pragma unroll
        for (int kk = 0; kk < 2; ++kk) {
            uint4 vv[4];
#pragma unroll
            for (int t = 0; t < 4; ++t)
                vv[t] = *(const uint4*)(vt + vt_base +
                    (size_t)(16 * t + lr) * SS + j0 + kk * 32 + quad * 8);
            bf16x8 pf[4];
#pragma unroll
            for (int i = 0; i < 4; ++i)
                pf[i] = *(const bf16x8*)&myPs[(16 * i + lr) * PST + kk * 32 + quad * 8];
#pragma unroll
            for (int i = 0; i < 4; ++i)
#pragma unroll
                for (int t = 0; t < 4; ++t)
                    o[i][t] = __builtin_amdgcn_mfma_f32_16x16x32_bf16(
                        pf[i], as_frag(vv[t]), o[i][t], 0, 0, 0);
        }
    }

    // reduce l partials across the 16 lanes of each row
#pragma unroll
    for (int i = 0; i < 4; ++i)
#pragma unroll
        for (int r = 0; r < 4; ++r) {
            float ls = l[i][r];
            ls += __shfl_xor(ls, 1);
            ls += __shfl_xor(ls, 2);
            ls += __shfl_xor(ls, 4);
            ls += __shfl_xor(ls, 8);
            l[i][r] = ls;
        }

    // merge j-halves: wj==1 dumps partial O,l to LDS; wj==0 combines+stores
    __syncthreads();
    float* obuf = (float*)Ps;             // [2][64][65] floats
    float* lbuf = obuf + 2 * 64 * 65;     // [2][64] floats
    if (wj == 1) {
#pragma unroll
        for (int i = 0; i < 4; ++i)
#pragma unroll
            for (int r = 0; r < 4; ++r) {
                int rl = 16 * i + quad * 4 + r;
#pragma unroll
                for (int t = 0; t < 4; ++t)
                    obuf[(wq * 64 + rl) * 65 + 16 * t + lr] = o[i][t][r];
                if (lr == 0) lbuf[wq * 64 + rl] = l[i][r];
            }
    }
    __syncthreads();
    if (wj == 0) {
#pragma unroll
        for (int i = 0; i < 4; ++i)
#pragma unroll
            for (int r = 0; r < 4; ++r) {
                int rl = 16 * i + quad * 4 + r;
                float inv = 1.0f / (l[i][r] + lbuf[wq * 64 + rl]);
                int row = q0 + 64 * wq + rl;
                size_t base = ((size_t)(b * SS + row)) * QKVS + h * 64;
#pragma unroll
                for (int t = 0; t < 4; ++t)
                    ctx[base + 16 * t + lr] =
                        f2bf((o[i][t][r] + obuf[(wq * 64 + rl) * 65 + 16 * t + lr]) * inv);
            }
    }
}

// ---------------------------------------------------------------------------
extern "C" void kernel_launch(void* const* d_in, const int* in_sizes, int n_in,
                              void* d_out, int out_size, void* d_ws, size_t ws_size,
                              hipStream_t stream) {
    const float* x     = (const float*)d_in[0];
    const float* Wq    = (const float*)d_in[1];
    const float* Wk    = (const float*)d_in[2];
    const float* Wv    = (const float*)d_in[3];
    const float* Wo    = (const float*)d_in[4];
    const float* ln1g  = (const float*)d_in[5];
    const float* ln1b  = (const float*)d_in[6];
    const float* fc1w  = (const float*)d_in[7];
    const float* fc1b  = (const float*)d_in[8];
    const float* fc2w  = (const float*)d_in[9];
    const float* fc2b  = (const float*)d_in[10];
    const float* ln2g  = (const float*)d_in[11];
    const float* ln2b  = (const float*)d_in[12];
    float* out = (float*)d_out;

    // workspace (peak 80MB):
    //  0..16 : weights (wqkvT@0 [3072x1024] 6MB, woT@6, fc1T@8, fc2T@12)
    // 16..32 : xn -> vt (after QKV GEMM) -> hn (after attention)
    // 32..80 : qkvb [8192][3072] 48MB; ctx lives in its V-cols (2048..3071)
    //          after transpose_v consumes them; h1 [8192][2048] overlays
    //          bytes 32..64MB once ctx is dead (after Wo GEMM).
    char* ws = (char*)d_ws;
    const size_t MB = 1024 * 1024;
    unsigned short* wqkvT = (unsigned short*)(ws + 0 * MB);
    unsigned short* woT   = (unsigned short*)(ws + 6 * MB);
    unsigned short* fc1T  = (unsigned short*)(ws + 8 * MB);
    unsigned short* fc2T  = (unsigned short*)(ws + 12 * MB);
    unsigned short* xn    = (unsigned short*)(ws + 16 * MB);
    unsigned short* vt    = xn;
    unsigned short* hn    = xn;
    unsigned short* qkvb  = (unsigned short*)(ws + 32 * MB);
    unsigned short* ctx   = qkvb + 2048;        // V-cols, stride QKVS
    unsigned short* h1    = qkvb;               // reuse after ctx dead

    dim3 blk(256);

    transpose_all<<<2048, blk, 0, stream>>>(Wq, Wk, Wv, Wo, fc1w, fc2w,
                                            wqkvT, woT, fc1T, fc2T);

    layernorm_bf16<<<NTOK, blk, 0, stream>>>(x, ln1g, ln1b, xn, 1e-5f);

    // fused QKV projection on the 8-phase 256^2 template:
    // 32 m-tiles x 12 n-tiles = 384 blocks (%8==0); Q cols pre-scaled
    gemm_8ph<<<384, 512, 0, stream>>>(xn, wqkvT, nullptr, qkvb,
                                      NTOK, QKVS, 1024, 0, 1024, 1024);
    transpose_v<<<dim3(8, 64), blk, 0, stream>>>(qkvb + 2048, vt);  // vt over xn

    attention_mfma7<<<1024, blk, 0, stream>>>(qkvb, vt, ctx);

    // Wo GEMM reads ctx (stride QKVS) -> fp32 out with residual x
    // (N=1024 -> 256^2 grid would be 128 blocks = half GPU; keep 128^2 db)
    gemm_db<<<512, blk, 0, stream>>>(ctx, woT, nullptr, x, out, nullptr,
                                     NTOK, 1024, 1024, 0, QKVS, 0);
    layernorm_bf16<<<NTOK, blk, 0, stream>>>(out, ln2g, ln2b, hn, 1e-6f);
    // fc1 on the 8-phase template: 32 x 8 = 256 blocks
    gemm_8ph<<<256, 512, 0, stream>>>(hn, fc1T, fc1b, h1,
                                      NTOK, 2048, 1024, 1, 1024, 0);
    gemm_db<<<512, blk, 0, stream>>>(h1, fc2T, fc2b, out, out, nullptr,
                                     NTOK, 1024, 2048, 0, 2048, 0);
}

// Round 4
// 559.154 us; speedup vs baseline: 1.5296x; 1.3848x over previous
//
#include <hip/hip_runtime.h>

// Problem constants
#define BB   4
#define SS   2048
#define DDIM 1024
#define HH   16
#define DKK  64
#define FFF  2048
#define NTOK (BB * SS)   // 8192
#define QKVS 3072        // fused qkv row stride
#define SCALE_Q 0.18033688011112042f   // 0.125 * log2(e), folded into Q

typedef __bf16 bf16x8 __attribute__((ext_vector_type(8)));
typedef float floatx4 __attribute__((ext_vector_type(4)));

__device__ __forceinline__ unsigned short f2bf(float f) {
    union { float f; unsigned u; } v; v.f = f;
    unsigned r = v.u + 0x7fffu + ((v.u >> 16) & 1u);   // RNE
    return (unsigned short)(r >> 16);
}

// pack hi16(a),hi16(b) -> one u32 (bf16 truncation x2 in one v_perm)
__device__ __forceinline__ unsigned pack_bf_trunc(float a, float b) {
    union { float f; unsigned u; } x, y; x.f = a; y.f = b;
    return __builtin_amdgcn_perm(y.u, x.u, 0x07060302u);
}

__device__ __forceinline__ bf16x8 as_frag(uint4 v) {
    union { uint4 u; bf16x8 f; } c; c.u = v; return c.f;
}

__device__ __forceinline__ void async_copy16(const unsigned short* g, unsigned short* l) {
    __builtin_amdgcn_global_load_lds(
        (const __attribute__((address_space(1))) void*)g,
        (__attribute__((address_space(3))) void*)l, 16, 0, 0);
}

// ---------------------------------------------------------------------------
// All six weight transposes fused: fp32 W[K][N] -> bf16 Wt[N][K], 64x64 tiles
// Wq/Wk/Wv land in one contiguous wqkvT [3072][1024].
// ---------------------------------------------------------------------------
__global__ __launch_bounds__(256) void transpose_all(
    const float* __restrict__ Wq, const float* __restrict__ Wk,
    const float* __restrict__ Wv, const float* __restrict__ Wo,
    const float* __restrict__ fc1, const float* __restrict__ fc2,
    unsigned short* __restrict__ wqkvT, unsigned short* __restrict__ woT,
    unsigned short* __restrict__ fc1T, unsigned short* __restrict__ fc2T) {
    __shared__ float tile[64][65];
    int t = blockIdx.x;
    const float* src; unsigned short* dst; int K, N, tl;
    if (t < 256)       { src = Wq;  dst = wqkvT;                       K = 1024; N = 1024; tl = t; }
    else if (t < 512)  { src = Wk;  dst = wqkvT + (size_t)1024 * 1024; K = 1024; N = 1024; tl = t - 256; }
    else if (t < 768)  { src = Wv;  dst = wqkvT + (size_t)2048 * 1024; K = 1024; N = 1024; tl = t - 512; }
    else if (t < 1024) { src = Wo;  dst = woT;                         K = 1024; N = 1024; tl = t - 768; }
    else if (t < 1536) { src = fc1; dst = fc1T;                        K = 1024; N = 2048; tl = t - 1024; }
    else               { src = fc2; dst = fc2T;                        K = 2048; N = 1024; tl = t - 1536; }
    int kt = K >> 6;
    int k0 = (tl & (kt - 1)) * 64, n0 = (tl / kt) * 64;
    int tid = threadIdx.x;
#pragma unroll
    for (int i = 0; i < 16; ++i) {
        int e = i * 256 + tid;
        int r = e >> 6, c = e & 63;
        tile[r][c] = src[(size_t)(k0 + r) * N + (n0 + c)];
    }
    __syncthreads();
#pragma unroll
    for (int i = 0; i < 16; ++i) {
        int e = i * 256 + tid;
        int r = e >> 6, c = e & 63;
        dst[(size_t)(n0 + r) * K + (k0 + c)] = f2bf(tile[c][r]);
    }
}

// ---------------------------------------------------------------------------
// LayerNorm: fp32 in -> bf16 out
// ---------------------------------------------------------------------------
__device__ __forceinline__ float block_sum256(float s) {
#pragma unroll
    for (int o = 32; o > 0; o >>= 1) s += __shfl_xor(s, o);
    __shared__ float partial[4];
    int w = threadIdx.x >> 6;
    __syncthreads();
    if ((threadIdx.x & 63) == 0) partial[w] = s;
    __syncthreads();
    return partial[0] + partial[1] + partial[2] + partial[3];
}

__global__ __launch_bounds__(256) void layernorm_bf16(
    const float* __restrict__ x, const float* __restrict__ g,
    const float* __restrict__ b, unsigned short* __restrict__ out, float eps) {
    size_t row = blockIdx.x;
    const float* xr = x + row * DDIM;
    int tid = threadIdx.x;
    float4 v = *(const float4*)(xr + tid * 4);
    float mu = block_sum256(v.x + v.y + v.z + v.w) * (1.0f / DDIM);
    float dx = v.x - mu, dy = v.y - mu, dz = v.z - mu, dw = v.w - mu;
    float var = block_sum256(dx * dx + dy * dy + dz * dz + dw * dw) * (1.0f / DDIM);
    float rstd = rsqrtf(var + eps);
    int c = tid * 4;
    unsigned short* o = out + row * DDIM + c;
    o[0] = f2bf(dx * rstd * g[c + 0] + b[c + 0]);
    o[1] = f2bf(dy * rstd * g[c + 1] + b[c + 1]);
    o[2] = f2bf(dz * rstd * g[c + 2] + b[c + 2]);
    o[3] = f2bf(dw * rstd * g[c + 3] + b[c + 3]);
}

// ---------------------------------------------------------------------------
// Double-buffered GEMM (r9 structure, kept for N=1024 outputs where 256^2
// tiling under-fills the grid): 128x128 tile, BK=32, one barrier per iter.
// ---------------------------------------------------------------------------
__global__ __launch_bounds__(256) void gemm_db(
    const unsigned short* __restrict__ A, const unsigned short* __restrict__ Bt,
    const float* __restrict__ bias, const float* __restrict__ resid,
    float* __restrict__ outf, unsigned short* __restrict__ outh,
    int M, int N, int K, int relu, int lda, int qcols) {
    __shared__ unsigned short As[2][128 * 32];
    __shared__ unsigned short Bs[2][128 * 32];
    int tid = threadIdx.x;
    int wave = tid >> 6, lane = tid & 63;
    int lr = lane & 15, quad = lane >> 4;
    int bid = blockIdx.x;
    int m0 = (bid & 63) * 128;         // M == 8192 -> 64 m-tiles
    int n0 = (bid >> 6) * 128;
    int wm = (wave >> 1) * 64, wn = (wave & 1) * 64;

    floatx4 acc[4][4];
#pragma unroll
    for (int i = 0; i < 4; ++i)
#pragma unroll
        for (int t = 0; t < 4; ++t)
#pragma unroll
            for (int r = 0; r < 4; ++r) acc[i][t][r] = 0.0f;

    int srow = tid >> 2;               // 0..63
    int scol = (tid & 3) * 8;
    const unsigned short* ag0 = A  + (size_t)(m0 + srow) * lda + scol;
    const unsigned short* ag1 = A  + (size_t)(m0 + srow + 64) * lda + scol;
    const unsigned short* bg0 = Bt + (size_t)(n0 + srow) * K + scol;
    const unsigned short* bg1 = Bt + (size_t)(n0 + srow + 64) * K + scol;
    int l0 = srow * 32 + scol;
    int l1 = (srow + 64) * 32 + scol;

    async_copy16(ag0, &As[0][l0]);
    async_copy16(ag1, &As[0][l1]);
    async_copy16(bg0, &Bs[0][l0]);
    async_copy16(bg1, &Bs[0][l1]);

    int cur = 0;
    for (int k0 = 0; k0 < K; k0 += 32) {
        __syncthreads();
        if (k0 + 32 < K) {
            int nb = cur ^ 1, kn = k0 + 32;
            async_copy16(ag0 + kn, &As[nb][l0]);
            async_copy16(ag1 + kn, &As[nb][l1]);
            async_copy16(bg0 + kn, &Bs[nb][l0]);
            async_copy16(bg1 + kn, &Bs[nb][l1]);
        }
        bf16x8 af[4], bfr[4];
#pragma unroll
        for (int i = 0; i < 4; ++i)
            af[i] = *(const bf16x8*)&As[cur][(wm + 16 * i + lr) * 32 + quad * 8];
#pragma unroll
        for (int t = 0; t < 4; ++t)
            bfr[t] = *(const bf16x8*)&Bs[cur][(wn + 16 * t + lr) * 32 + quad * 8];
#pragma unroll
        for (int i = 0; i < 4; ++i)
#pragma unroll
            for (int t = 0; t < 4; ++t)
                acc[i][t] = __builtin_amdgcn_mfma_f32_16x16x32_bf16(
                    af[i], bfr[t], acc[i][t], 0, 0, 0);
        cur ^= 1;
    }

#pragma unroll
    for (int i = 0; i < 4; ++i) {
#pragma unroll
        for (int t = 0; t < 4; ++t) {
            int col = n0 + wn + 16 * t + lr;
            float cs = (col < qcols) ? SCALE_Q : 1.0f;
#pragma unroll
            for (int r = 0; r < 4; ++r) {
                int row = m0 + wm + 16 * i + quad * 4 + r;
                float v = acc[i][t][r];
                if (bias)  v += bias[col];
                if (resid) v += resid[(size_t)row * N + col];
                if (relu)  v = fmaxf(v, 0.0f);
                v *= cs;
                size_t idx = (size_t)row * N + col;
                if (outf) outf[idx] = v;
                else      outh[idx] = f2bf(v);
            }
        }
    }
}

// ---------------------------------------------------------------------------
// 256x256 8-phase GEMM (m201 template: T2 st_16x32 LDS swizzle + T3/T4
// 8-phase counted-vmcnt pipeline + T5 setprio). 512 threads = 8 waves (2Mx4N),
// BK=64, 128 KiB LDS (2 bufs x (A 32KB + B 32KB)), 1 block/CU.
// (verified round 1: end-to-end -18.5us on QKV+fc1)
// ---------------------------------------------------------------------------
#define BAR8() asm volatile("s_barrier" ::: "memory")
#define WAIT_LGKM0() do { asm volatile("s_waitcnt lgkmcnt(0)" ::: "memory"); \
                          __builtin_amdgcn_sched_barrier(0); } while (0)

#define STAGE_A8(T, h) do { \
    const unsigned short* s_ = A + (size_t)(m0 + (h) * 128 + rowin) * lda + (T) * 64; \
    unsigned short* d_ = Asm + ((((T) & 1) << 14) + ((h) << 13) + sdst); \
    async_copy16(s_ + c0, d_); async_copy16(s_ + c1, d_ + 512); } while (0)

#define STAGE_B8(T, h) do { \
    const unsigned short* s_ = Bt + (size_t)(n0 + (h) * 128 + rowin) * (size_t)K + (T) * 64; \
    unsigned short* d_ = Bsm + ((((T) & 1) << 14) + ((h) << 13) + sdst); \
    async_copy16(s_ + c0, d_); async_copy16(s_ + c1, d_ + 512); } while (0)

#define READ_A4(P, ibase) \
    _Pragma("unroll") \
    for (int i = 0; i < 4; ++i) \
        _Pragma("unroll") \
        for (int kk = 0; kk < 2; ++kk) \
            a_f[i][kk] = *(const bf16x8*)&Asm[(P) + aoff + ((((ibase) + i) * 2 + kk) << 9)];

#define READ_B8(P) \
    _Pragma("unroll") \
    for (int t = 0; t < 4; ++t) \
        _Pragma("unroll") \
        for (int kk = 0; kk < 2; ++kk) \
            b_f[t][kk] = *(const bf16x8*)&Bsm[(P) + boff + ((t * 2 + kk) << 9)];

#define MFMA_Q(ilo, tlo) \
    _Pragma("unroll") \
    for (int i = 0; i < 4; ++i) \
        _Pragma("unroll") \
        for (int t = 0; t < 2; ++t) \
            _Pragma("unroll") \
            for (int kk = 0; kk < 2; ++kk) \
                acc[(ilo) + i][(tlo) + t] = __builtin_amdgcn_mfma_f32_16x16x32_bf16( \
                    a_f[i][kk], b_f[(tlo) + t][kk], acc[(ilo) + i][(tlo) + t], 0, 0, 0);

__global__ __launch_bounds__(512, 2) void gemm_8ph(
    const unsigned short* __restrict__ A, const unsigned short* __restrict__ Bt,
    const float* __restrict__ bias, unsigned short* __restrict__ outh,
    int M, int N, int K, int relu, int lda, int qcols) {
    // 2 bufs x (2 halves x 16 subtiles x 512 ushorts) = 32768 ushorts each
    __shared__ unsigned short Asm[32768];
    __shared__ unsigned short Bsm[32768];

    int tid = threadIdx.x;
    int w = tid >> 6, lane = tid & 63;
    int lr = lane & 15, quad = lane >> 4;

    // grid: requires gridDim.x % 8 == 0 and M == 8192 (32 m-tiles)
    int nwg = gridDim.x;
    int bid = blockIdx.x;
    int swz = (bid & 7) * (nwg >> 3) + (bid >> 3);   // XCD-contiguous
    int m0 = (swz & 31) << 8;
    int n0 = (swz >> 5) << 8;

    // staging geometry: wave w owns subtile-row w (rows w*16..w*16+15) of each
    // 128-row half-tile, both 32-col halves. Per-lane inverse-swizzled source.
    int rowin = (w << 4) + (lane >> 2);              // 0..127
    int q = (lane & 3) ^ ((lane >> 5) << 1);         // ^2 for lanes 32..63
    int c0 = q * 8, c1 = 32 + q * 8;                 // element col offsets
    int sdst = w << 10;                              // subtile 2w, ushort units

    // frag-read LDS offsets (ushort units); swizzled column
    int qsw8 = ((lane & 8) ? (quad ^ 2) : quad) * 8;
    int aoff = (w >> 2) * 8192 + lr * 32 + qsw8;                       // + (2i+kk)<<9
    int boff = ((w & 3) >> 1) * 8192 + ((w & 3) & 1) * 4096 + lr * 32 + qsw8;
    int wm = (w >> 2) * 128, wn = (w & 3) * 64;

    floatx4 acc[8][4];
#pragma unroll
    for (int i = 0; i < 8; ++i)
#pragma unroll
        for (int t = 0; t < 4; ++t)
#pragma unroll
            for (int r = 0; r < 4; ++r) acc[i][t][r] = 0.0f;

    int NT = K >> 6;   // assumed even, >= 2 (K = 1024 here)

    // prologue: 7 half-tiles = slots [t0.B0,t0.B1,t0.A0,t0.A1,t1.B0,t1.B1,t1.A0]
    STAGE_B8(0, 0); STAGE_B8(0, 1); STAGE_A8(0, 0); STAGE_A8(0, 1);
    STAGE_B8(1, 0); STAGE_B8(1, 1); STAGE_A8(1, 0);
    asm volatile("s_waitcnt vmcnt(4)" ::: "memory");   // tile 0 fully resident
    BAR8();

    bf16x8 a_f[4][2], b_f[4][2];

    for (int T = 0; T < NT; T += 2) {
        // ================= tile T (buf 0) =================
        // ---- phase 1: read A m0-3 + B all; stage (T+1).A1; MFMA Q00
        READ_A4(0, 0);
        READ_B8(0);
        if (T + 1 < NT) STAGE_A8(T + 1, 1);
        BAR8(); WAIT_LGKM0();
        __builtin_amdgcn_s_setprio(1); MFMA_Q(0, 0); __builtin_amdgcn_s_setprio(0);
        BAR8();
        // ---- phase 2: stage (T+2).B0; MFMA Q01
        if (T + 2 < NT) STAGE_B8(T + 2, 0);
        BAR8();
        __builtin_amdgcn_s_setprio(1); MFMA_Q(0, 2); __builtin_amdgcn_s_setprio(0);
        BAR8();
        // ---- phase 3: read A m4-7; stage (T+2).B1; MFMA Q10
        READ_A4(0, 4);
        if (T + 2 < NT) STAGE_B8(T + 2, 1);
        BAR8(); WAIT_LGKM0();
        __builtin_amdgcn_s_setprio(1); MFMA_Q(4, 0); __builtin_amdgcn_s_setprio(0);
        BAR8();
        // ---- phase 4: stage (T+2).A0; MFMA Q11; counted vmcnt
        if (T + 2 < NT) STAGE_A8(T + 2, 0);
        BAR8();
        __builtin_amdgcn_s_setprio(1); MFMA_Q(4, 2); __builtin_amdgcn_s_setprio(0);
        if (T + 2 < NT) { asm volatile("s_waitcnt vmcnt(6)" ::: "memory"); }
        else            { asm volatile("s_waitcnt vmcnt(0)" ::: "memory"); }
        BAR8();

        // ================= tile T+1 (buf 1) =================
        // ---- phase 5
        READ_A4(16384, 0);
        READ_B8(16384);
        if (T + 2 < NT) STAGE_A8(T + 2, 1);
        BAR8(); WAIT_LGKM0();
        __builtin_amdgcn_s_setprio(1); MFMA_Q(0, 0); __builtin_amdgcn_s_setprio(0);
        BAR8();
        // ---- phase 6
        if (T + 3 < NT) STAGE_B8(T + 3, 0);
        BAR8();
        __builtin_amdgcn_s_setprio(1); MFMA_Q(0, 2); __builtin_amdgcn_s_setprio(0);
        BAR8();
        // ---- phase 7
        READ_A4(16384, 4);
        if (T + 3 < NT) STAGE_B8(T + 3, 1);
        BAR8(); WAIT_LGKM0();
        __builtin_amdgcn_s_setprio(1); MFMA_Q(4, 0); __builtin_amdgcn_s_setprio(0);
        BAR8();
        // ---- phase 8
        if (T + 3 < NT) STAGE_A8(T + 3, 0);
        BAR8();
        __builtin_amdgcn_s_setprio(1); MFMA_Q(4, 2); __builtin_amdgcn_s_setprio(0);
        if (T + 3 < NT) { asm volatile("s_waitcnt vmcnt(6)" ::: "memory"); }
        else            { asm volatile("s_waitcnt vmcnt(0)" ::: "memory"); }
        BAR8();
    }

    // epilogue
#pragma unroll
    for (int i = 0; i < 8; ++i) {
#pragma unroll
        for (int t = 0; t < 4; ++t) {
            int col = n0 + wn + 16 * t + lr;
            float cs = (col < qcols) ? SCALE_Q : 1.0f;
            float bv = bias ? bias[col] : 0.0f;
#pragma unroll
            for (int r = 0; r < 4; ++r) {
                int row = m0 + wm + 16 * i + quad * 4 + r;
                float v = acc[i][t][r] + bv;
                if (relu) v = fmaxf(v, 0.0f);
                outh[(size_t)row * N + col] = f2bf(v * cs);
            }
        }
    }
}

// ---------------------------------------------------------------------------
// V transpose: vsrc rows (stride QKVS) -> vt[bh][dk][s'] with per-64-block
// permutation sigma(u) = 4*(u&15) + (u>>4)  (matches attention P-writes).
// ---------------------------------------------------------------------------
__global__ __launch_bounds__(256) void transpose_v(
    const unsigned short* __restrict__ vsrc, unsigned short* __restrict__ vt) {
    int bh = blockIdx.y;
    int b = bh >> 4, h = bh & 15;
    int s = blockIdx.x * 256 + threadIdx.x;
    size_t inbase = ((size_t)(b * SS + s)) * QKVS + h * 64;
    size_t outbase = (size_t)bh * 64 * SS;
    int sp = (s & ~63) + 4 * (s & 15) + ((s >> 4) & 3);
#pragma unroll
    for (int dk8 = 0; dk8 < 8; ++dk8) {
        uint4 raw = *(const uint4*)(vsrc + inbase + dk8 * 8);
        const unsigned short* ph = (const unsigned short*)&raw;
#pragma unroll
        for (int i = 0; i < 8; ++i)
            vt[outbase + (size_t)(dk8 * 8 + i) * SS + sp] = ph[i];
    }
}

// ---------------------------------------------------------------------------
// Flash attention v10: register-footprint restructure to fit 3 blocks/CU.
// Rounds 2/3 showed the old kernel's TRUE footprint is ~250 regs (124 arch +
// ~128 AGPR acc in the unified file) -> any min-waves>2 spilled. Changes:
//  - t-split: QK^T + exp2 done per t-pair {0,1},{2,3}; live s 64->32. Ps
//    writes become 2x u32 at cols 4*lr+2*th (same placement as before).
//  - Q frags in LDS (Qs[128][72], padded: 144B rows = bank-balanced b128
//    reads, 2-way max): frees 32 persistent arch regs; QK re-reads 2x
//    ds_read_b128 per (i,half) = 16/jt.
//  - PV kk-halves serialized (unroll 1): vv/pf live capped at 32.
// Peak live ~150 <= 170 budget at launch_bounds(256,3); LDS 53248*3 =
// 159.7KB <= 160KB -> 3 blocks/CU.
// ctx is written into the dead V-columns of the qkv buffer (stride QKVS).
// ---------------------------------------------------------------------------
#define PST 68    // Ps row stride (bf16)
#define QSP 72    // Qs row stride (bf16): 144B rows, bank-balanced

__global__ __launch_bounds__(256, 3) void attention_mfma8(
    const unsigned short* __restrict__ qkv, const unsigned short* __restrict__ vt,
    unsigned short* __restrict__ ctx /* = qkv + 2048, stride QKVS */) {
    __shared__ unsigned short Ps[256 * PST];   // 34816 B; reused by epilogue
    __shared__ unsigned short Qs[128 * QSP];   // 18432 B

    int tid = threadIdx.x;
    int wave = tid >> 6, lane = tid & 63;
    int lr = lane & 15, quad = lane >> 4;
    int wq = wave >> 1, wj = wave & 1;

    int bid = blockIdx.x;
    int bh = bid & 63;                 // same bh -> same XCD
    int qt = bid >> 6;
    int b = bh >> 4, h = bh & 15;
    int q0 = qt * 128;
    size_t q_base = ((size_t)b * SS) * QKVS + h * 64;
    size_t k_base = q_base + 1024;
    size_t vt_base = (size_t)bh * 64 * SS;

    // stage Q tile (128 rows x 64 cols, SCALE_Q pre-folded) into padded LDS
    {
        int srow = tid >> 1, sc = (tid & 1) * 32;
        const unsigned short* qsrc = qkv + q_base + (size_t)(q0 + srow) * QKVS + sc;
        uint4 v0 = *(const uint4*)(qsrc + 0);
        uint4 v1 = *(const uint4*)(qsrc + 8);
        uint4 v2 = *(const uint4*)(qsrc + 16);
        uint4 v3 = *(const uint4*)(qsrc + 24);
        unsigned short* qd = &Qs[srow * QSP + sc];
        *(uint4*)(qd + 0)  = v0;
        *(uint4*)(qd + 8)  = v1;
        *(uint4*)(qd + 16) = v2;
        *(uint4*)(qd + 24) = v3;
    }
    __syncthreads();

    floatx4 o[4][4];
    float l[4][4];
#pragma unroll
    for (int i = 0; i < 4; ++i)
#pragma unroll
        for (int t = 0; t < 4; ++t) {
#pragma unroll
            for (int r = 0; r < 4; ++r) o[i][t][r] = 0.0f;
            l[i][t] = 0.0f;
        }
    floatx4 zf;
#pragma unroll
    for (int r = 0; r < 4; ++r) zf[r] = 0.0f;

    unsigned short* myPs = &Ps[wave * 64 * PST];
    const unsigned short* aQ = &Qs[(64 * wq + lr) * QSP + quad * 8];

    for (int jt = 0; jt < SS / 128; ++jt) {
        int j0 = jt * 128 + 64 * wj;

        // S = Q K^T in t-pair halves; exp2 + pack + Ps write per half
#pragma unroll 1
        for (int th = 0; th < 2; ++th) {
            uint4 bva[2], bvb[2];
#pragma unroll
            for (int t2 = 0; t2 < 2; ++t2) {
                const unsigned short* kp = qkv + k_base +
                    (size_t)(j0 + 16 * (2 * th + t2) + lr) * QKVS + quad * 8;
                bva[t2] = *(const uint4*)(kp);
                bvb[t2] = *(const uint4*)(kp + 32);
            }
            floatx4 sh[4][2];
#pragma unroll
            for (int i = 0; i < 4; ++i) {
                bf16x8 a0 = *(const bf16x8*)(aQ + (16 * i) * QSP);
                bf16x8 a1 = *(const bf16x8*)(aQ + (16 * i) * QSP + 32);
                sh[i][0] = __builtin_amdgcn_mfma_f32_16x16x32_bf16(
                    a0, as_frag(bva[0]), zf, 0, 0, 0);
                sh[i][1] = __builtin_amdgcn_mfma_f32_16x16x32_bf16(
                    a0, as_frag(bva[1]), zf, 0, 0, 0);
                sh[i][0] = __builtin_amdgcn_mfma_f32_16x16x32_bf16(
                    a1, as_frag(bvb[0]), sh[i][0], 0, 0, 0);
                sh[i][1] = __builtin_amdgcn_mfma_f32_16x16x32_bf16(
                    a1, as_frag(bvb[1]), sh[i][1], 0, 0, 0);
            }
#pragma unroll
            for (int i = 0; i < 4; ++i)
#pragma unroll
                for (int r = 0; r < 4; ++r) {
                    float p0 = exp2f(sh[i][0][r]);
                    float p1 = exp2f(sh[i][1][r]);
                    l[i][r] += p0 + p1;
                    *(unsigned*)&myPs[(16 * i + quad * 4 + r) * PST + 4 * lr + 2 * th] =
                        pack_bf_trunc(p0, p1);
                }
        }

        // O += P @ V-half (kk-halves serialized to cap live regs)
#pragma unroll 1
        for (int kk = 0; kk < 2; ++kk) {
            uint4 vv[4];
#pragma unroll
            for (int t = 0; t < 4; ++t)
                vv[t] = *(const uint4*)(vt + vt_base +
                    (size_t)(16 * t + lr) * SS + j0 + kk * 32 + quad * 8);
            bf16x8 pf[4];
#pragma unroll
            for (int i = 0; i < 4; ++i)
                pf[i] = *(const bf16x8*)&myPs[(16 * i + lr) * PST + kk * 32 + quad * 8];
#pragma unroll
            for (int i = 0; i < 4; ++i)
#pragma unroll
                for (int t = 0; t < 4; ++t)
                    o[i][t] = __builtin_amdgcn_mfma_f32_16x16x32_bf16(
                        pf[i], as_frag(vv[t]), o[i][t], 0, 0, 0);
        }
    }

    // reduce l partials across the 16 lanes of each row
#pragma unroll
    for (int i = 0; i < 4; ++i)
#pragma unroll
        for (int r = 0; r < 4; ++r) {
            float ls = l[i][r];
            ls += __shfl_xor(ls, 1);
            ls += __shfl_xor(ls, 2);
            ls += __shfl_xor(ls, 4);
            ls += __shfl_xor(ls, 8);
            l[i][r] = ls;
        }

    // merge j-halves: wj==1 dumps partial O,l to LDS; wj==0 combines+stores
    __syncthreads();
    float* obuf = (float*)Ps;             // [2][64][65] floats
    float* lbuf = obuf + 2 * 64 * 65;     // [2][64] floats
    if (wj == 1) {
#pragma unroll
        for (int i = 0; i < 4; ++i)
#pragma unroll
            for (int r = 0; r < 4; ++r) {
                int rl = 16 * i + quad * 4 + r;
#pragma unroll
                for (int t = 0; t < 4; ++t)
                    obuf[(wq * 64 + rl) * 65 + 16 * t + lr] = o[i][t][r];
                if (lr == 0) lbuf[wq * 64 + rl] = l[i][r];
            }
    }
    __syncthreads();
    if (wj == 0) {
#pragma unroll
        for (int i = 0; i < 4; ++i)
#pragma unroll
            for (int r = 0; r < 4; ++r) {
                int rl = 16 * i + quad * 4 + r;
                float inv = 1.0f / (l[i][r] + lbuf[wq * 64 + rl]);
                int row = q0 + 64 * wq + rl;
                size_t base = ((size_t)(b * SS + row)) * QKVS + h * 64;
#pragma unroll
                for (int t = 0; t < 4; ++t)
                    ctx[base + 16 * t + lr] =
                        f2bf((o[i][t][r] + obuf[(wq * 64 + rl) * 65 + 16 * t + lr]) * inv);
            }
    }
}

// ---------------------------------------------------------------------------
extern "C" void kernel_launch(void* const* d_in, const int* in_sizes, int n_in,
                              void* d_out, int out_size, void* d_ws, size_t ws_size,
                              hipStream_t stream) {
    const float* x     = (const float*)d_in[0];
    const float* Wq    = (const float*)d_in[1];
    const float* Wk    = (const float*)d_in[2];
    const float* Wv    = (const float*)d_in[3];
    const float* Wo    = (const float*)d_in[4];
    const float* ln1g  = (const float*)d_in[5];
    const float* ln1b  = (const float*)d_in[6];
    const float* fc1w  = (const float*)d_in[7];
    const float* fc1b  = (const float*)d_in[8];
    const float* fc2w  = (const float*)d_in[9];
    const float* fc2b  = (const float*)d_in[10];
    const float* ln2g  = (const float*)d_in[11];
    const float* ln2b  = (const float*)d_in[12];
    float* out = (float*)d_out;

    // workspace (peak 80MB):
    //  0..16 : weights (wqkvT@0 [3072x1024] 6MB, woT@6, fc1T@8, fc2T@12)
    // 16..32 : xn -> vt (after QKV GEMM) -> hn (after attention)
    // 32..80 : qkvb [8192][3072] 48MB; ctx lives in its V-cols (2048..3071)
    //          after transpose_v consumes them; h1 [8192][2048] overlays
    //          bytes 32..64MB once ctx is dead (after Wo GEMM).
    char* ws = (char*)d_ws;
    const size_t MB = 1024 * 1024;
    unsigned short* wqkvT = (unsigned short*)(ws + 0 * MB);
    unsigned short* woT   = (unsigned short*)(ws + 6 * MB);
    unsigned short* fc1T  = (unsigned short*)(ws + 8 * MB);
    unsigned short* fc2T  = (unsigned short*)(ws + 12 * MB);
    unsigned short* xn    = (unsigned short*)(ws + 16 * MB);
    unsigned short* vt    = xn;
    unsigned short* hn    = xn;
    unsigned short* qkvb  = (unsigned short*)(ws + 32 * MB);
    unsigned short* ctx   = qkvb + 2048;        // V-cols, stride QKVS
    unsigned short* h1    = qkvb;               // reuse after ctx dead

    dim3 blk(256);

    transpose_all<<<2048, blk, 0, stream>>>(Wq, Wk, Wv, Wo, fc1w, fc2w,
                                            wqkvT, woT, fc1T, fc2T);

    layernorm_bf16<<<NTOK, blk, 0, stream>>>(x, ln1g, ln1b, xn, 1e-5f);

    // fused QKV projection on the 8-phase 256^2 template:
    // 32 m-tiles x 12 n-tiles = 384 blocks (%8==0); Q cols pre-scaled
    gemm_8ph<<<384, 512, 0, stream>>>(xn, wqkvT, nullptr, qkvb,
                                      NTOK, QKVS, 1024, 0, 1024, 1024);
    transpose_v<<<dim3(8, 64), blk, 0, stream>>>(qkvb + 2048, vt);  // vt over xn

    attention_mfma8<<<1024, blk, 0, stream>>>(qkvb, vt, ctx);

    // Wo GEMM reads ctx (stride QKVS) -> fp32 out with residual x
    // (N=1024 -> 256^2 grid would be 128 blocks = half GPU; keep 128^2 db)
    gemm_db<<<512, blk, 0, stream>>>(ctx, woT, nullptr, x, out, nullptr,
                                     NTOK, 1024, 1024, 0, QKVS, 0);
    layernorm_bf16<<<NTOK, blk, 0, stream>>>(out, ln2g, ln2b, hn, 1e-6f);
    // fc1 on the 8-phase template: 32 x 8 = 256 blocks
    gemm_8ph<<<256, 512, 0, stream>>>(hn, fc1T, fc1b, h1,
                                      NTOK, 2048, 1024, 1, 1024, 0);
    gemm_db<<<512, blk, 0, stream>>>(h1, fc2T, fc2b, out, out, nullptr,
                                     NTOK, 1024, 2048, 0, 2048, 0);
}

// Round 6
// 533.741 us; speedup vs baseline: 1.6024x; 1.0476x over previous
//
#include <hip/hip_runtime.h>

// Problem constants
#define BB   4
#define SS   2048
#define DDIM 1024
#define HH   16
#define DKK  64
#define FFF  2048
#define NTOK (BB * SS)   // 8192
#define QKVS 3072        // fused qkv row stride
#define SCALE_Q 0.18033688011112042f   // 0.125 * log2(e), folded into Q

typedef __bf16 bf16x8 __attribute__((ext_vector_type(8)));
typedef float floatx4 __attribute__((ext_vector_type(4)));

__device__ __forceinline__ unsigned short f2bf(float f) {
    union { float f; unsigned u; } v; v.f = f;
    unsigned r = v.u + 0x7fffu + ((v.u >> 16) & 1u);   // RNE
    return (unsigned short)(r >> 16);
}

// pack hi16(a),hi16(b) -> one u32 (bf16 truncation x2 in one v_perm)
__device__ __forceinline__ unsigned pack_bf_trunc(float a, float b) {
    union { float f; unsigned u; } x, y; x.f = a; y.f = b;
    return __builtin_amdgcn_perm(y.u, x.u, 0x07060302u);
}

__device__ __forceinline__ bf16x8 as_frag(uint4 v) {
    union { uint4 u; bf16x8 f; } c; c.u = v; return c.f;
}

__device__ __forceinline__ void async_copy16(const unsigned short* g, unsigned short* l) {
    __builtin_amdgcn_global_load_lds(
        (const __attribute__((address_space(1))) void*)g,
        (__attribute__((address_space(3))) void*)l, 16, 0, 0);
}

// ---------------------------------------------------------------------------
// All six weight transposes fused: fp32 W[K][N] -> bf16 Wt[N][K], 64x64 tiles
// Wq/Wk/Wv land in one contiguous wqkvT [3072][1024].
// ---------------------------------------------------------------------------
__global__ __launch_bounds__(256) void transpose_all(
    const float* __restrict__ Wq, const float* __restrict__ Wk,
    const float* __restrict__ Wv, const float* __restrict__ Wo,
    const float* __restrict__ fc1, const float* __restrict__ fc2,
    unsigned short* __restrict__ wqkvT, unsigned short* __restrict__ woT,
    unsigned short* __restrict__ fc1T, unsigned short* __restrict__ fc2T) {
    __shared__ float tile[64][65];
    int t = blockIdx.x;
    const float* src; unsigned short* dst; int K, N, tl;
    if (t < 256)       { src = Wq;  dst = wqkvT;                       K = 1024; N = 1024; tl = t; }
    else if (t < 512)  { src = Wk;  dst = wqkvT + (size_t)1024 * 1024; K = 1024; N = 1024; tl = t - 256; }
    else if (t < 768)  { src = Wv;  dst = wqkvT + (size_t)2048 * 1024; K = 1024; N = 1024; tl = t - 512; }
    else if (t < 1024) { src = Wo;  dst = woT;                         K = 1024; N = 1024; tl = t - 768; }
    else if (t < 1536) { src = fc1; dst = fc1T;                        K = 1024; N = 2048; tl = t - 1024; }
    else               { src = fc2; dst = fc2T;                        K = 2048; N = 1024; tl = t - 1536; }
    int kt = K >> 6;
    int k0 = (tl & (kt - 1)) * 64, n0 = (tl / kt) * 64;
    int tid = threadIdx.x;
#pragma unroll
    for (int i = 0; i < 16; ++i) {
        int e = i * 256 + tid;
        int r = e >> 6, c = e & 63;
        tile[r][c] = src[(size_t)(k0 + r) * N + (n0 + c)];
    }
    __syncthreads();
#pragma unroll
    for (int i = 0; i < 16; ++i) {
        int e = i * 256 + tid;
        int r = e >> 6, c = e & 63;
        dst[(size_t)(n0 + r) * K + (k0 + c)] = f2bf(tile[c][r]);
    }
}

// ---------------------------------------------------------------------------
// LayerNorm: fp32 in -> bf16 out
// ---------------------------------------------------------------------------
__device__ __forceinline__ float block_sum256(float s) {
#pragma unroll
    for (int o = 32; o > 0; o >>= 1) s += __shfl_xor(s, o);
    __shared__ float partial[4];
    int w = threadIdx.x >> 6;
    __syncthreads();
    if ((threadIdx.x & 63) == 0) partial[w] = s;
    __syncthreads();
    return partial[0] + partial[1] + partial[2] + partial[3];
}

__global__ __launch_bounds__(256) void layernorm_bf16(
    const float* __restrict__ x, const float* __restrict__ g,
    const float* __restrict__ b, unsigned short* __restrict__ out, float eps) {
    size_t row = blockIdx.x;
    const float* xr = x + row * DDIM;
    int tid = threadIdx.x;
    float4 v = *(const float4*)(xr + tid * 4);
    float mu = block_sum256(v.x + v.y + v.z + v.w) * (1.0f / DDIM);
    float dx = v.x - mu, dy = v.y - mu, dz = v.z - mu, dw = v.w - mu;
    float var = block_sum256(dx * dx + dy * dy + dz * dz + dw * dw) * (1.0f / DDIM);
    float rstd = rsqrtf(var + eps);
    int c = tid * 4;
    unsigned short* o = out + row * DDIM + c;
    o[0] = f2bf(dx * rstd * g[c + 0] + b[c + 0]);
    o[1] = f2bf(dy * rstd * g[c + 1] + b[c + 1]);
    o[2] = f2bf(dz * rstd * g[c + 2] + b[c + 2]);
    o[3] = f2bf(dw * rstd * g[c + 3] + b[c + 3]);
}

// ---------------------------------------------------------------------------
// Double-buffered GEMM (r9 structure, kept for N=1024 outputs where 256^2
// tiling under-fills the grid): 128x128 tile, BK=32, one barrier per iter.
// ---------------------------------------------------------------------------
__global__ __launch_bounds__(256) void gemm_db(
    const unsigned short* __restrict__ A, const unsigned short* __restrict__ Bt,
    const float* __restrict__ bias, const float* __restrict__ resid,
    float* __restrict__ outf, unsigned short* __restrict__ outh,
    int M, int N, int K, int relu, int lda, int qcols) {
    __shared__ unsigned short As[2][128 * 32];
    __shared__ unsigned short Bs[2][128 * 32];
    int tid = threadIdx.x;
    int wave = tid >> 6, lane = tid & 63;
    int lr = lane & 15, quad = lane >> 4;
    int bid = blockIdx.x;
    int m0 = (bid & 63) * 128;         // M == 8192 -> 64 m-tiles
    int n0 = (bid >> 6) * 128;
    int wm = (wave >> 1) * 64, wn = (wave & 1) * 64;

    floatx4 acc[4][4];
#pragma unroll
    for (int i = 0; i < 4; ++i)
#pragma unroll
        for (int t = 0; t < 4; ++t)
#pragma unroll
            for (int r = 0; r < 4; ++r) acc[i][t][r] = 0.0f;

    int srow = tid >> 2;               // 0..63
    int scol = (tid & 3) * 8;
    const unsigned short* ag0 = A  + (size_t)(m0 + srow) * lda + scol;
    const unsigned short* ag1 = A  + (size_t)(m0 + srow + 64) * lda + scol;
    const unsigned short* bg0 = Bt + (size_t)(n0 + srow) * K + scol;
    const unsigned short* bg1 = Bt + (size_t)(n0 + srow + 64) * K + scol;
    int l0 = srow * 32 + scol;
    int l1 = (srow + 64) * 32 + scol;

    async_copy16(ag0, &As[0][l0]);
    async_copy16(ag1, &As[0][l1]);
    async_copy16(bg0, &Bs[0][l0]);
    async_copy16(bg1, &Bs[0][l1]);

    int cur = 0;
    for (int k0 = 0; k0 < K; k0 += 32) {
        __syncthreads();
        if (k0 + 32 < K) {
            int nb = cur ^ 1, kn = k0 + 32;
            async_copy16(ag0 + kn, &As[nb][l0]);
            async_copy16(ag1 + kn, &As[nb][l1]);
            async_copy16(bg0 + kn, &Bs[nb][l0]);
            async_copy16(bg1 + kn, &Bs[nb][l1]);
        }
        bf16x8 af[4], bfr[4];
#pragma unroll
        for (int i = 0; i < 4; ++i)
            af[i] = *(const bf16x8*)&As[cur][(wm + 16 * i + lr) * 32 + quad * 8];
#pragma unroll
        for (int t = 0; t < 4; ++t)
            bfr[t] = *(const bf16x8*)&Bs[cur][(wn + 16 * t + lr) * 32 + quad * 8];
#pragma unroll
        for (int i = 0; i < 4; ++i)
#pragma unroll
            for (int t = 0; t < 4; ++t)
                acc[i][t] = __builtin_amdgcn_mfma_f32_16x16x32_bf16(
                    af[i], bfr[t], acc[i][t], 0, 0, 0);
        cur ^= 1;
    }

#pragma unroll
    for (int i = 0; i < 4; ++i) {
#pragma unroll
        for (int t = 0; t < 4; ++t) {
            int col = n0 + wn + 16 * t + lr;
            float cs = (col < qcols) ? SCALE_Q : 1.0f;
#pragma unroll
            for (int r = 0; r < 4; ++r) {
                int row = m0 + wm + 16 * i + quad * 4 + r;
                float v = acc[i][t][r];
                if (bias)  v += bias[col];
                if (resid) v += resid[(size_t)row * N + col];
                if (relu)  v = fmaxf(v, 0.0f);
                v *= cs;
                size_t idx = (size_t)row * N + col;
                if (outf) outf[idx] = v;
                else      outh[idx] = f2bf(v);
            }
        }
    }
}

// ---------------------------------------------------------------------------
// 256x256 8-phase GEMM (m201 template: T2 st_16x32 LDS swizzle + T3/T4
// 8-phase counted-vmcnt pipeline + T5 setprio). 512 threads = 8 waves (2Mx4N),
// BK=64, 128 KiB LDS (2 bufs x (A 32KB + B 32KB)), 1 block/CU.
// (verified round 1: end-to-end -18.5us on QKV+fc1)
// ---------------------------------------------------------------------------
#define BAR8() asm volatile("s_barrier" ::: "memory")
#define WAIT_LGKM0() do { asm volatile("s_waitcnt lgkmcnt(0)" ::: "memory"); \
                          __builtin_amdgcn_sched_barrier(0); } while (0)

#define STAGE_A8(T, h) do { \
    const unsigned short* s_ = A + (size_t)(m0 + (h) * 128 + rowin) * lda + (T) * 64; \
    unsigned short* d_ = Asm + ((((T) & 1) << 14) + ((h) << 13) + sdst); \
    async_copy16(s_ + c0, d_); async_copy16(s_ + c1, d_ + 512); } while (0)

#define STAGE_B8(T, h) do { \
    const unsigned short* s_ = Bt + (size_t)(n0 + (h) * 128 + rowin) * (size_t)K + (T) * 64; \
    unsigned short* d_ = Bsm + ((((T) & 1) << 14) + ((h) << 13) + sdst); \
    async_copy16(s_ + c0, d_); async_copy16(s_ + c1, d_ + 512); } while (0)

#define READ_A4(P, ibase) \
    _Pragma("unroll") \
    for (int i = 0; i < 4; ++i) \
        _Pragma("unroll") \
        for (int kk = 0; kk < 2; ++kk) \
            a_f[i][kk] = *(const bf16x8*)&Asm[(P) + aoff + ((((ibase) + i) * 2 + kk) << 9)];

#define READ_B8(P) \
    _Pragma("unroll") \
    for (int t = 0; t < 4; ++t) \
        _Pragma("unroll") \
        for (int kk = 0; kk < 2; ++kk) \
            b_f[t][kk] = *(const bf16x8*)&Bsm[(P) + boff + ((t * 2 + kk) << 9)];

#define MFMA_Q(ilo, tlo) \
    _Pragma("unroll") \
    for (int i = 0; i < 4; ++i) \
        _Pragma("unroll") \
        for (int t = 0; t < 2; ++t) \
            _Pragma("unroll") \
            for (int kk = 0; kk < 2; ++kk) \
                acc[(ilo) + i][(tlo) + t] = __builtin_amdgcn_mfma_f32_16x16x32_bf16( \
                    a_f[i][kk], b_f[(tlo) + t][kk], acc[(ilo) + i][(tlo) + t], 0, 0, 0);

__global__ __launch_bounds__(512, 2) void gemm_8ph(
    const unsigned short* __restrict__ A, const unsigned short* __restrict__ Bt,
    const float* __restrict__ bias, unsigned short* __restrict__ outh,
    int M, int N, int K, int relu, int lda, int qcols) {
    // 2 bufs x (2 halves x 16 subtiles x 512 ushorts) = 32768 ushorts each
    __shared__ unsigned short Asm[32768];
    __shared__ unsigned short Bsm[32768];

    int tid = threadIdx.x;
    int w = tid >> 6, lane = tid & 63;
    int lr = lane & 15, quad = lane >> 4;

    // grid: requires gridDim.x % 8 == 0 and M == 8192 (32 m-tiles)
    int nwg = gridDim.x;
    int bid = blockIdx.x;
    int swz = (bid & 7) * (nwg >> 3) + (bid >> 3);   // XCD-contiguous
    int m0 = (swz & 31) << 8;
    int n0 = (swz >> 5) << 8;

    // staging geometry: wave w owns subtile-row w (rows w*16..w*16+15) of each
    // 128-row half-tile, both 32-col halves. Per-lane inverse-swizzled source.
    int rowin = (w << 4) + (lane >> 2);              // 0..127
    int q = (lane & 3) ^ ((lane >> 5) << 1);         // ^2 for lanes 32..63
    int c0 = q * 8, c1 = 32 + q * 8;                 // element col offsets
    int sdst = w << 10;                              // subtile 2w, ushort units

    // frag-read LDS offsets (ushort units); swizzled column
    int qsw8 = ((lane & 8) ? (quad ^ 2) : quad) * 8;
    int aoff = (w >> 2) * 8192 + lr * 32 + qsw8;                       // + (2i+kk)<<9
    int boff = ((w & 3) >> 1) * 8192 + ((w & 3) & 1) * 4096 + lr * 32 + qsw8;
    int wm = (w >> 2) * 128, wn = (w & 3) * 64;

    floatx4 acc[8][4];
#pragma unroll
    for (int i = 0; i < 8; ++i)
#pragma unroll
        for (int t = 0; t < 4; ++t)
#pragma unroll
            for (int r = 0; r < 4; ++r) acc[i][t][r] = 0.0f;

    int NT = K >> 6;   // assumed even, >= 2 (K = 1024 here)

    // prologue: 7 half-tiles = slots [t0.B0,t0.B1,t0.A0,t0.A1,t1.B0,t1.B1,t1.A0]
    STAGE_B8(0, 0); STAGE_B8(0, 1); STAGE_A8(0, 0); STAGE_A8(0, 1);
    STAGE_B8(1, 0); STAGE_B8(1, 1); STAGE_A8(1, 0);
    asm volatile("s_waitcnt vmcnt(4)" ::: "memory");   // tile 0 fully resident
    BAR8();

    bf16x8 a_f[4][2], b_f[4][2];

    for (int T = 0; T < NT; T += 2) {
        // ================= tile T (buf 0) =================
        // ---- phase 1: read A m0-3 + B all; stage (T+1).A1; MFMA Q00
        READ_A4(0, 0);
        READ_B8(0);
        if (T + 1 < NT) STAGE_A8(T + 1, 1);
        BAR8(); WAIT_LGKM0();
        __builtin_amdgcn_s_setprio(1); MFMA_Q(0, 0); __builtin_amdgcn_s_setprio(0);
        BAR8();
        // ---- phase 2: stage (T+2).B0; MFMA Q01
        if (T + 2 < NT) STAGE_B8(T + 2, 0);
        BAR8();
        __builtin_amdgcn_s_setprio(1); MFMA_Q(0, 2); __builtin_amdgcn_s_setprio(0);
        BAR8();
        // ---- phase 3: read A m4-7; stage (T+2).B1; MFMA Q10
        READ_A4(0, 4);
        if (T + 2 < NT) STAGE_B8(T + 2, 1);
        BAR8(); WAIT_LGKM0();
        __builtin_amdgcn_s_setprio(1); MFMA_Q(4, 0); __builtin_amdgcn_s_setprio(0);
        BAR8();
        // ---- phase 4: stage (T+2).A0; MFMA Q11; counted vmcnt
        if (T + 2 < NT) STAGE_A8(T + 2, 0);
        BAR8();
        __builtin_amdgcn_s_setprio(1); MFMA_Q(4, 2); __builtin_amdgcn_s_setprio(0);
        if (T + 2 < NT) { asm volatile("s_waitcnt vmcnt(6)" ::: "memory"); }
        else            { asm volatile("s_waitcnt vmcnt(0)" ::: "memory"); }
        BAR8();

        // ================= tile T+1 (buf 1) =================
        // ---- phase 5
        READ_A4(16384, 0);
        READ_B8(16384);
        if (T + 2 < NT) STAGE_A8(T + 2, 1);
        BAR8(); WAIT_LGKM0();
        __builtin_amdgcn_s_setprio(1); MFMA_Q(0, 0); __builtin_amdgcn_s_setprio(0);
        BAR8();
        // ---- phase 6
        if (T + 3 < NT) STAGE_B8(T + 3, 0);
        BAR8();
        __builtin_amdgcn_s_setprio(1); MFMA_Q(0, 2); __builtin_amdgcn_s_setprio(0);
        BAR8();
        // ---- phase 7
        READ_A4(16384, 4);
        if (T + 3 < NT) STAGE_B8(T + 3, 1);
        BAR8(); WAIT_LGKM0();
        __builtin_amdgcn_s_setprio(1); MFMA_Q(4, 0); __builtin_amdgcn_s_setprio(0);
        BAR8();
        // ---- phase 8
        if (T + 3 < NT) STAGE_A8(T + 3, 0);
        BAR8();
        __builtin_amdgcn_s_setprio(1); MFMA_Q(4, 2); __builtin_amdgcn_s_setprio(0);
        if (T + 3 < NT) { asm volatile("s_waitcnt vmcnt(6)" ::: "memory"); }
        else            { asm volatile("s_waitcnt vmcnt(0)" ::: "memory"); }
        BAR8();
    }

    // epilogue
#pragma unroll
    for (int i = 0; i < 8; ++i) {
#pragma unroll
        for (int t = 0; t < 4; ++t) {
            int col = n0 + wn + 16 * t + lr;
            float cs = (col < qcols) ? SCALE_Q : 1.0f;
            float bv = bias ? bias[col] : 0.0f;
#pragma unroll
            for (int r = 0; r < 4; ++r) {
                int row = m0 + wm + 16 * i + quad * 4 + r;
                float v = acc[i][t][r] + bv;
                if (relu) v = fmaxf(v, 0.0f);
                outh[(size_t)row * N + col] = f2bf(v * cs);
            }
        }
    }
}

// ---------------------------------------------------------------------------
// V transpose: vsrc rows (stride QKVS) -> vt[bh][dk][s'] with per-64-block
// permutation sigma(u) = 4*(u&15) + (u>>4)  (matches attention P-writes).
// ---------------------------------------------------------------------------
__global__ __launch_bounds__(256) void transpose_v(
    const unsigned short* __restrict__ vsrc, unsigned short* __restrict__ vt) {
    int bh = blockIdx.y;
    int b = bh >> 4, h = bh & 15;
    int s = blockIdx.x * 256 + threadIdx.x;
    size_t inbase = ((size_t)(b * SS + s)) * QKVS + h * 64;
    size_t outbase = (size_t)bh * 64 * SS;
    int sp = (s & ~63) + 4 * (s & 15) + ((s >> 4) & 3);
#pragma unroll
    for (int dk8 = 0; dk8 < 8; ++dk8) {
        uint4 raw = *(const uint4*)(vsrc + inbase + dk8 * 8);
        const unsigned short* ph = (const unsigned short*)&raw;
#pragma unroll
        for (int i = 0; i < 8; ++i)
            vt[outbase + (size_t)(dk8 * 8 + i) * SS + sp] = ph[i];
    }
}

// ---------------------------------------------------------------------------
// Flash attention v11 = round-1 152us kernel (registers-resident Q, (256,2))
// + pure ILP reordering (T14 async-split, no new persistent state):
//  - K second-half loads at loop top (fly during first-half QK MFMAs)
//  - V loads for BOTH PV halves issued before softmax (fly under exp2/pack)
//  - K first-half for jt+1 prefetched before PV (flies under PV MFMAs)
// Peak live ~235 regs <= 256 budget at 2 blocks/CU. Occupancy arc (rounds
// 2-4) closed: working set can't fit 3 blocks/CU without critical-path cost.
// ctx is written into the dead V-columns of the qkv buffer (stride QKVS).
// (Round 5: resubmitted unchanged — round-4 bench was an acquisition timeout.)
// ---------------------------------------------------------------------------
#define PST 68    // Ps row stride (bf16)

__global__ __launch_bounds__(256, 2) void attention_mfma9(
    const unsigned short* __restrict__ qkv, const unsigned short* __restrict__ vt,
    unsigned short* __restrict__ ctx /* = qkv + 2048, stride QKVS */) {
    __shared__ unsigned short Ps[256 * PST];   // 34816 B; reused by epilogue

    int tid = threadIdx.x;
    int wave = tid >> 6, lane = tid & 63;
    int lr = lane & 15, quad = lane >> 4;
    int wq = wave >> 1, wj = wave & 1;

    int bid = blockIdx.x;
    int bh = bid & 63;                 // same bh -> same XCD
    int qt = bid >> 6;
    int b = bh >> 4, h = bh & 15;
    int q0 = qt * 128;
    size_t q_base = ((size_t)b * SS) * QKVS + h * 64;
    size_t k_base = q_base + 1024;
    size_t vt_base = (size_t)bh * 64 * SS;

    // preload Q A-frags (Q already carries SCALE_Q)
    uint4 af[4][2];
#pragma unroll
    for (int i = 0; i < 4; ++i)
#pragma unroll
        for (int kk = 0; kk < 2; ++kk)
            af[i][kk] = *(const uint4*)(qkv + q_base +
                (size_t)(q0 + 64 * wq + 16 * i + lr) * QKVS + kk * 32 + quad * 8);

    floatx4 o[4][4];
    float l[4][4];
#pragma unroll
    for (int i = 0; i < 4; ++i)
#pragma unroll
        for (int t = 0; t < 4; ++t) {
#pragma unroll
            for (int r = 0; r < 4; ++r) o[i][t][r] = 0.0f;
            l[i][t] = 0.0f;
        }
    floatx4 zf;
#pragma unroll
    for (int r = 0; r < 4; ++r) zf[r] = 0.0f;

    unsigned short* myPs = &Ps[wave * 64 * PST];

    // prefetch K first-half frags for jt=0
    uint4 kva[4];
#pragma unroll
    for (int t = 0; t < 4; ++t)
        kva[t] = *(const uint4*)(qkv + k_base +
            (size_t)(64 * wj + 16 * t + lr) * QKVS + quad * 8);

#pragma unroll 1
    for (int jt = 0; jt < SS / 128; ++jt) {
        int j0 = jt * 128 + 64 * wj;

        // issue K second-half loads (consumed by the second QK half below)
        uint4 kvb[4];
#pragma unroll
        for (int t = 0; t < 4; ++t)
            kvb[t] = *(const uint4*)(qkv + k_base +
                (size_t)(j0 + 16 * t + lr) * QKVS + 32 + quad * 8);

        // S = Q K^T : half 0 writes (zero C), half 1 accumulates
        floatx4 s[4][4];
#pragma unroll
        for (int i = 0; i < 4; ++i)
#pragma unroll
            for (int t = 0; t < 4; ++t)
                s[i][t] = __builtin_amdgcn_mfma_f32_16x16x32_bf16(
                    as_frag(af[i][0]), as_frag(kva[t]), zf, 0, 0, 0);
#pragma unroll
        for (int i = 0; i < 4; ++i)
#pragma unroll
            for (int t = 0; t < 4; ++t)
                s[i][t] = __builtin_amdgcn_mfma_f32_16x16x32_bf16(
                    as_frag(af[i][1]), as_frag(kvb[t]), s[i][t], 0, 0, 0);

        // V loads for BOTH PV halves issued now -> latency hides under softmax
        uint4 vv0[4], vv1[4];
#pragma unroll
        for (int t = 0; t < 4; ++t) {
            const unsigned short* vp = vt + vt_base + (size_t)(16 * t + lr) * SS + j0;
            vv0[t] = *(const uint4*)(vp + quad * 8);
            vv1[t] = *(const uint4*)(vp + 32 + quad * 8);
        }

        // softmax-lite: p = exp2(s) directly; wave-private P write
#pragma unroll
        for (int i = 0; i < 4; ++i) {
#pragma unroll
            for (int r = 0; r < 4; ++r) {
                float p0 = exp2f(s[i][0][r]);
                float p1 = exp2f(s[i][1][r]);
                float p2 = exp2f(s[i][2][r]);
                float p3 = exp2f(s[i][3][r]);
                l[i][r] += (p0 + p1) + (p2 + p3);
                uint2 w;
                w.x = pack_bf_trunc(p0, p1);
                w.y = pack_bf_trunc(p2, p3);
                *(uint2*)&myPs[(16 * i + quad * 4 + r) * PST + 4 * lr] = w;
            }
        }

        // prefetch K first-half for jt+1 -> latency hides under PV MFMAs
        if (jt + 1 < SS / 128) {
#pragma unroll
            for (int t = 0; t < 4; ++t)
                kva[t] = *(const uint4*)(qkv + k_base +
                    (size_t)(j0 + 128 + 16 * t + lr) * QKVS + quad * 8);
        }

        // O += P @ V (both halves; V already in registers)
        {
            bf16x8 pf[4];
#pragma unroll
            for (int i = 0; i < 4; ++i)
                pf[i] = *(const bf16x8*)&myPs[(16 * i + lr) * PST + quad * 8];
#pragma unroll
            for (int i = 0; i < 4; ++i)
#pragma unroll
                for (int t = 0; t < 4; ++t)
                    o[i][t] = __builtin_amdgcn_mfma_f32_16x16x32_bf16(
                        pf[i], as_frag(vv0[t]), o[i][t], 0, 0, 0);
#pragma unroll
            for (int i = 0; i < 4; ++i)
                pf[i] = *(const bf16x8*)&myPs[(16 * i + lr) * PST + 32 + quad * 8];
#pragma unroll
            for (int i = 0; i < 4; ++i)
#pragma unroll
                for (int t = 0; t < 4; ++t)
                    o[i][t] = __builtin_amdgcn_mfma_f32_16x16x32_bf16(
                        pf[i], as_frag(vv1[t]), o[i][t], 0, 0, 0);
        }
    }

    // reduce l partials across the 16 lanes of each row
#pragma unroll
    for (int i = 0; i < 4; ++i)
#pragma unroll
        for (int r = 0; r < 4; ++r) {
            float ls = l[i][r];
            ls += __shfl_xor(ls, 1);
            ls += __shfl_xor(ls, 2);
            ls += __shfl_xor(ls, 4);
            ls += __shfl_xor(ls, 8);
            l[i][r] = ls;
        }

    // merge j-halves: wj==1 dumps partial O,l to LDS; wj==0 combines+stores
    __syncthreads();
    float* obuf = (float*)Ps;             // [2][64][65] floats
    float* lbuf = obuf + 2 * 64 * 65;     // [2][64] floats
    if (wj == 1) {
#pragma unroll
        for (int i = 0; i < 4; ++i)
#pragma unroll
            for (int r = 0; r < 4; ++r) {
                int rl = 16 * i + quad * 4 + r;
#pragma unroll
                for (int t = 0; t < 4; ++t)
                    obuf[(wq * 64 + rl) * 65 + 16 * t + lr] = o[i][t][r];
                if (lr == 0) lbuf[wq * 64 + rl] = l[i][r];
            }
    }
    __syncthreads();
    if (wj == 0) {
#pragma unroll
        for (int i = 0; i < 4; ++i)
#pragma unroll
            for (int r = 0; r < 4; ++r) {
                int rl = 16 * i + quad * 4 + r;
                float inv = 1.0f / (l[i][r] + lbuf[wq * 64 + rl]);
                int row = q0 + 64 * wq + rl;
                size_t base = ((size_t)(b * SS + row)) * QKVS + h * 64;
#pragma unroll
                for (int t = 0; t < 4; ++t)
                    ctx[base + 16 * t + lr] =
                        f2bf((o[i][t][r] + obuf[(wq * 64 + rl) * 65 + 16 * t + lr]) * inv);
            }
    }
}

// ---------------------------------------------------------------------------
extern "C" void kernel_launch(void* const* d_in, const int* in_sizes, int n_in,
                              void* d_out, int out_size, void* d_ws, size_t ws_size,
                              hipStream_t stream) {
    const float* x     = (const float*)d_in[0];
    const float* Wq    = (const float*)d_in[1];
    const float* Wk    = (const float*)d_in[2];
    const float* Wv    = (const float*)d_in[3];
    const float* Wo    = (const float*)d_in[4];
    const float* ln1g  = (const float*)d_in[5];
    const float* ln1b  = (const float*)d_in[6];
    const float* fc1w  = (const float*)d_in[7];
    const float* fc1b  = (const float*)d_in[8];
    const float* fc2w  = (const float*)d_in[9];
    const float* fc2b  = (const float*)d_in[10];
    const float* ln2g  = (const float*)d_in[11];
    const float* ln2b  = (const float*)d_in[12];
    float* out = (float*)d_out;

    // workspace (peak 80MB):
    //  0..16 : weights (wqkvT@0 [3072x1024] 6MB, woT@6, fc1T@8, fc2T@12)
    // 16..32 : xn -> vt (after QKV GEMM) -> hn (after attention)
    // 32..80 : qkvb [8192][3072] 48MB; ctx lives in its V-cols (2048..3071)
    //          after transpose_v consumes them; h1 [8192][2048] overlays
    //          bytes 32..64MB once ctx is dead (after Wo GEMM).
    char* ws = (char*)d_ws;
    const size_t MB = 1024 * 1024;
    unsigned short* wqkvT = (unsigned short*)(ws + 0 * MB);
    unsigned short* woT   = (unsigned short*)(ws + 6 * MB);
    unsigned short* fc1T  = (unsigned short*)(ws + 8 * MB);
    unsigned short* fc2T  = (unsigned short*)(ws + 12 * MB);
    unsigned short* xn    = (unsigned short*)(ws + 16 * MB);
    unsigned short* vt    = xn;
    unsigned short* hn    = xn;
    unsigned short* qkvb  = (unsigned short*)(ws + 32 * MB);
    unsigned short* ctx   = qkvb + 2048;        // V-cols, stride QKVS
    unsigned short* h1    = qkvb;               // reuse after ctx dead

    dim3 blk(256);

    transpose_all<<<2048, blk, 0, stream>>>(Wq, Wk, Wv, Wo, fc1w, fc2w,
                                            wqkvT, woT, fc1T, fc2T);

    layernorm_bf16<<<NTOK, blk, 0, stream>>>(x, ln1g, ln1b, xn, 1e-5f);

    // fused QKV projection on the 8-phase 256^2 template:
    // 32 m-tiles x 12 n-tiles = 384 blocks (%8==0); Q cols pre-scaled
    gemm_8ph<<<384, 512, 0, stream>>>(xn, wqkvT, nullptr, qkvb,
                                      NTOK, QKVS, 1024, 0, 1024, 1024);
    transpose_v<<<dim3(8, 64), blk, 0, stream>>>(qkvb + 2048, vt);  // vt over xn

    attention_mfma9<<<1024, blk, 0, stream>>>(qkvb, vt, ctx);

    // Wo GEMM reads ctx (stride QKVS) -> fp32 out with residual x
    // (N=1024 -> 256^2 grid would be 128 blocks = half GPU; keep 128^2 db)
    gemm_db<<<512, blk, 0, stream>>>(ctx, woT, nullptr, x, out, nullptr,
                                     NTOK, 1024, 1024, 0, QKVS, 0);
    layernorm_bf16<<<NTOK, blk, 0, stream>>>(out, ln2g, ln2b, hn, 1e-6f);
    // fc1 on the 8-phase template: 32 x 8 = 256 blocks
    gemm_8ph<<<256, 512, 0, stream>>>(hn, fc1T, fc1b, h1,
                                      NTOK, 2048, 1024, 1, 1024, 0);
    gemm_db<<<512, blk, 0, stream>>>(h1, fc2T, fc2b, out, out, nullptr,
                                     NTOK, 1024, 2048, 0, 2048, 0);
}

// Round 7
// 525.244 us; speedup vs baseline: 1.6283x; 1.0162x over previous
//
#include <hip/hip_runtime.h>

// Problem constants
#define BB   4
#define SS   2048
#define DDIM 1024
#define HH   16
#define DKK  64
#define FFF  2048
#define NTOK (BB * SS)   // 8192
#define QKVS 3072        // fused qkv row stride
#define SCALE_Q 0.18033688011112042f   // 0.125 * log2(e), folded into Q

typedef __bf16 bf16x8 __attribute__((ext_vector_type(8)));
typedef float floatx4 __attribute__((ext_vector_type(4)));

__device__ __forceinline__ unsigned short f2bf(float f) {
    union { float f; unsigned u; } v; v.f = f;
    unsigned r = v.u + 0x7fffu + ((v.u >> 16) & 1u);   // RNE
    return (unsigned short)(r >> 16);
}

// pack hi16(a),hi16(b) -> one u32 (bf16 truncation x2 in one v_perm)
__device__ __forceinline__ unsigned pack_bf_trunc(float a, float b) {
    union { float f; unsigned u; } x, y; x.f = a; y.f = b;
    return __builtin_amdgcn_perm(y.u, x.u, 0x07060302u);
}

__device__ __forceinline__ bf16x8 as_frag(uint4 v) {
    union { uint4 u; bf16x8 f; } c; c.u = v; return c.f;
}

__device__ __forceinline__ void async_copy16(const unsigned short* g, unsigned short* l) {
    __builtin_amdgcn_global_load_lds(
        (const __attribute__((address_space(1))) void*)g,
        (__attribute__((address_space(3))) void*)l, 16, 0, 0);
}

// ---------------------------------------------------------------------------
// All six weight transposes fused: fp32 W[K][N] -> bf16 Wt[N][K], 64x64 tiles
// Wq/Wk/Wv land in one contiguous wqkvT [3072][1024].
// ---------------------------------------------------------------------------
__global__ __launch_bounds__(256) void transpose_all(
    const float* __restrict__ Wq, const float* __restrict__ Wk,
    const float* __restrict__ Wv, const float* __restrict__ Wo,
    const float* __restrict__ fc1, const float* __restrict__ fc2,
    unsigned short* __restrict__ wqkvT, unsigned short* __restrict__ woT,
    unsigned short* __restrict__ fc1T, unsigned short* __restrict__ fc2T) {
    __shared__ float tile[64][65];
    int t = blockIdx.x;
    const float* src; unsigned short* dst; int K, N, tl;
    if (t < 256)       { src = Wq;  dst = wqkvT;                       K = 1024; N = 1024; tl = t; }
    else if (t < 512)  { src = Wk;  dst = wqkvT + (size_t)1024 * 1024; K = 1024; N = 1024; tl = t - 256; }
    else if (t < 768)  { src = Wv;  dst = wqkvT + (size_t)2048 * 1024; K = 1024; N = 1024; tl = t - 512; }
    else if (t < 1024) { src = Wo;  dst = woT;                         K = 1024; N = 1024; tl = t - 768; }
    else if (t < 1536) { src = fc1; dst = fc1T;                        K = 1024; N = 2048; tl = t - 1024; }
    else               { src = fc2; dst = fc2T;                        K = 2048; N = 1024; tl = t - 1536; }
    int kt = K >> 6;
    int k0 = (tl & (kt - 1)) * 64, n0 = (tl / kt) * 64;
    int tid = threadIdx.x;
#pragma unroll
    for (int i = 0; i < 16; ++i) {
        int e = i * 256 + tid;
        int r = e >> 6, c = e & 63;
        tile[r][c] = src[(size_t)(k0 + r) * N + (n0 + c)];
    }
    __syncthreads();
#pragma unroll
    for (int i = 0; i < 16; ++i) {
        int e = i * 256 + tid;
        int r = e >> 6, c = e & 63;
        dst[(size_t)(n0 + r) * K + (k0 + c)] = f2bf(tile[c][r]);
    }
}

// ---------------------------------------------------------------------------
// LayerNorm: fp32 in -> bf16 out
// ---------------------------------------------------------------------------
__device__ __forceinline__ float block_sum256(float s) {
#pragma unroll
    for (int o = 32; o > 0; o >>= 1) s += __shfl_xor(s, o);
    __shared__ float partial[4];
    int w = threadIdx.x >> 6;
    __syncthreads();
    if ((threadIdx.x & 63) == 0) partial[w] = s;
    __syncthreads();
    return partial[0] + partial[1] + partial[2] + partial[3];
}

__global__ __launch_bounds__(256) void layernorm_bf16(
    const float* __restrict__ x, const float* __restrict__ g,
    const float* __restrict__ b, unsigned short* __restrict__ out, float eps) {
    size_t row = blockIdx.x;
    const float* xr = x + row * DDIM;
    int tid = threadIdx.x;
    float4 v = *(const float4*)(xr + tid * 4);
    float mu = block_sum256(v.x + v.y + v.z + v.w) * (1.0f / DDIM);
    float dx = v.x - mu, dy = v.y - mu, dz = v.z - mu, dw = v.w - mu;
    float var = block_sum256(dx * dx + dy * dy + dz * dz + dw * dw) * (1.0f / DDIM);
    float rstd = rsqrtf(var + eps);
    int c = tid * 4;
    unsigned short* o = out + row * DDIM + c;
    o[0] = f2bf(dx * rstd * g[c + 0] + b[c + 0]);
    o[1] = f2bf(dy * rstd * g[c + 1] + b[c + 1]);
    o[2] = f2bf(dz * rstd * g[c + 2] + b[c + 2]);
    o[3] = f2bf(dw * rstd * g[c + 3] + b[c + 3]);
}

// ---------------------------------------------------------------------------
// Double-buffered GEMM (r9 structure, kept for N=1024 outputs where 256^2
// tiling under-fills the grid): 128x128 tile, BK=32, one barrier per iter.
// ---------------------------------------------------------------------------
__global__ __launch_bounds__(256) void gemm_db(
    const unsigned short* __restrict__ A, const unsigned short* __restrict__ Bt,
    const float* __restrict__ bias, const float* __restrict__ resid,
    float* __restrict__ outf, unsigned short* __restrict__ outh,
    int M, int N, int K, int relu, int lda, int qcols) {
    __shared__ unsigned short As[2][128 * 32];
    __shared__ unsigned short Bs[2][128 * 32];
    int tid = threadIdx.x;
    int wave = tid >> 6, lane = tid & 63;
    int lr = lane & 15, quad = lane >> 4;
    int bid = blockIdx.x;
    int m0 = (bid & 63) * 128;         // M == 8192 -> 64 m-tiles
    int n0 = (bid >> 6) * 128;
    int wm = (wave >> 1) * 64, wn = (wave & 1) * 64;

    floatx4 acc[4][4];
#pragma unroll
    for (int i = 0; i < 4; ++i)
#pragma unroll
        for (int t = 0; t < 4; ++t)
#pragma unroll
            for (int r = 0; r < 4; ++r) acc[i][t][r] = 0.0f;

    int srow = tid >> 2;               // 0..63
    int scol = (tid & 3) * 8;
    const unsigned short* ag0 = A  + (size_t)(m0 + srow) * lda + scol;
    const unsigned short* ag1 = A  + (size_t)(m0 + srow + 64) * lda + scol;
    const unsigned short* bg0 = Bt + (size_t)(n0 + srow) * K + scol;
    const unsigned short* bg1 = Bt + (size_t)(n0 + srow + 64) * K + scol;
    int l0 = srow * 32 + scol;
    int l1 = (srow + 64) * 32 + scol;

    async_copy16(ag0, &As[0][l0]);
    async_copy16(ag1, &As[0][l1]);
    async_copy16(bg0, &Bs[0][l0]);
    async_copy16(bg1, &Bs[0][l1]);

    int cur = 0;
    for (int k0 = 0; k0 < K; k0 += 32) {
        __syncthreads();
        if (k0 + 32 < K) {
            int nb = cur ^ 1, kn = k0 + 32;
            async_copy16(ag0 + kn, &As[nb][l0]);
            async_copy16(ag1 + kn, &As[nb][l1]);
            async_copy16(bg0 + kn, &Bs[nb][l0]);
            async_copy16(bg1 + kn, &Bs[nb][l1]);
        }
        bf16x8 af[4], bfr[4];
#pragma unroll
        for (int i = 0; i < 4; ++i)
            af[i] = *(const bf16x8*)&As[cur][(wm + 16 * i + lr) * 32 + quad * 8];
#pragma unroll
        for (int t = 0; t < 4; ++t)
            bfr[t] = *(const bf16x8*)&Bs[cur][(wn + 16 * t + lr) * 32 + quad * 8];
#pragma unroll
        for (int i = 0; i < 4; ++i)
#pragma unroll
            for (int t = 0; t < 4; ++t)
                acc[i][t] = __builtin_amdgcn_mfma_f32_16x16x32_bf16(
                    af[i], bfr[t], acc[i][t], 0, 0, 0);
        cur ^= 1;
    }

#pragma unroll
    for (int i = 0; i < 4; ++i) {
#pragma unroll
        for (int t = 0; t < 4; ++t) {
            int col = n0 + wn + 16 * t + lr;
            float cs = (col < qcols) ? SCALE_Q : 1.0f;
#pragma unroll
            for (int r = 0; r < 4; ++r) {
                int row = m0 + wm + 16 * i + quad * 4 + r;
                float v = acc[i][t][r];
                if (bias)  v += bias[col];
                if (resid) v += resid[(size_t)row * N + col];
                if (relu)  v = fmaxf(v, 0.0f);
                v *= cs;
                size_t idx = (size_t)row * N + col;
                if (outf) outf[idx] = v;
                else      outh[idx] = f2bf(v);
            }
        }
    }
}

// ---------------------------------------------------------------------------
// 256x256 8-phase GEMM (m201 template: T2 st_16x32 LDS swizzle + T3/T4
// 8-phase counted-vmcnt pipeline + T5 setprio). 512 threads = 8 waves (2Mx4N),
// BK=64, 128 KiB LDS (2 bufs x (A 32KB + B 32KB)), 1 block/CU.
// (verified round 1: end-to-end -18.5us on QKV+fc1)
// ---------------------------------------------------------------------------
#define BAR8() asm volatile("s_barrier" ::: "memory")
#define WAIT_LGKM0() do { asm volatile("s_waitcnt lgkmcnt(0)" ::: "memory"); \
                          __builtin_amdgcn_sched_barrier(0); } while (0)

#define STAGE_A8(T, h) do { \
    const unsigned short* s_ = A + (size_t)(m0 + (h) * 128 + rowin) * lda + (T) * 64; \
    unsigned short* d_ = Asm + ((((T) & 1) << 14) + ((h) << 13) + sdst); \
    async_copy16(s_ + c0, d_); async_copy16(s_ + c1, d_ + 512); } while (0)

#define STAGE_B8(T, h) do { \
    const unsigned short* s_ = Bt + (size_t)(n0 + (h) * 128 + rowin) * (size_t)K + (T) * 64; \
    unsigned short* d_ = Bsm + ((((T) & 1) << 14) + ((h) << 13) + sdst); \
    async_copy16(s_ + c0, d_); async_copy16(s_ + c1, d_ + 512); } while (0)

#define READ_A4(P, ibase) \
    _Pragma("unroll") \
    for (int i = 0; i < 4; ++i) \
        _Pragma("unroll") \
        for (int kk = 0; kk < 2; ++kk) \
            a_f[i][kk] = *(const bf16x8*)&Asm[(P) + aoff + ((((ibase) + i) * 2 + kk) << 9)];

#define READ_B8(P) \
    _Pragma("unroll") \
    for (int t = 0; t < 4; ++t) \
        _Pragma("unroll") \
        for (int kk = 0; kk < 2; ++kk) \
            b_f[t][kk] = *(const bf16x8*)&Bsm[(P) + boff + ((t * 2 + kk) << 9)];

#define MFMA_Q(ilo, tlo) \
    _Pragma("unroll") \
    for (int i = 0; i < 4; ++i) \
        _Pragma("unroll") \
        for (int t = 0; t < 2; ++t) \
            _Pragma("unroll") \
            for (int kk = 0; kk < 2; ++kk) \
                acc[(ilo) + i][(tlo) + t] = __builtin_amdgcn_mfma_f32_16x16x32_bf16( \
                    a_f[i][kk], b_f[(tlo) + t][kk], acc[(ilo) + i][(tlo) + t], 0, 0, 0);

__global__ __launch_bounds__(512, 2) void gemm_8ph(
    const unsigned short* __restrict__ A, const unsigned short* __restrict__ Bt,
    const float* __restrict__ bias, unsigned short* __restrict__ outh,
    int M, int N, int K, int relu, int lda, int qcols) {
    // 2 bufs x (2 halves x 16 subtiles x 512 ushorts) = 32768 ushorts each
    __shared__ unsigned short Asm[32768];
    __shared__ unsigned short Bsm[32768];

    int tid = threadIdx.x;
    int w = tid >> 6, lane = tid & 63;
    int lr = lane & 15, quad = lane >> 4;

    // grid: requires gridDim.x % 8 == 0 and M == 8192 (32 m-tiles)
    int nwg = gridDim.x;
    int bid = blockIdx.x;
    int swz = (bid & 7) * (nwg >> 3) + (bid >> 3);   // XCD-contiguous
    int m0 = (swz & 31) << 8;
    int n0 = (swz >> 5) << 8;

    // staging geometry: wave w owns subtile-row w (rows w*16..w*16+15) of each
    // 128-row half-tile, both 32-col halves. Per-lane inverse-swizzled source.
    int rowin = (w << 4) + (lane >> 2);              // 0..127
    int q = (lane & 3) ^ ((lane >> 5) << 1);         // ^2 for lanes 32..63
    int c0 = q * 8, c1 = 32 + q * 8;                 // element col offsets
    int sdst = w << 10;                              // subtile 2w, ushort units

    // frag-read LDS offsets (ushort units); swizzled column
    int qsw8 = ((lane & 8) ? (quad ^ 2) : quad) * 8;
    int aoff = (w >> 2) * 8192 + lr * 32 + qsw8;                       // + (2i+kk)<<9
    int boff = ((w & 3) >> 1) * 8192 + ((w & 3) & 1) * 4096 + lr * 32 + qsw8;
    int wm = (w >> 2) * 128, wn = (w & 3) * 64;

    floatx4 acc[8][4];
#pragma unroll
    for (int i = 0; i < 8; ++i)
#pragma unroll
        for (int t = 0; t < 4; ++t)
#pragma unroll
            for (int r = 0; r < 4; ++r) acc[i][t][r] = 0.0f;

    int NT = K >> 6;   // assumed even, >= 2 (K = 1024 here)

    // prologue: 7 half-tiles = slots [t0.B0,t0.B1,t0.A0,t0.A1,t1.B0,t1.B1,t1.A0]
    STAGE_B8(0, 0); STAGE_B8(0, 1); STAGE_A8(0, 0); STAGE_A8(0, 1);
    STAGE_B8(1, 0); STAGE_B8(1, 1); STAGE_A8(1, 0);
    asm volatile("s_waitcnt vmcnt(4)" ::: "memory");   // tile 0 fully resident
    BAR8();

    bf16x8 a_f[4][2], b_f[4][2];

    for (int T = 0; T < NT; T += 2) {
        // ================= tile T (buf 0) =================
        // ---- phase 1: read A m0-3 + B all; stage (T+1).A1; MFMA Q00
        READ_A4(0, 0);
        READ_B8(0);
        if (T + 1 < NT) STAGE_A8(T + 1, 1);
        BAR8(); WAIT_LGKM0();
        __builtin_amdgcn_s_setprio(1); MFMA_Q(0, 0); __builtin_amdgcn_s_setprio(0);
        BAR8();
        // ---- phase 2: stage (T+2).B0; MFMA Q01
        if (T + 2 < NT) STAGE_B8(T + 2, 0);
        BAR8();
        __builtin_amdgcn_s_setprio(1); MFMA_Q(0, 2); __builtin_amdgcn_s_setprio(0);
        BAR8();
        // ---- phase 3: read A m4-7; stage (T+2).B1; MFMA Q10
        READ_A4(0, 4);
        if (T + 2 < NT) STAGE_B8(T + 2, 1);
        BAR8(); WAIT_LGKM0();
        __builtin_amdgcn_s_setprio(1); MFMA_Q(4, 0); __builtin_amdgcn_s_setprio(0);
        BAR8();
        // ---- phase 4: stage (T+2).A0; MFMA Q11; counted vmcnt
        if (T + 2 < NT) STAGE_A8(T + 2, 0);
        BAR8();
        __builtin_amdgcn_s_setprio(1); MFMA_Q(4, 2); __builtin_amdgcn_s_setprio(0);
        if (T + 2 < NT) { asm volatile("s_waitcnt vmcnt(6)" ::: "memory"); }
        else            { asm volatile("s_waitcnt vmcnt(0)" ::: "memory"); }
        BAR8();

        // ================= tile T+1 (buf 1) =================
        // ---- phase 5
        READ_A4(16384, 0);
        READ_B8(16384);
        if (T + 2 < NT) STAGE_A8(T + 2, 1);
        BAR8(); WAIT_LGKM0();
        __builtin_amdgcn_s_setprio(1); MFMA_Q(0, 0); __builtin_amdgcn_s_setprio(0);
        BAR8();
        // ---- phase 6
        if (T + 3 < NT) STAGE_B8(T + 3, 0);
        BAR8();
        __builtin_amdgcn_s_setprio(1); MFMA_Q(0, 2); __builtin_amdgcn_s_setprio(0);
        BAR8();
        // ---- phase 7
        READ_A4(16384, 4);
        if (T + 3 < NT) STAGE_B8(T + 3, 1);
        BAR8(); WAIT_LGKM0();
        __builtin_amdgcn_s_setprio(1); MFMA_Q(4, 0); __builtin_amdgcn_s_setprio(0);
        BAR8();
        // ---- phase 8
        if (T + 3 < NT) STAGE_A8(T + 3, 0);
        BAR8();
        __builtin_amdgcn_s_setprio(1); MFMA_Q(4, 2); __builtin_amdgcn_s_setprio(0);
        if (T + 3 < NT) { asm volatile("s_waitcnt vmcnt(6)" ::: "memory"); }
        else            { asm volatile("s_waitcnt vmcnt(0)" ::: "memory"); }
        BAR8();
    }

    // epilogue
#pragma unroll
    for (int i = 0; i < 8; ++i) {
#pragma unroll
        for (int t = 0; t < 4; ++t) {
            int col = n0 + wn + 16 * t + lr;
            float cs = (col < qcols) ? SCALE_Q : 1.0f;
            float bv = bias ? bias[col] : 0.0f;
#pragma unroll
            for (int r = 0; r < 4; ++r) {
                int row = m0 + wm + 16 * i + quad * 4 + r;
                float v = acc[i][t][r] + bv;
                if (relu) v = fmaxf(v, 0.0f);
                outh[(size_t)row * N + col] = f2bf(v * cs);
            }
        }
    }
}

// ---------------------------------------------------------------------------
// V transpose: vsrc rows (stride QKVS) -> vt[bh][dk][s'] with per-64-block
// permutation sigma(u) = 4*(u&15) + (u>>4)  (matches attention P-writes).
// ---------------------------------------------------------------------------
__global__ __launch_bounds__(256) void transpose_v(
    const unsigned short* __restrict__ vsrc, unsigned short* __restrict__ vt) {
    int bh = blockIdx.y;
    int b = bh >> 4, h = bh & 15;
    int s = blockIdx.x * 256 + threadIdx.x;
    size_t inbase = ((size_t)(b * SS + s)) * QKVS + h * 64;
    size_t outbase = (size_t)bh * 64 * SS;
    int sp = (s & ~63) + 4 * (s & 15) + ((s >> 4) & 3);
#pragma unroll
    for (int dk8 = 0; dk8 < 8; ++dk8) {
        uint4 raw = *(const uint4*)(vsrc + inbase + dk8 * 8);
        const unsigned short* ph = (const unsigned short*)&raw;
#pragma unroll
        for (int i = 0; i < 8; ++i)
            vt[outbase + (size_t)(dk8 * 8 + i) * SS + sp] = ph[i];
    }
}

// ---------------------------------------------------------------------------
// Flash attention v12 = EXACT round-1 152us kernel (registers-resident Q,
// launch_bounds(256,2), compiler-scheduled loads — rounds 2-6 proved both
// occupancy-raising and manual ILP reordering regress) + ONE change:
// T5 s_setprio(1)/(0) around the QK and PV MFMA clusters. Regime check:
// 8 independent waves/CU at different phases (no main-loop barriers) =
// m191's attention configuration where isolated A/B measured +4-7%.
// ctx is written into the dead V-columns of the qkv buffer (stride QKVS).
// ---------------------------------------------------------------------------
#define PST 68    // Ps row stride (bf16)

__global__ __launch_bounds__(256, 2) void attention_mfma10(
    const unsigned short* __restrict__ qkv, const unsigned short* __restrict__ vt,
    unsigned short* __restrict__ ctx /* = qkv + 2048, stride QKVS */) {
    __shared__ unsigned short Ps[256 * PST];   // 34816 B; reused by epilogue

    int tid = threadIdx.x;
    int wave = tid >> 6, lane = tid & 63;
    int lr = lane & 15, quad = lane >> 4;
    int wq = wave >> 1, wj = wave & 1;

    int bid = blockIdx.x;
    int bh = bid & 63;                 // same bh -> same XCD
    int qt = bid >> 6;
    int b = bh >> 4, h = bh & 15;
    int q0 = qt * 128;
    size_t q_base = ((size_t)b * SS) * QKVS + h * 64;
    size_t k_base = q_base + 1024;
    size_t vt_base = (size_t)bh * 64 * SS;

    // preload Q A-frags (Q already carries SCALE_Q)
    uint4 af[4][2];
#pragma unroll
    for (int i = 0; i < 4; ++i)
#pragma unroll
        for (int kk = 0; kk < 2; ++kk)
            af[i][kk] = *(const uint4*)(qkv + q_base +
                (size_t)(q0 + 64 * wq + 16 * i + lr) * QKVS + kk * 32 + quad * 8);

    floatx4 o[4][4];
    float l[4][4];
#pragma unroll
    for (int i = 0; i < 4; ++i)
#pragma unroll
        for (int t = 0; t < 4; ++t) {
#pragma unroll
            for (int r = 0; r < 4; ++r) o[i][t][r] = 0.0f;
            l[i][t] = 0.0f;
        }
    floatx4 zf;
#pragma unroll
    for (int r = 0; r < 4; ++r) zf[r] = 0.0f;

    unsigned short* myPs = &Ps[wave * 64 * PST];

    for (int jt = 0; jt < SS / 128; ++jt) {
        int j0 = jt * 128 + 64 * wj;

        // S = Q K^T : kk=0 writes (zero C), kk=1 accumulates
        floatx4 s[4][4];
        {
            uint4 bv[4];
#pragma unroll
            for (int t = 0; t < 4; ++t)
                bv[t] = *(const uint4*)(qkv + k_base +
                    (size_t)(j0 + 16 * t + lr) * QKVS + quad * 8);
            __builtin_amdgcn_s_setprio(1);
#pragma unroll
            for (int i = 0; i < 4; ++i)
#pragma unroll
                for (int t = 0; t < 4; ++t)
                    s[i][t] = __builtin_amdgcn_mfma_f32_16x16x32_bf16(
                        as_frag(af[i][0]), as_frag(bv[t]), zf, 0, 0, 0);
            __builtin_amdgcn_s_setprio(0);
        }
        {
            uint4 bv[4];
#pragma unroll
            for (int t = 0; t < 4; ++t)
                bv[t] = *(const uint4*)(qkv + k_base +
                    (size_t)(j0 + 16 * t + lr) * QKVS + 32 + quad * 8);
            __builtin_amdgcn_s_setprio(1);
#pragma unroll
            for (int i = 0; i < 4; ++i)
#pragma unroll
                for (int t = 0; t < 4; ++t)
                    s[i][t] = __builtin_amdgcn_mfma_f32_16x16x32_bf16(
                        as_frag(af[i][1]), as_frag(bv[t]), s[i][t], 0, 0, 0);
            __builtin_amdgcn_s_setprio(0);
        }

        // softmax-lite: p = exp2(s) directly; wave-private P write
#pragma unroll
        for (int i = 0; i < 4; ++i) {
#pragma unroll
            for (int r = 0; r < 4; ++r) {
                float p0 = exp2f(s[i][0][r]);
                float p1 = exp2f(s[i][1][r]);
                float p2 = exp2f(s[i][2][r]);
                float p3 = exp2f(s[i][3][r]);
                l[i][r] += (p0 + p1) + (p2 + p3);
                uint2 w;
                w.x = pack_bf_trunc(p0, p1);
                w.y = pack_bf_trunc(p2, p3);
                *(uint2*)&myPs[(16 * i + quad * 4 + r) * PST + 4 * lr] = w;
            }
        }

        // O += P @ V-half
#pragma unroll
        for (int kk = 0; kk < 2; ++kk) {
            uint4 vv[4];
#pragma unroll
            for (int t = 0; t < 4; ++t)
                vv[t] = *(const uint4*)(vt + vt_base +
                    (size_t)(16 * t + lr) * SS + j0 + kk * 32 + quad * 8);
            bf16x8 pf[4];
#pragma unroll
            for (int i = 0; i < 4; ++i)
                pf[i] = *(const bf16x8*)&myPs[(16 * i + lr) * PST + kk * 32 + quad * 8];
            __builtin_amdgcn_s_setprio(1);
#pragma unroll
            for (int i = 0; i < 4; ++i)
#pragma unroll
                for (int t = 0; t < 4; ++t)
                    o[i][t] = __builtin_amdgcn_mfma_f32_16x16x32_bf16(
                        pf[i], as_frag(vv[t]), o[i][t], 0, 0, 0);
            __builtin_amdgcn_s_setprio(0);
        }
    }

    // reduce l partials across the 16 lanes of each row
#pragma unroll
    for (int i = 0; i < 4; ++i)
#pragma unroll
        for (int r = 0; r < 4; ++r) {
            float ls = l[i][r];
            ls += __shfl_xor(ls, 1);
            ls += __shfl_xor(ls, 2);
            ls += __shfl_xor(ls, 4);
            ls += __shfl_xor(ls, 8);
            l[i][r] = ls;
        }

    // merge j-halves: wj==1 dumps partial O,l to LDS; wj==0 combines+stores
    __syncthreads();
    float* obuf = (float*)Ps;             // [2][64][65] floats
    float* lbuf = obuf + 2 * 64 * 65;     // [2][64] floats
    if (wj == 1) {
#pragma unroll
        for (int i = 0; i < 4; ++i)
#pragma unroll
            for (int r = 0; r < 4; ++r) {
                int rl = 16 * i + quad * 4 + r;
#pragma unroll
                for (int t = 0; t < 4; ++t)
                    obuf[(wq * 64 + rl) * 65 + 16 * t + lr] = o[i][t][r];
                if (lr == 0) lbuf[wq * 64 + rl] = l[i][r];
            }
    }
    __syncthreads();
    if (wj == 0) {
#pragma unroll
        for (int i = 0; i < 4; ++i)
#pragma unroll
            for (int r = 0; r < 4; ++r) {
                int rl = 16 * i + quad * 4 + r;
                float inv = 1.0f / (l[i][r] + lbuf[wq * 64 + rl]);
                int row = q0 + 64 * wq + rl;
                size_t base = ((size_t)(b * SS + row)) * QKVS + h * 64;
#pragma unroll
                for (int t = 0; t < 4; ++t)
                    ctx[base + 16 * t + lr] =
                        f2bf((o[i][t][r] + obuf[(wq * 64 + rl) * 65 + 16 * t + lr]) * inv);
            }
    }
}

// ---------------------------------------------------------------------------
extern "C" void kernel_launch(void* const* d_in, const int* in_sizes, int n_in,
                              void* d_out, int out_size, void* d_ws, size_t ws_size,
                              hipStream_t stream) {
    const float* x     = (const float*)d_in[0];
    const float* Wq    = (const float*)d_in[1];
    const float* Wk    = (const float*)d_in[2];
    const float* Wv    = (const float*)d_in[3];
    const float* Wo    = (const float*)d_in[4];
    const float* ln1g  = (const float*)d_in[5];
    const float* ln1b  = (const float*)d_in[6];
    const float* fc1w  = (const float*)d_in[7];
    const float* fc1b  = (const float*)d_in[8];
    const float* fc2w  = (const float*)d_in[9];
    const float* fc2b  = (const float*)d_in[10];
    const float* ln2g  = (const float*)d_in[11];
    const float* ln2b  = (const float*)d_in[12];
    float* out = (float*)d_out;

    // workspace (peak 80MB):
    //  0..16 : weights (wqkvT@0 [3072x1024] 6MB, woT@6, fc1T@8, fc2T@12)
    // 16..32 : xn -> vt (after QKV GEMM) -> hn (after attention)
    // 32..80 : qkvb [8192][3072] 48MB; ctx lives in its V-cols (2048..3071)
    //          after transpose_v consumes them; h1 [8192][2048] overlays
    //          bytes 32..64MB once ctx is dead (after Wo GEMM).
    char* ws = (char*)d_ws;
    const size_t MB = 1024 * 1024;
    unsigned short* wqkvT = (unsigned short*)(ws + 0 * MB);
    unsigned short* woT   = (unsigned short*)(ws + 6 * MB);
    unsigned short* fc1T  = (unsigned short*)(ws + 8 * MB);
    unsigned short* fc2T  = (unsigned short*)(ws + 12 * MB);
    unsigned short* xn    = (unsigned short*)(ws + 16 * MB);
    unsigned short* vt    = xn;
    unsigned short* hn    = xn;
    unsigned short* qkvb  = (unsigned short*)(ws + 32 * MB);
    unsigned short* ctx   = qkvb + 2048;        // V-cols, stride QKVS
    unsigned short* h1    = qkvb;               // reuse after ctx dead

    dim3 blk(256);

    transpose_all<<<2048, blk, 0, stream>>>(Wq, Wk, Wv, Wo, fc1w, fc2w,
                                            wqkvT, woT, fc1T, fc2T);

    layernorm_bf16<<<NTOK, blk, 0, stream>>>(x, ln1g, ln1b, xn, 1e-5f);

    // fused QKV projection on the 8-phase 256^2 template:
    // 32 m-tiles x 12 n-tiles = 384 blocks (%8==0); Q cols pre-scaled
    gemm_8ph<<<384, 512, 0, stream>>>(xn, wqkvT, nullptr, qkvb,
                                      NTOK, QKVS, 1024, 0, 1024, 1024);
    transpose_v<<<dim3(8, 64), blk, 0, stream>>>(qkvb + 2048, vt);  // vt over xn

    attention_mfma10<<<1024, blk, 0, stream>>>(qkvb, vt, ctx);

    // Wo GEMM reads ctx (stride QKVS) -> fp32 out with residual x
    // (N=1024 -> 256^2 grid would be 128 blocks = half GPU; keep 128^2 db)
    gemm_db<<<512, blk, 0, stream>>>(ctx, woT, nullptr, x, out, nullptr,
                                     NTOK, 1024, 1024, 0, QKVS, 0);
    layernorm_bf16<<<NTOK, blk, 0, stream>>>(out, ln2g, ln2b, hn, 1e-6f);
    // fc1 on the 8-phase template: 32 x 8 = 256 blocks
    gemm_8ph<<<256, 512, 0, stream>>>(hn, fc1T, fc1b, h1,
                                      NTOK, 2048, 1024, 1, 1024, 0);
    gemm_db<<<512, blk, 0, stream>>>(h1, fc2T, fc2b, out, out, nullptr,
                                     NTOK, 1024, 2048, 0, 2048, 0);
}

// Round 8
// 491.055 us; speedup vs baseline: 1.7417x; 1.0696x over previous
//
#include <hip/hip_runtime.h>

// Problem constants
#define BB   4
#define SS   2048
#define DDIM 1024
#define HH   16
#define DKK  64
#define FFF  2048
#define NTOK (BB * SS)   // 8192
#define QKVS 3072        // fused qkv row stride
#define SCALE_Q 0.18033688011112042f   // 0.125 * log2(e), folded into Q

typedef __bf16 bf16x8 __attribute__((ext_vector_type(8)));
typedef float floatx4 __attribute__((ext_vector_type(4)));

__device__ __forceinline__ unsigned short f2bf(float f) {
    union { float f; unsigned u; } v; v.f = f;
    unsigned r = v.u + 0x7fffu + ((v.u >> 16) & 1u);   // RNE
    return (unsigned short)(r >> 16);
}

// pack hi16(a),hi16(b) -> one u32 (bf16 truncation x2 in one v_perm)
__device__ __forceinline__ unsigned pack_bf_trunc(float a, float b) {
    union { float f; unsigned u; } x, y; x.f = a; y.f = b;
    return __builtin_amdgcn_perm(y.u, x.u, 0x07060302u);
}

__device__ __forceinline__ bf16x8 as_frag(uint4 v) {
    union { uint4 u; bf16x8 f; } c; c.u = v; return c.f;
}

__device__ __forceinline__ void async_copy16(const unsigned short* g, unsigned short* l) {
    __builtin_amdgcn_global_load_lds(
        (const __attribute__((address_space(1))) void*)g,
        (__attribute__((address_space(3))) void*)l, 16, 0, 0);
}

// ---------------------------------------------------------------------------
// All six weight transposes fused: fp32 W[K][N] -> bf16 Wt[N][K], 64x64 tiles
// ---------------------------------------------------------------------------
__global__ __launch_bounds__(256) void transpose_all(
    const float* __restrict__ Wq, const float* __restrict__ Wk,
    const float* __restrict__ Wv, const float* __restrict__ Wo,
    const float* __restrict__ fc1, const float* __restrict__ fc2,
    unsigned short* __restrict__ wqkvT, unsigned short* __restrict__ woT,
    unsigned short* __restrict__ fc1T, unsigned short* __restrict__ fc2T) {
    __shared__ float tile[64][65];
    int t = blockIdx.x;
    const float* src; unsigned short* dst; int K, N, tl;
    if (t < 256)       { src = Wq;  dst = wqkvT;                       K = 1024; N = 1024; tl = t; }
    else if (t < 512)  { src = Wk;  dst = wqkvT + (size_t)1024 * 1024; K = 1024; N = 1024; tl = t - 256; }
    else if (t < 768)  { src = Wv;  dst = wqkvT + (size_t)2048 * 1024; K = 1024; N = 1024; tl = t - 512; }
    else if (t < 1024) { src = Wo;  dst = woT;                         K = 1024; N = 1024; tl = t - 768; }
    else if (t < 1536) { src = fc1; dst = fc1T;                        K = 1024; N = 2048; tl = t - 1024; }
    else               { src = fc2; dst = fc2T;                        K = 2048; N = 1024; tl = t - 1536; }
    int kt = K >> 6;
    int k0 = (tl & (kt - 1)) * 64, n0 = (tl / kt) * 64;
    int tid = threadIdx.x;
#pragma unroll
    for (int i = 0; i < 16; ++i) {
        int e = i * 256 + tid;
        int r = e >> 6, c = e & 63;
        tile[r][c] = src[(size_t)(k0 + r) * N + (n0 + c)];
    }
    __syncthreads();
#pragma unroll
    for (int i = 0; i < 16; ++i) {
        int e = i * 256 + tid;
        int r = e >> 6, c = e & 63;
        dst[(size_t)(n0 + r) * K + (k0 + c)] = f2bf(tile[c][r]);
    }
}

// ---------------------------------------------------------------------------
// LayerNorm: fp32 in -> bf16 out
// ---------------------------------------------------------------------------
__device__ __forceinline__ float block_sum256(float s) {
#pragma unroll
    for (int o = 32; o > 0; o >>= 1) s += __shfl_xor(s, o);
    __shared__ float partial[4];
    int w = threadIdx.x >> 6;
    __syncthreads();
    if ((threadIdx.x & 63) == 0) partial[w] = s;
    __syncthreads();
    return partial[0] + partial[1] + partial[2] + partial[3];
}

__global__ __launch_bounds__(256) void layernorm_bf16(
    const float* __restrict__ x, const float* __restrict__ g,
    const float* __restrict__ b, unsigned short* __restrict__ out, float eps) {
    size_t row = blockIdx.x;
    const float* xr = x + row * DDIM;
    int tid = threadIdx.x;
    float4 v = *(const float4*)(xr + tid * 4);
    float mu = block_sum256(v.x + v.y + v.z + v.w) * (1.0f / DDIM);
    float dx = v.x - mu, dy = v.y - mu, dz = v.z - mu, dw = v.w - mu;
    float var = block_sum256(dx * dx + dy * dy + dz * dz + dw * dw) * (1.0f / DDIM);
    float rstd = rsqrtf(var + eps);
    int c = tid * 4;
    unsigned short* o = out + row * DDIM + c;
    o[0] = f2bf(dx * rstd * g[c + 0] + b[c + 0]);
    o[1] = f2bf(dy * rstd * g[c + 1] + b[c + 1]);
    o[2] = f2bf(dz * rstd * g[c + 2] + b[c + 2]);
    o[3] = f2bf(dw * rstd * g[c + 3] + b[c + 3]);
}

// ---------------------------------------------------------------------------
// 256x256 8-phase GEMM (m201 template). 512 threads = 8 waves (2Mx4N), BK=64,
// 128 KiB LDS, 1 block/CU. Used for QKV (384 blocks) and fc1 (256 blocks).
// (verified round 1: end-to-end -18.5us vs gemm_db on QKV+fc1)
// ---------------------------------------------------------------------------
#define BAR8() asm volatile("s_barrier" ::: "memory")
#define WAIT_LGKM0() do { asm volatile("s_waitcnt lgkmcnt(0)" ::: "memory"); \
                          __builtin_amdgcn_sched_barrier(0); } while (0)

#define STAGE_A8(T, h) do { \
    const unsigned short* s_ = A + (size_t)(m0 + (h) * 128 + rowin) * lda + (T) * 64; \
    unsigned short* d_ = Asm + ((((T) & 1) << 14) + ((h) << 13) + sdst); \
    async_copy16(s_ + c0, d_); async_copy16(s_ + c1, d_ + 512); } while (0)

#define STAGE_B8(T, h) do { \
    const unsigned short* s_ = Bt + (size_t)(n0 + (h) * 128 + rowin) * (size_t)K + (T) * 64; \
    unsigned short* d_ = Bsm + ((((T) & 1) << 14) + ((h) << 13) + sdst); \
    async_copy16(s_ + c0, d_); async_copy16(s_ + c1, d_ + 512); } while (0)

#define READ_A4(P, ibase) \
    _Pragma("unroll") \
    for (int i = 0; i < 4; ++i) \
        _Pragma("unroll") \
        for (int kk = 0; kk < 2; ++kk) \
            a_f[i][kk] = *(const bf16x8*)&Asm[(P) + aoff + ((((ibase) + i) * 2 + kk) << 9)];

#define READ_B8(P) \
    _Pragma("unroll") \
    for (int t = 0; t < 4; ++t) \
        _Pragma("unroll") \
        for (int kk = 0; kk < 2; ++kk) \
            b_f[t][kk] = *(const bf16x8*)&Bsm[(P) + boff + ((t * 2 + kk) << 9)];

#define MFMA_Q(ilo, tlo) \
    _Pragma("unroll") \
    for (int i = 0; i < 4; ++i) \
        _Pragma("unroll") \
        for (int t = 0; t < 2; ++t) \
            _Pragma("unroll") \
            for (int kk = 0; kk < 2; ++kk) \
                acc[(ilo) + i][(tlo) + t] = __builtin_amdgcn_mfma_f32_16x16x32_bf16( \
                    a_f[i][kk], b_f[(tlo) + t][kk], acc[(ilo) + i][(tlo) + t], 0, 0, 0);

__global__ __launch_bounds__(512, 2) void gemm_8ph(
    const unsigned short* __restrict__ A, const unsigned short* __restrict__ Bt,
    const float* __restrict__ bias, unsigned short* __restrict__ outh,
    int M, int N, int K, int relu, int lda, int qcols) {
    __shared__ unsigned short Asm[32768];
    __shared__ unsigned short Bsm[32768];

    int tid = threadIdx.x;
    int w = tid >> 6, lane = tid & 63;
    int lr = lane & 15, quad = lane >> 4;

    int nwg = gridDim.x;
    int bid = blockIdx.x;
    int swz = (bid & 7) * (nwg >> 3) + (bid >> 3);   // XCD-contiguous
    int m0 = (swz & 31) << 8;
    int n0 = (swz >> 5) << 8;

    int rowin = (w << 4) + (lane >> 2);              // 0..127
    int q = (lane & 3) ^ ((lane >> 5) << 1);         // inverse swizzle
    int c0 = q * 8, c1 = 32 + q * 8;
    int sdst = w << 10;

    int qsw8 = ((lane & 8) ? (quad ^ 2) : quad) * 8;
    int aoff = (w >> 2) * 8192 + lr * 32 + qsw8;
    int boff = ((w & 3) >> 1) * 8192 + ((w & 3) & 1) * 4096 + lr * 32 + qsw8;
    int wm = (w >> 2) * 128, wn = (w & 3) * 64;

    floatx4 acc[8][4];
#pragma unroll
    for (int i = 0; i < 8; ++i)
#pragma unroll
        for (int t = 0; t < 4; ++t)
#pragma unroll
            for (int r = 0; r < 4; ++r) acc[i][t][r] = 0.0f;

    int NT = K >> 6;

    STAGE_B8(0, 0); STAGE_B8(0, 1); STAGE_A8(0, 0); STAGE_A8(0, 1);
    STAGE_B8(1, 0); STAGE_B8(1, 1); STAGE_A8(1, 0);
    asm volatile("s_waitcnt vmcnt(4)" ::: "memory");
    BAR8();

    bf16x8 a_f[4][2], b_f[4][2];

    for (int T = 0; T < NT; T += 2) {
        READ_A4(0, 0);
        READ_B8(0);
        if (T + 1 < NT) STAGE_A8(T + 1, 1);
        BAR8(); WAIT_LGKM0();
        __builtin_amdgcn_s_setprio(1); MFMA_Q(0, 0); __builtin_amdgcn_s_setprio(0);
        BAR8();
        if (T + 2 < NT) STAGE_B8(T + 2, 0);
        BAR8();
        __builtin_amdgcn_s_setprio(1); MFMA_Q(0, 2); __builtin_amdgcn_s_setprio(0);
        BAR8();
        READ_A4(0, 4);
        if (T + 2 < NT) STAGE_B8(T + 2, 1);
        BAR8(); WAIT_LGKM0();
        __builtin_amdgcn_s_setprio(1); MFMA_Q(4, 0); __builtin_amdgcn_s_setprio(0);
        BAR8();
        if (T + 2 < NT) STAGE_A8(T + 2, 0);
        BAR8();
        __builtin_amdgcn_s_setprio(1); MFMA_Q(4, 2); __builtin_amdgcn_s_setprio(0);
        if (T + 2 < NT) { asm volatile("s_waitcnt vmcnt(6)" ::: "memory"); }
        else            { asm volatile("s_waitcnt vmcnt(0)" ::: "memory"); }
        BAR8();

        READ_A4(16384, 0);
        READ_B8(16384);
        if (T + 2 < NT) STAGE_A8(T + 2, 1);
        BAR8(); WAIT_LGKM0();
        __builtin_amdgcn_s_setprio(1); MFMA_Q(0, 0); __builtin_amdgcn_s_setprio(0);
        BAR8();
        if (T + 3 < NT) STAGE_B8(T + 3, 0);
        BAR8();
        __builtin_amdgcn_s_setprio(1); MFMA_Q(0, 2); __builtin_amdgcn_s_setprio(0);
        BAR8();
        READ_A4(16384, 4);
        if (T + 3 < NT) STAGE_B8(T + 3, 1);
        BAR8(); WAIT_LGKM0();
        __builtin_amdgcn_s_setprio(1); MFMA_Q(4, 0); __builtin_amdgcn_s_setprio(0);
        BAR8();
        if (T + 3 < NT) STAGE_A8(T + 3, 0);
        BAR8();
        __builtin_amdgcn_s_setprio(1); MFMA_Q(4, 2); __builtin_amdgcn_s_setprio(0);
        if (T + 3 < NT) { asm volatile("s_waitcnt vmcnt(6)" ::: "memory"); }
        else            { asm volatile("s_waitcnt vmcnt(0)" ::: "memory"); }
        BAR8();
    }

#pragma unroll
    for (int i = 0; i < 8; ++i) {
#pragma unroll
        for (int t = 0; t < 4; ++t) {
            int col = n0 + wn + 16 * t + lr;
            float cs = (col < qcols) ? SCALE_Q : 1.0f;
            float bv = bias ? bias[col] : 0.0f;
#pragma unroll
            for (int r = 0; r < 4; ++r) {
                int row = m0 + wm + 16 * i + quad * 4 + r;
                float v = acc[i][t][r] + bv;
                if (relu) v = fmaxf(v, 0.0f);
                outh[(size_t)row * N + col] = f2bf(v * cs);
            }
        }
    }
}

// ---------------------------------------------------------------------------
// NEW: 128x256-tile 8-phase GEMM for N=1024 outputs (Wo, fc2): grid = 64x4 =
// 256 blocks = exactly full chip (vs 256^2's 128-block half-fill, vs gemm_db's
// ~900 TF ceiling). Derivation from the verified 256^2 template:
//  - B-side byte-identical (128-row halves, 2 loads/thread, same LDS layout).
//  - A-side: 64-row halves (8KB) = 1 load/thread; wave w stages subtile w
//    (rows 16*(w>>1)..+15 of the half, col-half w&1) -> lane l lands at
//    l*16B = (l>>2)*32 + (l&3)*8 elems = exactly the [16][32]-subtile inner
//    layout. Inverse swizzle on source col: (lane&3)^((lane&32)?2:0).
//  - Stage slots per tile: [A1(T+1) @ph1 | B0,B1(T+2) @ph2,3 | A0(T+2) @ph4].
//    Counted vmcnt at ph4 = loads issued after tile(T+1)'s last half-tile
//    (A1 at T.ph1): B0(2)+B1(2)+A0(1) = vmcnt(5). Prologue: 7 half-tiles,
//    wait tile0 = vmcnt(5). Never 0 mid-loop (T4).
//  - MFMA quadrants 8/phase (acc[4][4], 2i x 2t x 2kk).
//  - Clobber-safe: ALL buf(T) reads in ph1 (A and B); stages into buf(T)
//    begin at ph2 (T+2 stages), after the read-complete lgkmcnt of ph1 and
//    barriers. A1(T+1) targets the opposite buffer, last read 4+ barriers ago.
// fp32 output + residual epilogue (Wo: +x; fc2: in-place += out).
// LDS 96KB -> 1 block/CU.
// ---------------------------------------------------------------------------
#define STAGE_A1B(T, h) do { \
    const unsigned short* s_ = A + (size_t)(m0 + (h) * 64 + rowA) * lda + (T) * 64 + colA; \
    unsigned short* d_ = Asm + ((((T) & 1) << 13) + ((h) << 12) + (w << 9)); \
    async_copy16(s_, d_); } while (0)

#define STAGE_B8B(T, h) do { \
    const unsigned short* s_ = Bt + (size_t)(n0 + (h) * 128 + rowin) * (size_t)K + (T) * 64; \
    unsigned short* d_ = Bsm + ((((T) & 1) << 14) + ((h) << 13) + sdst); \
    async_copy16(s_ + c0, d_); async_copy16(s_ + c1, d_ + 512); } while (0)

#define READ_A4B(PA) \
    _Pragma("unroll") \
    for (int i = 0; i < 4; ++i) \
        _Pragma("unroll") \
        for (int kk = 0; kk < 2; ++kk) \
            a_f[i][kk] = *(const bf16x8*)&Asm[(PA) + aoffb + ((i * 2 + kk) << 9)];

#define READ_B8B(PB) \
    _Pragma("unroll") \
    for (int t = 0; t < 4; ++t) \
        _Pragma("unroll") \
        for (int kk = 0; kk < 2; ++kk) \
            b_f[t][kk] = *(const bf16x8*)&Bsm[(PB) + boff + ((t * 2 + kk) << 9)];

#define MFMA_QB(ilo, tlo) \
    _Pragma("unroll") \
    for (int i = 0; i < 2; ++i) \
        _Pragma("unroll") \
        for (int t = 0; t < 2; ++t) \
            _Pragma("unroll") \
            for (int kk = 0; kk < 2; ++kk) \
                acc[(ilo) + i][(tlo) + t] = __builtin_amdgcn_mfma_f32_16x16x32_bf16( \
                    a_f[(ilo) + i][kk], b_f[(tlo) + t][kk], acc[(ilo) + i][(tlo) + t], 0, 0, 0);

__global__ __launch_bounds__(512, 2) void gemm_8ph_b(
    const unsigned short* __restrict__ A, const unsigned short* __restrict__ Bt,
    const float* __restrict__ bias, const float* __restrict__ resid,
    float* __restrict__ outf, int M, int N, int K, int lda) {
    __shared__ unsigned short Asm[16384];   // 32KB: 2buf x 2half(64r) x 8sub x 512
    __shared__ unsigned short Bsm[32768];   // 64KB: identical to 256^2 template

    int tid = threadIdx.x;
    int w = tid >> 6, lane = tid & 63;
    int lr = lane & 15, quad = lane >> 4;

    int nwg = gridDim.x;                     // 256 (grid%8==0)
    int bid = blockIdx.x;
    int swz = (bid & 7) * (nwg >> 3) + (bid >> 3);
    int m0 = (swz & 63) << 7;                // 64 m-tiles x 128
    int n0 = (swz >> 6) << 8;                // 4 n-tiles x 256

    // B staging geometry (identical to 256^2 template)
    int rowin = (w << 4) + (lane >> 2);
    int q = (lane & 3) ^ ((lane >> 5) << 1);
    int c0 = q * 8, c1 = 32 + q * 8;
    int sdst = w << 10;

    // A staging geometry: wave w -> subtile w of each 64-row half
    int rowA = ((w >> 1) << 4) + (lane >> 2);            // 0..63
    int colA = ((w & 1) << 5) + (((lane & 3) ^ ((lane & 32) ? 2 : 0)) << 3);

    int qsw8 = ((lane & 8) ? (quad ^ 2) : quad) * 8;
    int aoffb = ((w >> 2) << 12) + lr * 32 + qsw8;       // + (2i+kk)<<9
    int boff = ((w & 3) >> 1) * 8192 + ((w & 3) & 1) * 4096 + lr * 32 + qsw8;
    int wm = (w >> 2) * 64, wn = (w & 3) * 64;

    floatx4 acc[4][4];
#pragma unroll
    for (int i = 0; i < 4; ++i)
#pragma unroll
        for (int t = 0; t < 4; ++t)
#pragma unroll
            for (int r = 0; r < 4; ++r) acc[i][t][r] = 0.0f;

    int NT = K >> 6;   // even (16 or 32 here)

    // prologue: t0 fully + t1's B0,B1,A0 ; wait tile0 -> vmcnt(5)
    STAGE_B8B(0, 0); STAGE_B8B(0, 1); STAGE_A1B(0, 0); STAGE_A1B(0, 1);
    STAGE_B8B(1, 0); STAGE_B8B(1, 1); STAGE_A1B(1, 0);
    asm volatile("s_waitcnt vmcnt(5)" ::: "memory");
    BAR8();

    bf16x8 a_f[4][2], b_f[4][2];

    for (int T = 0; T < NT; T += 2) {
        // ======== tile T (buf 0: A @0, B @0) ========
        READ_A4B(0);
        READ_B8B(0);
        if (T + 1 < NT) STAGE_A1B(T + 1, 1);
        BAR8(); WAIT_LGKM0();
        __builtin_amdgcn_s_setprio(1); MFMA_QB(0, 0); __builtin_amdgcn_s_setprio(0);
        BAR8();
        if (T + 2 < NT) STAGE_B8B(T + 2, 0);
        BAR8();
        __builtin_amdgcn_s_setprio(1); MFMA_QB(0, 2); __builtin_amdgcn_s_setprio(0);
        BAR8();
        if (T + 2 < NT) STAGE_B8B(T + 2, 1);
        BAR8();
        __builtin_amdgcn_s_setprio(1); MFMA_QB(2, 0); __builtin_amdgcn_s_setprio(0);
        BAR8();
        if (T + 2 < NT) STAGE_A1B(T + 2, 0);
        BAR8();
        __builtin_amdgcn_s_setprio(1); MFMA_QB(2, 2); __builtin_amdgcn_s_setprio(0);
        if (T + 2 < NT) { asm volatile("s_waitcnt vmcnt(5)" ::: "memory"); }
        else            { asm volatile("s_waitcnt vmcnt(0)" ::: "memory"); }
        BAR8();

        // ======== tile T+1 (buf 1: A @8192, B @16384) ========
        READ_A4B(8192);
        READ_B8B(16384);
        if (T + 2 < NT) STAGE_A1B(T + 2, 1);
        BAR8(); WAIT_LGKM0();
        __builtin_amdgcn_s_setprio(1); MFMA_QB(0, 0); __builtin_amdgcn_s_setprio(0);
        BAR8();
        if (T + 3 < NT) STAGE_B8B(T + 3, 0);
        BAR8();
        __builtin_amdgcn_s_setprio(1); MFMA_QB(0, 2); __builtin_amdgcn_s_setprio(0);
        BAR8();
        if (T + 3 < NT) STAGE_B8B(T + 3, 1);
        BAR8();
        __builtin_amdgcn_s_setprio(1); MFMA_QB(2, 0); __builtin_amdgcn_s_setprio(0);
        BAR8();
        if (T + 3 < NT) STAGE_A1B(T + 3, 0);
        BAR8();
        __builtin_amdgcn_s_setprio(1); MFMA_QB(2, 2); __builtin_amdgcn_s_setprio(0);
        if (T + 3 < NT) { asm volatile("s_waitcnt vmcnt(5)" ::: "memory"); }
        else            { asm volatile("s_waitcnt vmcnt(0)" ::: "memory"); }
        BAR8();
    }

    // epilogue: fp32 out + optional bias/residual
#pragma unroll
    for (int i = 0; i < 4; ++i) {
#pragma unroll
        for (int t = 0; t < 4; ++t) {
            int col = n0 + wn + 16 * t + lr;
            float bv = bias ? bias[col] : 0.0f;
#pragma unroll
            for (int r = 0; r < 4; ++r) {
                int row = m0 + wm + 16 * i + quad * 4 + r;
                size_t idx = (size_t)row * N + col;
                float v = acc[i][t][r] + bv;
                if (resid) v += resid[idx];
                outf[idx] = v;
            }
        }
    }
}

// ---------------------------------------------------------------------------
// V transpose: vsrc rows (stride QKVS) -> vt[bh][dk][s'] with per-64-block
// permutation sigma(u) = 4*(u&15) + (u>>4)  (matches attention P-writes).
// ---------------------------------------------------------------------------
__global__ __launch_bounds__(256) void transpose_v(
    const unsigned short* __restrict__ vsrc, unsigned short* __restrict__ vt) {
    int bh = blockIdx.y;
    int b = bh >> 4, h = bh & 15;
    int s = blockIdx.x * 256 + threadIdx.x;
    size_t inbase = ((size_t)(b * SS + s)) * QKVS + h * 64;
    size_t outbase = (size_t)bh * 64 * SS;
    int sp = (s & ~63) + 4 * (s & 15) + ((s >> 4) & 3);
#pragma unroll
    for (int dk8 = 0; dk8 < 8; ++dk8) {
        uint4 raw = *(const uint4*)(vsrc + inbase + dk8 * 8);
        const unsigned short* ph = (const unsigned short*)&raw;
#pragma unroll
        for (int i = 0; i < 8; ++i)
            vt[outbase + (size_t)(dk8 * 8 + i) * SS + sp] = ph[i];
    }
}

// ---------------------------------------------------------------------------
// Flash attention v12 (round-7 verified best: 149.3us): round-1 structure
// (registers-resident Q, (256,2), compiler-scheduled loads) + T5 setprio
// around MFMA clusters (+2%, m191-consistent).
// ctx is written into the dead V-columns of the qkv buffer (stride QKVS).
// ---------------------------------------------------------------------------
#define PST 68    // Ps row stride (bf16)

__global__ __launch_bounds__(256, 2) void attention_mfma10(
    const unsigned short* __restrict__ qkv, const unsigned short* __restrict__ vt,
    unsigned short* __restrict__ ctx /* = qkv + 2048, stride QKVS */) {
    __shared__ unsigned short Ps[256 * PST];   // 34816 B; reused by epilogue

    int tid = threadIdx.x;
    int wave = tid >> 6, lane = tid & 63;
    int lr = lane & 15, quad = lane >> 4;
    int wq = wave >> 1, wj = wave & 1;

    int bid = blockIdx.x;
    int bh = bid & 63;                 // same bh -> same XCD
    int qt = bid >> 6;
    int b = bh >> 4, h = bh & 15;
    int q0 = qt * 128;
    size_t q_base = ((size_t)b * SS) * QKVS + h * 64;
    size_t k_base = q_base + 1024;
    size_t vt_base = (size_t)bh * 64 * SS;

    uint4 af[4][2];
#pragma unroll
    for (int i = 0; i < 4; ++i)
#pragma unroll
        for (int kk = 0; kk < 2; ++kk)
            af[i][kk] = *(const uint4*)(qkv + q_base +
                (size_t)(q0 + 64 * wq + 16 * i + lr) * QKVS + kk * 32 + quad * 8);

    floatx4 o[4][4];
    float l[4][4];
#pragma unroll
    for (int i = 0; i < 4; ++i)
#pragma unroll
        for (int t = 0; t < 4; ++t) {
#pragma unroll
            for (int r = 0; r < 4; ++r) o[i][t][r] = 0.0f;
            l[i][t] = 0.0f;
        }
    floatx4 zf;
#pragma unroll
    for (int r = 0; r < 4; ++r) zf[r] = 0.0f;

    unsigned short* myPs = &Ps[wave * 64 * PST];

    for (int jt = 0; jt < SS / 128; ++jt) {
        int j0 = jt * 128 + 64 * wj;

        floatx4 s[4][4];
        {
            uint4 bv[4];
#pragma unroll
            for (int t = 0; t < 4; ++t)
                bv[t] = *(const uint4*)(qkv + k_base +
                    (size_t)(j0 + 16 * t + lr) * QKVS + quad * 8);
            __builtin_amdgcn_s_setprio(1);
#pragma unroll
            for (int i = 0; i < 4; ++i)
#pragma unroll
                for (int t = 0; t < 4; ++t)
                    s[i][t] = __builtin_amdgcn_mfma_f32_16x16x32_bf16(
                        as_frag(af[i][0]), as_frag(bv[t]), zf, 0, 0, 0);
            __builtin_amdgcn_s_setprio(0);
        }
        {
            uint4 bv[4];
#pragma unroll
            for (int t = 0; t < 4; ++t)
                bv[t] = *(const uint4*)(qkv + k_base +
                    (size_t)(j0 + 16 * t + lr) * QKVS + 32 + quad * 8);
            __builtin_amdgcn_s_setprio(1);
#pragma unroll
            for (int i = 0; i < 4; ++i)
#pragma unroll
                for (int t = 0; t < 4; ++t)
                    s[i][t] = __builtin_amdgcn_mfma_f32_16x16x32_bf16(
                        as_frag(af[i][1]), as_frag(bv[t]), s[i][t], 0, 0, 0);
            __builtin_amdgcn_s_setprio(0);
        }

#pragma unroll
        for (int i = 0; i < 4; ++i) {
#pragma unroll
            for (int r = 0; r < 4; ++r) {
                float p0 = exp2f(s[i][0][r]);
                float p1 = exp2f(s[i][1][r]);
                float p2 = exp2f(s[i][2][r]);
                float p3 = exp2f(s[i][3][r]);
                l[i][r] += (p0 + p1) + (p2 + p3);
                uint2 w;
                w.x = pack_bf_trunc(p0, p1);
                w.y = pack_bf_trunc(p2, p3);
                *(uint2*)&myPs[(16 * i + quad * 4 + r) * PST + 4 * lr] = w;
            }
        }

#pragma unroll
        for (int kk = 0; kk < 2; ++kk) {
            uint4 vv[4];
#pragma unroll
            for (int t = 0; t < 4; ++t)
                vv[t] = *(const uint4*)(vt + vt_base +
                    (size_t)(16 * t + lr) * SS + j0 + kk * 32 + quad * 8);
            bf16x8 pf[4];
#pragma unroll
            for (int i = 0; i < 4; ++i)
                pf[i] = *(const bf16x8*)&myPs[(16 * i + lr) * PST + kk * 32 + quad * 8];
            __builtin_amdgcn_s_setprio(1);
#pragma unroll
            for (int i = 0; i < 4; ++i)
#pragma unroll
                for (int t = 0; t < 4; ++t)
                    o[i][t] = __builtin_amdgcn_mfma_f32_16x16x32_bf16(
                        pf[i], as_frag(vv[t]), o[i][t], 0, 0, 0);
            __builtin_amdgcn_s_setprio(0);
        }
    }

#pragma unroll
    for (int i = 0; i < 4; ++i)
#pragma unroll
        for (int r = 0; r < 4; ++r) {
            float ls = l[i][r];
            ls += __shfl_xor(ls, 1);
            ls += __shfl_xor(ls, 2);
            ls += __shfl_xor(ls, 4);
            ls += __shfl_xor(ls, 8);
            l[i][r] = ls;
        }

    __syncthreads();
    float* obuf = (float*)Ps;             // [2][64][65] floats
    float* lbuf = obuf + 2 * 64 * 65;     // [2][64] floats
    if (wj == 1) {
#pragma unroll
        for (int i = 0; i < 4; ++i)
#pragma unroll
            for (int r = 0; r < 4; ++r) {
                int rl = 16 * i + quad * 4 + r;
#pragma unroll
                for (int t = 0; t < 4; ++t)
                    obuf[(wq * 64 + rl) * 65 + 16 * t + lr] = o[i][t][r];
                if (lr == 0) lbuf[wq * 64 + rl] = l[i][r];
            }
    }
    __syncthreads();
    if (wj == 0) {
#pragma unroll
        for (int i = 0; i < 4; ++i)
#pragma unroll
            for (int r = 0; r < 4; ++r) {
                int rl = 16 * i + quad * 4 + r;
                float inv = 1.0f / (l[i][r] + lbuf[wq * 64 + rl]);
                int row = q0 + 64 * wq + rl;
                size_t base = ((size_t)(b * SS + row)) * QKVS + h * 64;
#pragma unroll
                for (int t = 0; t < 4; ++t)
                    ctx[base + 16 * t + lr] =
                        f2bf((o[i][t][r] + obuf[(wq * 64 + rl) * 65 + 16 * t + lr]) * inv);
            }
    }
}

// ---------------------------------------------------------------------------
extern "C" void kernel_launch(void* const* d_in, const int* in_sizes, int n_in,
                              void* d_out, int out_size, void* d_ws, size_t ws_size,
                              hipStream_t stream) {
    const float* x     = (const float*)d_in[0];
    const float* Wq    = (const float*)d_in[1];
    const float* Wk    = (const float*)d_in[2];
    const float* Wv    = (const float*)d_in[3];
    const float* Wo    = (const float*)d_in[4];
    const float* ln1g  = (const float*)d_in[5];
    const float* ln1b  = (const float*)d_in[6];
    const float* fc1w  = (const float*)d_in[7];
    const float* fc1b  = (const float*)d_in[8];
    const float* fc2w  = (const float*)d_in[9];
    const float* fc2b  = (const float*)d_in[10];
    const float* ln2g  = (const float*)d_in[11];
    const float* ln2b  = (const float*)d_in[12];
    float* out = (float*)d_out;

    // workspace (peak 80MB): see round-1 comment for the overlay plan
    char* ws = (char*)d_ws;
    const size_t MB = 1024 * 1024;
    unsigned short* wqkvT = (unsigned short*)(ws + 0 * MB);
    unsigned short* woT   = (unsigned short*)(ws + 6 * MB);
    unsigned short* fc1T  = (unsigned short*)(ws + 8 * MB);
    unsigned short* fc2T  = (unsigned short*)(ws + 12 * MB);
    unsigned short* xn    = (unsigned short*)(ws + 16 * MB);
    unsigned short* vt    = xn;
    unsigned short* hn    = xn;
    unsigned short* qkvb  = (unsigned short*)(ws + 32 * MB);
    unsigned short* ctx   = qkvb + 2048;        // V-cols, stride QKVS
    unsigned short* h1    = qkvb;               // reuse after ctx dead

    dim3 blk(256);

    transpose_all<<<2048, blk, 0, stream>>>(Wq, Wk, Wv, Wo, fc1w, fc2w,
                                            wqkvT, woT, fc1T, fc2T);

    layernorm_bf16<<<NTOK, blk, 0, stream>>>(x, ln1g, ln1b, xn, 1e-5f);

    // fused QKV projection: 256^2 8-phase, 384 blocks; Q cols pre-scaled
    gemm_8ph<<<384, 512, 0, stream>>>(xn, wqkvT, nullptr, qkvb,
                                      NTOK, QKVS, 1024, 0, 1024, 1024);
    transpose_v<<<dim3(8, 64), blk, 0, stream>>>(qkvb + 2048, vt);  // vt over xn

    attention_mfma10<<<1024, blk, 0, stream>>>(qkvb, vt, ctx);

    // Wo GEMM on the 128x256 8-phase variant: 64x4 = 256 blocks (full chip)
    gemm_8ph_b<<<256, 512, 0, stream>>>(ctx, woT, nullptr, x, out,
                                        NTOK, 1024, 1024, QKVS);
    layernorm_bf16<<<NTOK, blk, 0, stream>>>(out, ln2g, ln2b, hn, 1e-6f);
    // fc1: 256^2 8-phase, 256 blocks (exact fill)
    gemm_8ph<<<256, 512, 0, stream>>>(hn, fc1T, fc1b, h1,
                                      NTOK, 2048, 1024, 1, 1024, 0);
    // fc2 on the 128x256 8-phase variant: in-place residual accumulate
    gemm_8ph_b<<<256, 512, 0, stream>>>(h1, fc2T, fc2b, out, out,
                                        NTOK, 1024, 2048, 2048);
}

// Round 10
// 489.351 us; speedup vs baseline: 1.7478x; 1.0035x over previous
//
#include <hip/hip_runtime.h>

// Problem constants
#define BB   4
#define SS   2048
#define DDIM 1024
#define HH   16
#define DKK  64
#define FFF  2048
#define NTOK (BB * SS)   // 8192
#define QKVS 3072        // fused qkv row stride
#define SCALE_Q 0.18033688011112042f   // 0.125 * log2(e), folded into Q

typedef __bf16 bf16x8 __attribute__((ext_vector_type(8)));
typedef float floatx4 __attribute__((ext_vector_type(4)));

__device__ __forceinline__ unsigned short f2bf(float f) {
    union { float f; unsigned u; } v; v.f = f;
    unsigned r = v.u + 0x7fffu + ((v.u >> 16) & 1u);   // RNE
    return (unsigned short)(r >> 16);
}

// pack hi16(a),hi16(b) -> one u32 (bf16 truncation x2 in one v_perm)
__device__ __forceinline__ unsigned pack_bf_trunc(float a, float b) {
    union { float f; unsigned u; } x, y; x.f = a; y.f = b;
    return __builtin_amdgcn_perm(y.u, x.u, 0x07060302u);
}

__device__ __forceinline__ bf16x8 as_frag(uint4 v) {
    union { uint4 u; bf16x8 f; } c; c.u = v; return c.f;
}

__device__ __forceinline__ void async_copy16(const unsigned short* g, unsigned short* l) {
    __builtin_amdgcn_global_load_lds(
        (const __attribute__((address_space(1))) void*)g,
        (__attribute__((address_space(3))) void*)l, 16, 0, 0);
}

// ---------------------------------------------------------------------------
// All six weight transposes fused: fp32 W[K][N] -> bf16 Wt[N][K], 64x64 tiles
// ---------------------------------------------------------------------------
__global__ __launch_bounds__(256) void transpose_all(
    const float* __restrict__ Wq, const float* __restrict__ Wk,
    const float* __restrict__ Wv, const float* __restrict__ Wo,
    const float* __restrict__ fc1, const float* __restrict__ fc2,
    unsigned short* __restrict__ wqkvT, unsigned short* __restrict__ woT,
    unsigned short* __restrict__ fc1T, unsigned short* __restrict__ fc2T) {
    __shared__ float tile[64][65];
    int t = blockIdx.x;
    const float* src; unsigned short* dst; int K, N, tl;
    if (t < 256)       { src = Wq;  dst = wqkvT;                       K = 1024; N = 1024; tl = t; }
    else if (t < 512)  { src = Wk;  dst = wqkvT + (size_t)1024 * 1024; K = 1024; N = 1024; tl = t - 256; }
    else if (t < 768)  { src = Wv;  dst = wqkvT + (size_t)2048 * 1024; K = 1024; N = 1024; tl = t - 512; }
    else if (t < 1024) { src = Wo;  dst = woT;                         K = 1024; N = 1024; tl = t - 768; }
    else if (t < 1536) { src = fc1; dst = fc1T;                        K = 1024; N = 2048; tl = t - 1024; }
    else               { src = fc2; dst = fc2T;                        K = 2048; N = 1024; tl = t - 1536; }
    int kt = K >> 6;
    int k0 = (tl & (kt - 1)) * 64, n0 = (tl / kt) * 64;
    int tid = threadIdx.x;
#pragma unroll
    for (int i = 0; i < 16; ++i) {
        int e = i * 256 + tid;
        int r = e >> 6, c = e & 63;
        tile[r][c] = src[(size_t)(k0 + r) * N + (n0 + c)];
    }
    __syncthreads();
#pragma unroll
    for (int i = 0; i < 16; ++i) {
        int e = i * 256 + tid;
        int r = e >> 6, c = e & 63;
        dst[(size_t)(n0 + r) * K + (k0 + c)] = f2bf(tile[c][r]);
    }
}

// ---------------------------------------------------------------------------
// LayerNorm: fp32 in -> bf16 out
// ---------------------------------------------------------------------------
__device__ __forceinline__ float block_sum256(float s) {
#pragma unroll
    for (int o = 32; o > 0; o >>= 1) s += __shfl_xor(s, o);
    __shared__ float partial[4];
    int w = threadIdx.x >> 6;
    __syncthreads();
    if ((threadIdx.x & 63) == 0) partial[w] = s;
    __syncthreads();
    return partial[0] + partial[1] + partial[2] + partial[3];
}

__global__ __launch_bounds__(256) void layernorm_bf16(
    const float* __restrict__ x, const float* __restrict__ g,
    const float* __restrict__ b, unsigned short* __restrict__ out, float eps) {
    size_t row = blockIdx.x;
    const float* xr = x + row * DDIM;
    int tid = threadIdx.x;
    float4 v = *(const float4*)(xr + tid * 4);
    float mu = block_sum256(v.x + v.y + v.z + v.w) * (1.0f / DDIM);
    float dx = v.x - mu, dy = v.y - mu, dz = v.z - mu, dw = v.w - mu;
    float var = block_sum256(dx * dx + dy * dy + dz * dz + dw * dw) * (1.0f / DDIM);
    float rstd = rsqrtf(var + eps);
    int c = tid * 4;
    unsigned short* o = out + row * DDIM + c;
    o[0] = f2bf(dx * rstd * g[c + 0] + b[c + 0]);
    o[1] = f2bf(dy * rstd * g[c + 1] + b[c + 1]);
    o[2] = f2bf(dz * rstd * g[c + 2] + b[c + 2]);
    o[3] = f2bf(dw * rstd * g[c + 3] + b[c + 3]);
}

// ---------------------------------------------------------------------------
// 256x256 8-phase GEMM (m201 template). 512 threads = 8 waves (2Mx4N), BK=64,
// 128 KiB LDS, 1 block/CU. Used for fc1 (256 blocks = exact full chip).
// ---------------------------------------------------------------------------
#define BAR8() asm volatile("s_barrier" ::: "memory")
#define WAIT_LGKM0() do { asm volatile("s_waitcnt lgkmcnt(0)" ::: "memory"); \
                          __builtin_amdgcn_sched_barrier(0); } while (0)

#define STAGE_A8(T, h) do { \
    const unsigned short* s_ = A + (size_t)(m0 + (h) * 128 + rowin) * lda + (T) * 64; \
    unsigned short* d_ = Asm + ((((T) & 1) << 14) + ((h) << 13) + sdst); \
    async_copy16(s_ + c0, d_); async_copy16(s_ + c1, d_ + 512); } while (0)

#define STAGE_B8(T, h) do { \
    const unsigned short* s_ = Bt + (size_t)(n0 + (h) * 128 + rowin) * (size_t)K + (T) * 64; \
    unsigned short* d_ = Bsm + ((((T) & 1) << 14) + ((h) << 13) + sdst); \
    async_copy16(s_ + c0, d_); async_copy16(s_ + c1, d_ + 512); } while (0)

#define READ_A4(P, ibase) \
    _Pragma("unroll") \
    for (int i = 0; i < 4; ++i) \
        _Pragma("unroll") \
        for (int kk = 0; kk < 2; ++kk) \
            a_f[i][kk] = *(const bf16x8*)&Asm[(P) + aoff + ((((ibase) + i) * 2 + kk) << 9)];

#define READ_B8(P) \
    _Pragma("unroll") \
    for (int t = 0; t < 4; ++t) \
        _Pragma("unroll") \
        for (int kk = 0; kk < 2; ++kk) \
            b_f[t][kk] = *(const bf16x8*)&Bsm[(P) + boff + ((t * 2 + kk) << 9)];

#define MFMA_Q(ilo, tlo) \
    _Pragma("unroll") \
    for (int i = 0; i < 4; ++i) \
        _Pragma("unroll") \
        for (int t = 0; t < 2; ++t) \
            _Pragma("unroll") \
            for (int kk = 0; kk < 2; ++kk) \
                acc[(ilo) + i][(tlo) + t] = __builtin_amdgcn_mfma_f32_16x16x32_bf16( \
                    a_f[i][kk], b_f[(tlo) + t][kk], acc[(ilo) + i][(tlo) + t], 0, 0, 0);

__global__ __launch_bounds__(512, 2) void gemm_8ph(
    const unsigned short* __restrict__ A, const unsigned short* __restrict__ Bt,
    const float* __restrict__ bias, unsigned short* __restrict__ outh,
    int M, int N, int K, int relu, int lda, int qcols) {
    __shared__ unsigned short Asm[32768];
    __shared__ unsigned short Bsm[32768];

    int tid = threadIdx.x;
    int w = tid >> 6, lane = tid & 63;
    int lr = lane & 15, quad = lane >> 4;

    int nwg = gridDim.x;
    int bid = blockIdx.x;
    int swz = (bid & 7) * (nwg >> 3) + (bid >> 3);   // XCD-contiguous
    int m0 = (swz & 31) << 8;
    int n0 = (swz >> 5) << 8;

    int rowin = (w << 4) + (lane >> 2);              // 0..127
    int q = (lane & 3) ^ ((lane >> 5) << 1);         // inverse swizzle
    int c0 = q * 8, c1 = 32 + q * 8;
    int sdst = w << 10;

    int qsw8 = ((lane & 8) ? (quad ^ 2) : quad) * 8;
    int aoff = (w >> 2) * 8192 + lr * 32 + qsw8;
    int boff = ((w & 3) >> 1) * 8192 + ((w & 3) & 1) * 4096 + lr * 32 + qsw8;
    int wm = (w >> 2) * 128, wn = (w & 3) * 64;

    floatx4 acc[8][4];
#pragma unroll
    for (int i = 0; i < 8; ++i)
#pragma unroll
        for (int t = 0; t < 4; ++t)
#pragma unroll
            for (int r = 0; r < 4; ++r) acc[i][t][r] = 0.0f;

    int NT = K >> 6;

    STAGE_B8(0, 0); STAGE_B8(0, 1); STAGE_A8(0, 0); STAGE_A8(0, 1);
    STAGE_B8(1, 0); STAGE_B8(1, 1); STAGE_A8(1, 0);
    asm volatile("s_waitcnt vmcnt(4)" ::: "memory");
    BAR8();

    bf16x8 a_f[4][2], b_f[4][2];

    for (int T = 0; T < NT; T += 2) {
        READ_A4(0, 0);
        READ_B8(0);
        if (T + 1 < NT) STAGE_A8(T + 1, 1);
        BAR8(); WAIT_LGKM0();
        __builtin_amdgcn_s_setprio(1); MFMA_Q(0, 0); __builtin_amdgcn_s_setprio(0);
        BAR8();
        if (T + 2 < NT) STAGE_B8(T + 2, 0);
        BAR8();
        __builtin_amdgcn_s_setprio(1); MFMA_Q(0, 2); __builtin_amdgcn_s_setprio(0);
        BAR8();
        READ_A4(0, 4);
        if (T + 2 < NT) STAGE_B8(T + 2, 1);
        BAR8(); WAIT_LGKM0();
        __builtin_amdgcn_s_setprio(1); MFMA_Q(4, 0); __builtin_amdgcn_s_setprio(0);
        BAR8();
        if (T + 2 < NT) STAGE_A8(T + 2, 0);
        BAR8();
        __builtin_amdgcn_s_setprio(1); MFMA_Q(4, 2); __builtin_amdgcn_s_setprio(0);
        if (T + 2 < NT) { asm volatile("s_waitcnt vmcnt(6)" ::: "memory"); }
        else            { asm volatile("s_waitcnt vmcnt(0)" ::: "memory"); }
        BAR8();

        READ_A4(16384, 0);
        READ_B8(16384);
        if (T + 2 < NT) STAGE_A8(T + 2, 1);
        BAR8(); WAIT_LGKM0();
        __builtin_amdgcn_s_setprio(1); MFMA_Q(0, 0); __builtin_amdgcn_s_setprio(0);
        BAR8();
        if (T + 3 < NT) STAGE_B8(T + 3, 0);
        BAR8();
        __builtin_amdgcn_s_setprio(1); MFMA_Q(0, 2); __builtin_amdgcn_s_setprio(0);
        BAR8();
        READ_A4(16384, 4);
        if (T + 3 < NT) STAGE_B8(T + 3, 1);
        BAR8(); WAIT_LGKM0();
        __builtin_amdgcn_s_setprio(1); MFMA_Q(4, 0); __builtin_amdgcn_s_setprio(0);
        BAR8();
        if (T + 3 < NT) STAGE_A8(T + 3, 0);
        BAR8();
        __builtin_amdgcn_s_setprio(1); MFMA_Q(4, 2); __builtin_amdgcn_s_setprio(0);
        if (T + 3 < NT) { asm volatile("s_waitcnt vmcnt(6)" ::: "memory"); }
        else            { asm volatile("s_waitcnt vmcnt(0)" ::: "memory"); }
        BAR8();
    }

#pragma unroll
    for (int i = 0; i < 8; ++i) {
#pragma unroll
        for (int t = 0; t < 4; ++t) {
            int col = n0 + wn + 16 * t + lr;
            float cs = (col < qcols) ? SCALE_Q : 1.0f;
            float bv = bias ? bias[col] : 0.0f;
#pragma unroll
            for (int r = 0; r < 4; ++r) {
                int row = m0 + wm + 16 * i + quad * 4 + r;
                float v = acc[i][t][r] + bv;
                if (relu) v = fmaxf(v, 0.0f);
                outh[(size_t)row * N + col] = f2bf(v * cs);
            }
        }
    }
}

// ---------------------------------------------------------------------------
// 128x256-tile 8-phase GEMM (round-8 verified). For M=8192: grid = 64 x N/256
// blocks -> exact multiples of 256 CUs (Wo/fc2: 256; QKV: 768 = 3.0 waves vs
// 256^2's 1.5-wave tail). Unified epilogue — outh!=null writes bf16 with
// qcols SCALE_Q (QKV); else fp32 + optional residual (Wo: +x; fc2: in-place
// += out). LDS 96KB -> 1 block/CU.
// ---------------------------------------------------------------------------
#define STAGE_A1B(T, h) do { \
    const unsigned short* s_ = A + (size_t)(m0 + (h) * 64 + rowA) * lda + (T) * 64 + colA; \
    unsigned short* d_ = Asm + ((((T) & 1) << 13) + ((h) << 12) + (w << 9)); \
    async_copy16(s_, d_); } while (0)

#define STAGE_B8B(T, h) do { \
    const unsigned short* s_ = Bt + (size_t)(n0 + (h) * 128 + rowin) * (size_t)K + (T) * 64; \
    unsigned short* d_ = Bsm + ((((T) & 1) << 14) + ((h) << 13) + sdst); \
    async_copy16(s_ + c0, d_); async_copy16(s_ + c1, d_ + 512); } while (0)

#define READ_A4B(PA) \
    _Pragma("unroll") \
    for (int i = 0; i < 4; ++i) \
        _Pragma("unroll") \
        for (int kk = 0; kk < 2; ++kk) \
            a_f[i][kk] = *(const bf16x8*)&Asm[(PA) + aoffb + ((i * 2 + kk) << 9)];

#define READ_B8B(PB) \
    _Pragma("unroll") \
    for (int t = 0; t < 4; ++t) \
        _Pragma("unroll") \
        for (int kk = 0; kk < 2; ++kk) \
            b_f[t][kk] = *(const bf16x8*)&Bsm[(PB) + boff + ((t * 2 + kk) << 9)];

#define MFMA_QB(ilo, tlo) \
    _Pragma("unroll") \
    for (int i = 0; i < 2; ++i) \
        _Pragma("unroll") \
        for (int t = 0; t < 2; ++t) \
            _Pragma("unroll") \
            for (int kk = 0; kk < 2; ++kk) \
                acc[(ilo) + i][(tlo) + t] = __builtin_amdgcn_mfma_f32_16x16x32_bf16( \
                    a_f[(ilo) + i][kk], b_f[(tlo) + t][kk], acc[(ilo) + i][(tlo) + t], 0, 0, 0);

__global__ __launch_bounds__(512, 2) void gemm_8ph_b(
    const unsigned short* __restrict__ A, const unsigned short* __restrict__ Bt,
    const float* __restrict__ bias, const float* __restrict__ resid,
    float* __restrict__ outf, unsigned short* __restrict__ outh,
    int M, int N, int K, int lda, int qcols) {
    __shared__ unsigned short Asm[16384];   // 32KB: 2buf x 2half(64r) x 8sub x 512
    __shared__ unsigned short Bsm[32768];   // 64KB: identical to 256^2 template

    int tid = threadIdx.x;
    int w = tid >> 6, lane = tid & 63;
    int lr = lane & 15, quad = lane >> 4;

    int nwg = gridDim.x;                     // multiple of 8
    int bid = blockIdx.x;
    int swz = (bid & 7) * (nwg >> 3) + (bid >> 3);
    int m0 = (swz & 63) << 7;                // 64 m-tiles x 128
    int n0 = (swz >> 6) << 8;                // n-tiles x 256

    // B staging geometry (identical to 256^2 template)
    int rowin = (w << 4) + (lane >> 2);
    int q = (lane & 3) ^ ((lane >> 5) << 1);
    int c0 = q * 8, c1 = 32 + q * 8;
    int sdst = w << 10;

    // A staging geometry: wave w -> subtile w of each 64-row half
    int rowA = ((w >> 1) << 4) + (lane >> 2);            // 0..63
    int colA = ((w & 1) << 5) + (((lane & 3) ^ ((lane & 32) ? 2 : 0)) << 3);

    int qsw8 = ((lane & 8) ? (quad ^ 2) : quad) * 8;
    int aoffb = ((w >> 2) << 12) + lr * 32 + qsw8;       // + (2i+kk)<<9
    int boff = ((w & 3) >> 1) * 8192 + ((w & 3) & 1) * 4096 + lr * 32 + qsw8;
    int wm = (w >> 2) * 64, wn = (w & 3) * 64;

    floatx4 acc[4][4];
#pragma unroll
    for (int i = 0; i < 4; ++i)
#pragma unroll
        for (int t = 0; t < 4; ++t)
#pragma unroll
            for (int r = 0; r < 4; ++r) acc[i][t][r] = 0.0f;

    int NT = K >> 6;   // even

    // prologue: t0 fully + t1's B0,B1,A0 ; wait tile0 -> vmcnt(5)
    STAGE_B8B(0, 0); STAGE_B8B(0, 1); STAGE_A1B(0, 0); STAGE_A1B(0, 1);
    STAGE_B8B(1, 0); STAGE_B8B(1, 1); STAGE_A1B(1, 0);
    asm volatile("s_waitcnt vmcnt(5)" ::: "memory");
    BAR8();

    bf16x8 a_f[4][2], b_f[4][2];

    for (int T = 0; T < NT; T += 2) {
        // ======== tile T (buf 0: A @0, B @0) ========
        READ_A4B(0);
        READ_B8B(0);
        if (T + 1 < NT) STAGE_A1B(T + 1, 1);
        BAR8(); WAIT_LGKM0();
        __builtin_amdgcn_s_setprio(1); MFMA_QB(0, 0); __builtin_amdgcn_s_setprio(0);
        BAR8();
        if (T + 2 < NT) STAGE_B8B(T + 2, 0);
        BAR8();
        __builtin_amdgcn_s_setprio(1); MFMA_QB(0, 2); __builtin_amdgcn_s_setprio(0);
        BAR8();
        if (T + 2 < NT) STAGE_B8B(T + 2, 1);
        BAR8();
        __builtin_amdgcn_s_setprio(1); MFMA_QB(2, 0); __builtin_amdgcn_s_setprio(0);
        BAR8();
        if (T + 2 < NT) STAGE_A1B(T + 2, 0);
        BAR8();
        __builtin_amdgcn_s_setprio(1); MFMA_QB(2, 2); __builtin_amdgcn_s_setprio(0);
        if (T + 2 < NT) { asm volatile("s_waitcnt vmcnt(5)" ::: "memory"); }
        else            { asm volatile("s_waitcnt vmcnt(0)" ::: "memory"); }
        BAR8();

        // ======== tile T+1 (buf 1: A @8192, B @16384) ========
        READ_A4B(8192);
        READ_B8B(16384);
        if (T + 2 < NT) STAGE_A1B(T + 2, 1);
        BAR8(); WAIT_LGKM0();
        __builtin_amdgcn_s_setprio(1); MFMA_QB(0, 0); __builtin_amdgcn_s_setprio(0);
        BAR8();
        if (T + 3 < NT) STAGE_B8B(T + 3, 0);
        BAR8();
        __builtin_amdgcn_s_setprio(1); MFMA_QB(0, 2); __builtin_amdgcn_s_setprio(0);
        BAR8();
        if (T + 3 < NT) STAGE_B8B(T + 3, 1);
        BAR8();
        __builtin_amdgcn_s_setprio(1); MFMA_QB(2, 0); __builtin_amdgcn_s_setprio(0);
        BAR8();
        if (T + 3 < NT) STAGE_A1B(T + 3, 0);
        BAR8();
        __builtin_amdgcn_s_setprio(1); MFMA_QB(2, 2); __builtin_amdgcn_s_setprio(0);
        if (T + 3 < NT) { asm volatile("s_waitcnt vmcnt(5)" ::: "memory"); }
        else            { asm volatile("s_waitcnt vmcnt(0)" ::: "memory"); }
        BAR8();
    }

    // unified epilogue: bf16 (+qcols scale) or fp32 (+bias/residual)
#pragma unroll
    for (int i = 0; i < 4; ++i) {
#pragma unroll
        for (int t = 0; t < 4; ++t) {
            int col = n0 + wn + 16 * t + lr;
            float cs = (col < qcols) ? SCALE_Q : 1.0f;
            float bv = bias ? bias[col] : 0.0f;
#pragma unroll
            for (int r = 0; r < 4; ++r) {
                int row = m0 + wm + 16 * i + quad * 4 + r;
                size_t idx = (size_t)row * N + col;
                float v = acc[i][t][r] + bv;
                if (outh) {
                    outh[idx] = f2bf(v * cs);
                } else {
                    if (resid) v += resid[idx];
                    outf[idx] = v;
                }
            }
        }
    }
}

// ---------------------------------------------------------------------------
// V transpose: vsrc rows (stride QKVS) -> vt[bh][dk][s'] with per-64-block
// permutation sigma(u) = 4*(u&15) + (u>>4)  (matches attention P-writes).
// ---------------------------------------------------------------------------
__global__ __launch_bounds__(256) void transpose_v(
    const unsigned short* __restrict__ vsrc, unsigned short* __restrict__ vt) {
    int bh = blockIdx.y;
    int b = bh >> 4, h = bh & 15;
    int s = blockIdx.x * 256 + threadIdx.x;
    size_t inbase = ((size_t)(b * SS + s)) * QKVS + h * 64;
    size_t outbase = (size_t)bh * 64 * SS;
    int sp = (s & ~63) + 4 * (s & 15) + ((s >> 4) & 3);
#pragma unroll
    for (int dk8 = 0; dk8 < 8; ++dk8) {
        uint4 raw = *(const uint4*)(vsrc + inbase + dk8 * 8);
        const unsigned short* ph = (const unsigned short*)&raw;
#pragma unroll
        for (int i = 0; i < 8; ++i)
            vt[outbase + (size_t)(dk8 * 8 + i) * SS + sp] = ph[i];
    }
}

// ---------------------------------------------------------------------------
// Flash attention v13 = round-7 verified structure (registers-resident Q,
// (256,2), compiler-scheduled loads, T5 setprio) + l-via-MFMA:
// lacc[i] = mfma(pf[i], ones, lacc[i]) gives full row sums of the SAME bf16 P
// used in PV (8 extra MFMA/jt on the 19%-busy pipe) and deletes 64 VALU
// adds/jt (47%-busy pipe) + the entire epilogue shfl-reduce chain.
// ctx is written into the dead V-columns of the qkv buffer (stride QKVS).
// (Round 9 resubmission — round-9 bench was an acquisition timeout.)
// ---------------------------------------------------------------------------
#define PST 68    // Ps row stride (bf16)

__global__ __launch_bounds__(256, 2) void attention_mfma11(
    const unsigned short* __restrict__ qkv, const unsigned short* __restrict__ vt,
    unsigned short* __restrict__ ctx /* = qkv + 2048, stride QKVS */) {
    __shared__ unsigned short Ps[256 * PST];   // 34816 B; reused by epilogue

    int tid = threadIdx.x;
    int wave = tid >> 6, lane = tid & 63;
    int lr = lane & 15, quad = lane >> 4;
    int wq = wave >> 1, wj = wave & 1;

    int bid = blockIdx.x;
    int bh = bid & 63;                 // same bh -> same XCD
    int qt = bid >> 6;
    int b = bh >> 4, h = bh & 15;
    int q0 = qt * 128;
    size_t q_base = ((size_t)b * SS) * QKVS + h * 64;
    size_t k_base = q_base + 1024;
    size_t vt_base = (size_t)bh * 64 * SS;

    uint4 af[4][2];
#pragma unroll
    for (int i = 0; i < 4; ++i)
#pragma unroll
        for (int kk = 0; kk < 2; ++kk)
            af[i][kk] = *(const uint4*)(qkv + q_base +
                (size_t)(q0 + 64 * wq + 16 * i + lr) * QKVS + kk * 32 + quad * 8);

    floatx4 o[4][4];
    floatx4 lacc[4];
#pragma unroll
    for (int i = 0; i < 4; ++i) {
#pragma unroll
        for (int t = 0; t < 4; ++t)
#pragma unroll
            for (int r = 0; r < 4; ++r) o[i][t][r] = 0.0f;
#pragma unroll
        for (int r = 0; r < 4; ++r) lacc[i][r] = 0.0f;
    }
    floatx4 zf;
#pragma unroll
    for (int r = 0; r < 4; ++r) zf[r] = 0.0f;

    // all-ones bf16 B-fragment for P@ones row sums
    uint4 onesu;
    onesu.x = 0x3F803F80u; onesu.y = 0x3F803F80u;
    onesu.z = 0x3F803F80u; onesu.w = 0x3F803F80u;
    bf16x8 onesf = as_frag(onesu);

    unsigned short* myPs = &Ps[wave * 64 * PST];

    for (int jt = 0; jt < SS / 128; ++jt) {
        int j0 = jt * 128 + 64 * wj;

        floatx4 s[4][4];
        {
            uint4 bv[4];
#pragma unroll
            for (int t = 0; t < 4; ++t)
                bv[t] = *(const uint4*)(qkv + k_base +
                    (size_t)(j0 + 16 * t + lr) * QKVS + quad * 8);
            __builtin_amdgcn_s_setprio(1);
#pragma unroll
            for (int i = 0; i < 4; ++i)
#pragma unroll
                for (int t = 0; t < 4; ++t)
                    s[i][t] = __builtin_amdgcn_mfma_f32_16x16x32_bf16(
                        as_frag(af[i][0]), as_frag(bv[t]), zf, 0, 0, 0);
            __builtin_amdgcn_s_setprio(0);
        }
        {
            uint4 bv[4];
#pragma unroll
            for (int t = 0; t < 4; ++t)
                bv[t] = *(const uint4*)(qkv + k_base +
                    (size_t)(j0 + 16 * t + lr) * QKVS + 32 + quad * 8);
            __builtin_amdgcn_s_setprio(1);
#pragma unroll
            for (int i = 0; i < 4; ++i)
#pragma unroll
                for (int t = 0; t < 4; ++t)
                    s[i][t] = __builtin_amdgcn_mfma_f32_16x16x32_bf16(
                        as_frag(af[i][1]), as_frag(bv[t]), s[i][t], 0, 0, 0);
            __builtin_amdgcn_s_setprio(0);
        }

        // softmax-lite: p = exp2(s); pack + wave-private P write (no l adds)
#pragma unroll
        for (int i = 0; i < 4; ++i) {
#pragma unroll
            for (int r = 0; r < 4; ++r) {
                float p0 = exp2f(s[i][0][r]);
                float p1 = exp2f(s[i][1][r]);
                float p2 = exp2f(s[i][2][r]);
                float p3 = exp2f(s[i][3][r]);
                uint2 w;
                w.x = pack_bf_trunc(p0, p1);
                w.y = pack_bf_trunc(p2, p3);
                *(uint2*)&myPs[(16 * i + quad * 4 + r) * PST + 4 * lr] = w;
            }
        }

        // O += P @ V-half ; lacc += P @ ones (row sums of bf16 P)
#pragma unroll
        for (int kk = 0; kk < 2; ++kk) {
            uint4 vv[4];
#pragma unroll
            for (int t = 0; t < 4; ++t)
                vv[t] = *(const uint4*)(vt + vt_base +
                    (size_t)(16 * t + lr) * SS + j0 + kk * 32 + quad * 8);
            bf16x8 pf[4];
#pragma unroll
            for (int i = 0; i < 4; ++i)
                pf[i] = *(const bf16x8*)&myPs[(16 * i + lr) * PST + kk * 32 + quad * 8];
            __builtin_amdgcn_s_setprio(1);
#pragma unroll
            for (int i = 0; i < 4; ++i)
#pragma unroll
                for (int t = 0; t < 4; ++t)
                    o[i][t] = __builtin_amdgcn_mfma_f32_16x16x32_bf16(
                        pf[i], as_frag(vv[t]), o[i][t], 0, 0, 0);
#pragma unroll
            for (int i = 0; i < 4; ++i)
                lacc[i] = __builtin_amdgcn_mfma_f32_16x16x32_bf16(
                    pf[i], onesf, lacc[i], 0, 0, 0);
            __builtin_amdgcn_s_setprio(0);
        }
    }

    // merge j-halves: wj==1 dumps partial O,l to LDS; wj==0 combines+stores
    // (lacc already holds complete row sums — no shfl reduce needed)
    __syncthreads();
    float* obuf = (float*)Ps;             // [2][64][65] floats
    float* lbuf = obuf + 2 * 64 * 65;     // [2][64] floats
    if (wj == 1) {
#pragma unroll
        for (int i = 0; i < 4; ++i)
#pragma unroll
            for (int r = 0; r < 4; ++r) {
                int rl = 16 * i + quad * 4 + r;
#pragma unroll
                for (int t = 0; t < 4; ++t)
                    obuf[(wq * 64 + rl) * 65 + 16 * t + lr] = o[i][t][r];
                if (lr == 0) lbuf[wq * 64 + rl] = lacc[i][r];
            }
    }
    __syncthreads();
    if (wj == 0) {
#pragma unroll
        for (int i = 0; i < 4; ++i)
#pragma unroll
            for (int r = 0; r < 4; ++r) {
                int rl = 16 * i + quad * 4 + r;
                float inv = 1.0f / (lacc[i][r] + lbuf[wq * 64 + rl]);
                int row = q0 + 64 * wq + rl;
                size_t base = ((size_t)(b * SS + row)) * QKVS + h * 64;
#pragma unroll
                for (int t = 0; t < 4; ++t)
                    ctx[base + 16 * t + lr] =
                        f2bf((o[i][t][r] + obuf[(wq * 64 + rl) * 65 + 16 * t + lr]) * inv);
            }
    }
}

// ---------------------------------------------------------------------------
extern "C" void kernel_launch(void* const* d_in, const int* in_sizes, int n_in,
                              void* d_out, int out_size, void* d_ws, size_t ws_size,
                              hipStream_t stream) {
    const float* x     = (const float*)d_in[0];
    const float* Wq    = (const float*)d_in[1];
    const float* Wk    = (const float*)d_in[2];
    const float* Wv    = (const float*)d_in[3];
    const float* Wo    = (const float*)d_in[4];
    const float* ln1g  = (const float*)d_in[5];
    const float* ln1b  = (const float*)d_in[6];
    const float* fc1w  = (const float*)d_in[7];
    const float* fc1b  = (const float*)d_in[8];
    const float* fc2w  = (const float*)d_in[9];
    const float* fc2b  = (const float*)d_in[10];
    const float* ln2g  = (const float*)d_in[11];
    const float* ln2b  = (const float*)d_in[12];
    float* out = (float*)d_out;

    // workspace (peak 80MB): see round-1 comment for the overlay plan
    char* ws = (char*)d_ws;
    const size_t MB = 1024 * 1024;
    unsigned short* wqkvT = (unsigned short*)(ws + 0 * MB);
    unsigned short* woT   = (unsigned short*)(ws + 6 * MB);
    unsigned short* fc1T  = (unsigned short*)(ws + 8 * MB);
    unsigned short* fc2T  = (unsigned short*)(ws + 12 * MB);
    unsigned short* xn    = (unsigned short*)(ws + 16 * MB);
    unsigned short* vt    = xn;
    unsigned short* hn    = xn;
    unsigned short* qkvb  = (unsigned short*)(ws + 32 * MB);
    unsigned short* ctx   = qkvb + 2048;        // V-cols, stride QKVS
    unsigned short* h1    = qkvb;               // reuse after ctx dead

    dim3 blk(256);

    transpose_all<<<2048, blk, 0, stream>>>(Wq, Wk, Wv, Wo, fc1w, fc2w,
                                            wqkvT, woT, fc1T, fc2T);

    layernorm_bf16<<<NTOK, blk, 0, stream>>>(x, ln1g, ln1b, xn, 1e-5f);

    // fused QKV projection: 128x256 8-phase, 64x12 = 768 blocks = 3.0 exact
    // dispatch waves (vs 256^2's 384 = 1.5-wave tail); Q cols pre-scaled
    gemm_8ph_b<<<768, 512, 0, stream>>>(xn, wqkvT, nullptr, nullptr,
                                        nullptr, qkvb,
                                        NTOK, QKVS, 1024, 1024, 1024);
    transpose_v<<<dim3(8, 64), blk, 0, stream>>>(qkvb + 2048, vt);  // vt over xn

    attention_mfma11<<<1024, blk, 0, stream>>>(qkvb, vt, ctx);

    // Wo GEMM: 128x256 8-phase, 256 blocks (full chip), fp32 out + residual x
    gemm_8ph_b<<<256, 512, 0, stream>>>(ctx, woT, nullptr, x, out, nullptr,
                                        NTOK, 1024, 1024, QKVS, 0);
    layernorm_bf16<<<NTOK, blk, 0, stream>>>(out, ln2g, ln2b, hn, 1e-6f);
    // fc1: 256^2 8-phase, 256 blocks (exact fill), relu
    gemm_8ph<<<256, 512, 0, stream>>>(hn, fc1T, fc1b, h1,
                                      NTOK, 2048, 1024, 1, 1024, 0);
    // fc2: 128x256 8-phase, in-place residual accumulate
    gemm_8ph_b<<<256, 512, 0, stream>>>(h1, fc2T, fc2b, out, out, nullptr,
                                        NTOK, 1024, 2048, 2048, 0);
}